// Round 1
// baseline (2079.015 us; speedup 1.0000x reference)
//
#include <hip/hip_runtime.h>
#include <math.h>

static inline int cdiv(long a, long b){ return (int)((a + b - 1) / b); }

// ---- order-preserving float<->uint for atomicMax on floats of any sign ----
__device__ __forceinline__ unsigned ford(float f){
  unsigned u = __float_as_uint(f);
  return (u & 0x80000000u) ? ~u : (u | 0x80000000u);
}
__device__ __forceinline__ float fdec(unsigned u){
  return (u & 0x80000000u) ? __uint_as_float(u & 0x7FFFFFFFu) : __uint_as_float(~u);
}
__device__ __forceinline__ float lrelu(float x){ return x > 0.f ? x : 0.2f * x; }
__device__ __forceinline__ float eluf(float x){ return x > 0.f ? x : expm1f(x); }

// ---- dense: out[N,FOUT] = A[N,K] @ W[K,FOUT], W staged in LDS ----
template<int K, int FOUT>
__global__ void k_gemm(const float* __restrict__ A, const float* __restrict__ W,
                       float* __restrict__ out, int N){
  __shared__ float Ws[K * FOUT];
  for(int i = threadIdx.x; i < K * FOUT; i += blockDim.x) Ws[i] = W[i];
  __syncthreads();
  long total = (long)N * FOUT;
  for(long idx = (long)blockIdx.x * blockDim.x + threadIdx.x; idx < total;
      idx += (long)gridDim.x * blockDim.x){
    int row = (int)(idx / FOUT);
    int col = (int)(idx - (long)row * FOUT);
    const float* a = A + (long)row * K;
    float acc = 0.f;
    #pragma unroll
    for(int k = 0; k < K; ++k) acc = fmaf(a[k], Ws[k * FOUT + col], acc);
    out[idx] = acc;
  }
}

// ---- per-node attention dots: as_[i] = h[i,:]·a_s ; ad_[i] = h[i,:]·a_d  (F=128) ----
__global__ void k_attn_dots(const float* __restrict__ h, const float* __restrict__ a_s,
                            const float* __restrict__ a_d, float* __restrict__ outs,
                            float* __restrict__ outd, int N){
  int i = blockIdx.x * blockDim.x + threadIdx.x;
  if(i >= N) return;
  const float4* hp  = (const float4*)(h + (long)i * 128);
  const float4* asp = (const float4*)a_s;
  const float4* adp = (const float4*)a_d;
  float ss = 0.f, sd = 0.f;
  #pragma unroll
  for(int k = 0; k < 32; ++k){
    float4 v = hp[k], xa = asp[k], ya = adp[k];
    ss += v.x*xa.x + v.y*xa.y + v.z*xa.z + v.w*xa.w;
    sd += v.x*ya.x + v.y*ya.y + v.z*ya.z + v.w*ya.w;
  }
  outs[i] = ss; outd[i] = sd;
}

__device__ __forceinline__ void edge_sd(const int* __restrict__ ei, int E, int e,
                                        int& s, int& d){
  if(e < E){ s = ei[e]; d = ei[E + e]; } else { s = e - E; d = s; }  // self-loops appended
}

// ---- GAT edge pass 1: segment max of leaky_relu logits over dst ----
__global__ void k_edge_max(const int* __restrict__ ei, int E, int N,
                           const float* __restrict__ as_, const float* __restrict__ ad_,
                           unsigned* __restrict__ m){
  int e = blockIdx.x * blockDim.x + threadIdx.x;
  if(e >= E + N) return;
  int s, d; edge_sd(ei, E, e, s, d);
  float l = lrelu(as_[s] + ad_[d]);
  atomicMax(&m[d], ford(l));
}

// ---- GAT edge pass 2: segment sum of exp(logit - max) ----
__global__ void k_edge_expsum(const int* __restrict__ ei, int E, int N,
                              const float* __restrict__ as_, const float* __restrict__ ad_,
                              const unsigned* __restrict__ m, float* __restrict__ ssum){
  int e = blockIdx.x * blockDim.x + threadIdx.x;
  if(e >= E + N) return;
  int s, d; edge_sd(ei, E, e, s, d);
  float l = lrelu(as_[s] + ad_[d]);
  atomicAdd(&ssum[d], expf(l - fdec(m[d])));
}

// ---- GAT edge pass 3: out[dst,:] += alpha * h[src,:]  (wave per edge) ----
template<int F>
__global__ void k_gat_scatter(const int* __restrict__ ei, int E, int N,
                              const float* __restrict__ as_, const float* __restrict__ ad_,
                              const unsigned* __restrict__ m, const float* __restrict__ ssum,
                              const float* __restrict__ h, float* __restrict__ out){
  long t = (long)blockIdx.x * blockDim.x + threadIdx.x;
  int e = (int)(t >> 6), lane = (int)(t & 63);
  if(e >= E + N) return;
  int s, d; edge_sd(ei, E, e, s, d);
  float l = lrelu(as_[s] + ad_[d]);
  float alpha = expf(l - fdec(m[d])) / (ssum[d] + 1e-16f);
  #pragma unroll
  for(int f = lane; f < F; f += 64)
    atomicAdd(&out[(long)d * F + f], alpha * h[(long)s * F + f]);
}

// ---- GCN degree (with self-loops) ----
__global__ void k_deg(const int* __restrict__ ei, int E, int N, float* __restrict__ deg){
  int e = blockIdx.x * blockDim.x + threadIdx.x;
  if(e >= E + N) return;
  int d = (e < E) ? ei[E + e] : (e - E);
  atomicAdd(&deg[d], 1.f);
}
__global__ void k_rsqrt_inplace(float* __restrict__ v, int N){
  int i = blockIdx.x * blockDim.x + threadIdx.x;
  if(i >= N) return;
  float d = v[i];
  v[i] = d > 0.f ? rsqrtf(d) : 0.f;
}

// ---- GCN scatter: out[dst,:] += dinv[s]*dinv[d]*h[src,:]  (wave per edge) ----
template<int F>
__global__ void k_gcn_scatter(const int* __restrict__ ei, int E, int N,
                              const float* __restrict__ dinv,
                              const float* __restrict__ h, float* __restrict__ out){
  long t = (long)blockIdx.x * blockDim.x + threadIdx.x;
  int e = (int)(t >> 6), lane = (int)(t & 63);
  if(e >= E + N) return;
  int s, d; edge_sd(ei, E, e, s, d);
  float norm = dinv[s] * dinv[d];
  #pragma unroll
  for(int f = lane; f < F; f += 64)
    atomicAdd(&out[(long)d * F + f], norm * h[(long)s * F + f]);
}

// ---- bias + ELU, in place ----
template<int F>
__global__ void k_bias_elu(float* __restrict__ h, const float* __restrict__ b, int N){
  long idx = (long)blockIdx.x * blockDim.x + threadIdx.x;
  if(idx >= (long)N * F) return;
  int c = (int)(idx % F);
  h[idx] = eluf(h[idx] + b[c]);
}

// ---- per-graph softmax aggregation (3 passes), channels C=32 ----
__global__ void k_agg_max(const float* __restrict__ h, const int* __restrict__ batch,
                          const float* __restrict__ t, unsigned* __restrict__ mB, int N){
  long idx = (long)blockIdx.x * blockDim.x + threadIdx.x;
  if(idx >= (long)N * 32) return;
  int i = (int)(idx >> 5), c = (int)(idx & 31);
  atomicMax(&mB[batch[i] * 32 + c], ford(h[idx] * t[0]));
}
__global__ void k_agg_sum(const float* __restrict__ h, const int* __restrict__ batch,
                          const float* __restrict__ t, const unsigned* __restrict__ mB,
                          float* __restrict__ sB, int N){
  long idx = (long)blockIdx.x * blockDim.x + threadIdx.x;
  if(idx >= (long)N * 32) return;
  int i = (int)(idx >> 5), c = (int)(idx & 31);
  unsigned mo = mB[batch[i] * 32 + c];
  float mv = (mo == 0u) ? 0.f : fdec(mo);
  atomicAdd(&sB[batch[i] * 32 + c], expf(h[idx] * t[0] - mv));
}
__global__ void k_agg_g(const float* __restrict__ h, const int* __restrict__ batch,
                        const float* __restrict__ t, const unsigned* __restrict__ mB,
                        const float* __restrict__ sB, float* __restrict__ g, int N){
  long idx = (long)blockIdx.x * blockDim.x + threadIdx.x;
  if(idx >= (long)N * 32) return;
  int i = (int)(idx >> 5), c = (int)(idx & 31);
  int bc = batch[i] * 32 + c;
  unsigned mo = mB[bc];
  float mv = (mo == 0u) ? 0.f : fdec(mo);
  float w = expf(h[idx] * t[0] - mv) / (sB[bc] + 1e-16f);
  atomicAdd(&g[bc], w * h[idx]);
}

// ---- heads: elu(g@Wl1+bl1) @ Wl2 + bl2 -> log_softmax ----
__global__ void k_head(const float* __restrict__ g, const float* __restrict__ Wl1,
                       const float* __restrict__ bl1, const float* __restrict__ Wl2,
                       const float* __restrict__ bl2, float* __restrict__ out, int B){
  int b = blockIdx.x * blockDim.x + threadIdx.x;
  if(b >= B) return;
  float gr[32];
  #pragma unroll
  for(int k = 0; k < 32; ++k) gr[k] = g[b * 32 + k];
  float h1[16];
  #pragma unroll
  for(int j = 0; j < 16; ++j){
    float acc = bl1[j];
    #pragma unroll
    for(int k = 0; k < 32; ++k) acc = fmaf(gr[k], Wl1[k * 16 + j], acc);
    h1[j] = eluf(acc);
  }
  float l0 = bl2[0], l1 = bl2[1];
  #pragma unroll
  for(int k = 0; k < 16; ++k){
    l0 = fmaf(h1[k], Wl2[k * 2 + 0], l0);
    l1 = fmaf(h1[k], Wl2[k * 2 + 1], l1);
  }
  float mx = fmaxf(l0, l1);
  float lse = mx + logf(expf(l0 - mx) + expf(l1 - mx));
  out[b * 2 + 0] = l0 - lse;
  out[b * 2 + 1] = l1 - lse;
}

extern "C" void kernel_launch(void* const* d_in, const int* in_sizes, int n_in,
                              void* d_out, int out_size, void* d_ws, size_t ws_size,
                              hipStream_t stream){
  const float* x     = (const float*)d_in[0];
  const int*   ei    = (const int*)d_in[1];
  const int*   batch = (const int*)d_in[2];
  const float* W1 = (const float*)d_in[3];
  const float* a1s = (const float*)d_in[4];
  const float* a1d = (const float*)d_in[5];
  const float* b1 = (const float*)d_in[6];
  const float* W2 = (const float*)d_in[7];
  const float* a2s = (const float*)d_in[8];
  const float* a2d = (const float*)d_in[9];
  const float* b2 = (const float*)d_in[10];
  const float* W3 = (const float*)d_in[11];
  const float* a3s = (const float*)d_in[12];
  const float* a3d = (const float*)d_in[13];
  const float* b3 = (const float*)d_in[14];
  const float* Wg1 = (const float*)d_in[15];
  const float* bg1 = (const float*)d_in[16];
  const float* Wg2 = (const float*)d_in[17];
  const float* bg2 = (const float*)d_in[18];
  const float* t   = (const float*)d_in[19];
  const float* Wl1 = (const float*)d_in[20];
  const float* bl1 = (const float*)d_in[21];
  const float* Wl2 = (const float*)d_in[22];
  const float* bl2 = (const float*)d_in[23];

  const int N = in_sizes[0];
  const int E = in_sizes[1] / 2;
  const int B = out_size / 2;
  const int ET = E + N;
  float* out = (float*)d_out;

  // workspace layout
  float*    A   = (float*)d_ws;                 // [N,128] accumulate / layer io
  float*    Bf  = A + (size_t)N * 128;          // [N,128] gemm out
  float*    as_ = Bf + (size_t)N * 128;         // [N]
  float*    ad_ = as_ + N;                      // [N]
  unsigned* m_  = (unsigned*)(ad_ + N);         // [N]
  float*    s_  = (float*)(m_ + N);             // [N] (softmax denom / deg / dinv)
  unsigned* mB  = (unsigned*)(s_ + N);          // [B*32]
  float*    sB  = (float*)(mB + (size_t)B * 32);// [B*32]
  float*    g   = sB + (size_t)B * 32;          // [B*32]

  const int T = 256;
  const int gNF128 = cdiv((long)N * 128, T);
  const int gN     = cdiv(N, T);
  const int gE     = cdiv(ET, T);
  const int gE64   = cdiv((long)ET * 64, T);

  // ---------- GAT layer 1 (1 -> 128) ----------
  k_gemm<1,128><<<dim3(4096), dim3(T), 0, stream>>>(x, W1, Bf, N);
  k_attn_dots<<<dim3(gN), dim3(T), 0, stream>>>(Bf, a1s, a1d, as_, ad_, N);
  hipMemsetAsync(m_, 0, (size_t)N * 4, stream);
  hipMemsetAsync(s_, 0, (size_t)N * 4, stream);
  hipMemsetAsync(A, 0, (size_t)N * 128 * 4, stream);
  k_edge_max<<<dim3(gE), dim3(T), 0, stream>>>(ei, E, N, as_, ad_, m_);
  k_edge_expsum<<<dim3(gE), dim3(T), 0, stream>>>(ei, E, N, as_, ad_, m_, s_);
  k_gat_scatter<128><<<dim3(gE64), dim3(T), 0, stream>>>(ei, E, N, as_, ad_, m_, s_, Bf, A);
  k_bias_elu<128><<<dim3(gNF128), dim3(T), 0, stream>>>(A, b1, N);

  // ---------- GAT layer 2 (128 -> 128) ----------
  k_gemm<128,128><<<dim3(4096), dim3(T), 0, stream>>>(A, W2, Bf, N);
  k_attn_dots<<<dim3(gN), dim3(T), 0, stream>>>(Bf, a2s, a2d, as_, ad_, N);
  hipMemsetAsync(m_, 0, (size_t)N * 4, stream);
  hipMemsetAsync(s_, 0, (size_t)N * 4, stream);
  hipMemsetAsync(A, 0, (size_t)N * 128 * 4, stream);
  k_edge_max<<<dim3(gE), dim3(T), 0, stream>>>(ei, E, N, as_, ad_, m_);
  k_edge_expsum<<<dim3(gE), dim3(T), 0, stream>>>(ei, E, N, as_, ad_, m_, s_);
  k_gat_scatter<128><<<dim3(gE64), dim3(T), 0, stream>>>(ei, E, N, as_, ad_, m_, s_, Bf, A);
  k_bias_elu<128><<<dim3(gNF128), dim3(T), 0, stream>>>(A, b2, N);

  // ---------- GAT layer 3 (128 -> 128) ----------
  k_gemm<128,128><<<dim3(4096), dim3(T), 0, stream>>>(A, W3, Bf, N);
  k_attn_dots<<<dim3(gN), dim3(T), 0, stream>>>(Bf, a3s, a3d, as_, ad_, N);
  hipMemsetAsync(m_, 0, (size_t)N * 4, stream);
  hipMemsetAsync(s_, 0, (size_t)N * 4, stream);
  hipMemsetAsync(A, 0, (size_t)N * 128 * 4, stream);
  k_edge_max<<<dim3(gE), dim3(T), 0, stream>>>(ei, E, N, as_, ad_, m_);
  k_edge_expsum<<<dim3(gE), dim3(T), 0, stream>>>(ei, E, N, as_, ad_, m_, s_);
  k_gat_scatter<128><<<dim3(gE64), dim3(T), 0, stream>>>(ei, E, N, as_, ad_, m_, s_, Bf, A);
  k_bias_elu<128><<<dim3(gNF128), dim3(T), 0, stream>>>(A, b3, N);

  // ---------- degree -> dinv (shared by both GCN layers) ----------
  hipMemsetAsync(s_, 0, (size_t)N * 4, stream);
  k_deg<<<dim3(gE), dim3(T), 0, stream>>>(ei, E, N, s_);
  k_rsqrt_inplace<<<dim3(gN), dim3(T), 0, stream>>>(s_, N);

  // ---------- GCN layer 1 (128 -> 64) ----------
  k_gemm<128,64><<<dim3(4096), dim3(T), 0, stream>>>(A, Wg1, Bf, N);
  hipMemsetAsync(A, 0, (size_t)N * 64 * 4, stream);
  k_gcn_scatter<64><<<dim3(gE64), dim3(T), 0, stream>>>(ei, E, N, s_, Bf, A);
  k_bias_elu<64><<<dim3(cdiv((long)N * 64, T)), dim3(T), 0, stream>>>(A, bg1, N);

  // ---------- GCN layer 2 (64 -> 32) ----------
  k_gemm<64,32><<<dim3(4096), dim3(T), 0, stream>>>(A, Wg2, Bf, N);
  hipMemsetAsync(A, 0, (size_t)N * 32 * 4, stream);
  k_gcn_scatter<32><<<dim3(gE64), dim3(T), 0, stream>>>(ei, E, N, s_, Bf, A);
  k_bias_elu<32><<<dim3(cdiv((long)N * 32, T)), dim3(T), 0, stream>>>(A, bg2, N);

  // ---------- per-graph softmax aggregation ----------
  hipMemsetAsync(mB, 0, (size_t)B * 32 * 4, stream);
  hipMemsetAsync(sB, 0, (size_t)B * 32 * 4, stream);
  hipMemsetAsync(g, 0, (size_t)B * 32 * 4, stream);
  const int gN32 = cdiv((long)N * 32, T);
  k_agg_max<<<dim3(gN32), dim3(T), 0, stream>>>(A, batch, t, mB, N);
  k_agg_sum<<<dim3(gN32), dim3(T), 0, stream>>>(A, batch, t, mB, sB, N);
  k_agg_g<<<dim3(gN32), dim3(T), 0, stream>>>(A, batch, t, mB, sB, g, N);

  // ---------- MLP heads + log_softmax ----------
  k_head<<<dim3(cdiv(B, 64)), dim3(64), 0, stream>>>(g, Wl1, bl1, Wl2, bl2, out, B);
}

// Round 2
// 1050.148 us; speedup vs baseline: 1.9797x; 1.9797x over previous
//
#include <hip/hip_runtime.h>
#include <math.h>

static inline int cdiv(long a, long b){ return (int)((a + b - 1) / b); }

__device__ __forceinline__ float lrelu(float x){ return x > 0.f ? x : 0.2f * x; }
__device__ __forceinline__ float eluf(float x){ return x > 0.f ? x : expm1f(x); }

// ---- dense: out[N,FOUT] = A[N,K] @ W[K,FOUT], W staged in LDS ----
template<int K, int FOUT>
__global__ void k_gemm(const float* __restrict__ A, const float* __restrict__ W,
                       float* __restrict__ out, int N){
  __shared__ float Ws[K * FOUT];
  for(int i = threadIdx.x; i < K * FOUT; i += blockDim.x) Ws[i] = W[i];
  __syncthreads();
  long total = (long)N * FOUT;
  for(long idx = (long)blockIdx.x * blockDim.x + threadIdx.x; idx < total;
      idx += (long)gridDim.x * blockDim.x){
    int row = (int)(idx / FOUT);
    int col = (int)(idx - (long)row * FOUT);
    const float* a = A + (long)row * K;
    float acc = 0.f;
    #pragma unroll
    for(int k = 0; k < K; ++k) acc = fmaf(a[k], Ws[k * FOUT + col], acc);
    out[idx] = acc;
  }
}

// ---- per-node attention dots: as_[i] = h[i,:]·a_s ; ad_[i] = h[i,:]·a_d  (F=128) ----
__global__ void k_attn_dots(const float* __restrict__ h, const float* __restrict__ a_s,
                            const float* __restrict__ a_d, float* __restrict__ outs,
                            float* __restrict__ outd, int N){
  int i = blockIdx.x * blockDim.x + threadIdx.x;
  if(i >= N) return;
  const float4* hp  = (const float4*)(h + (long)i * 128);
  const float4* asp = (const float4*)a_s;
  const float4* adp = (const float4*)a_d;
  float ss = 0.f, sd = 0.f;
  #pragma unroll
  for(int k = 0; k < 32; ++k){
    float4 v = hp[k], xa = asp[k], ya = adp[k];
    ss += v.x*xa.x + v.y*xa.y + v.z*xa.z + v.w*xa.w;
    sd += v.x*ya.x + v.y*ya.y + v.z*ya.z + v.w*ya.w;
  }
  outs[i] = ss; outd[i] = sd;
}

// ======================= CSR build (dst-sorted, with self-loops) =======================
__global__ void k_deg_init(int* __restrict__ deg, int N){
  int i = blockIdx.x * blockDim.x + threadIdx.x;
  if(i < N) deg[i] = 1;                       // self-loop
}
__global__ void k_deg_count(const int* __restrict__ ei, int E, int* __restrict__ deg){
  int e = blockIdx.x * blockDim.x + threadIdx.x;
  if(e < E) atomicAdd(&deg[ei[E + e]], 1);
}
// single-block exclusive scan, 1024 threads, chunked Hillis-Steele
__global__ void k_scan(const int* __restrict__ deg, int* __restrict__ rowptr, int N){
  __shared__ int buf[1024];
  __shared__ int carry;
  if(threadIdx.x == 0) carry = 0;
  __syncthreads();
  for(int base = 0; base < N; base += 1024){
    int i = base + threadIdx.x;
    int v = (i < N) ? deg[i] : 0;
    buf[threadIdx.x] = v;
    __syncthreads();
    for(int off = 1; off < 1024; off <<= 1){
      int t = (threadIdx.x >= off) ? buf[threadIdx.x - off] : 0;
      __syncthreads();
      buf[threadIdx.x] += t;
      __syncthreads();
    }
    if(i < N) rowptr[i] = carry + buf[threadIdx.x] - v;
    __syncthreads();
    if(threadIdx.x == 0) carry += buf[1023];
    __syncthreads();
  }
  if(threadIdx.x == 0) rowptr[N] = carry;
}
__global__ void k_copy_i32(const int* __restrict__ src, int* __restrict__ dst, int N){
  int i = blockIdx.x * blockDim.x + threadIdx.x;
  if(i < N) dst[i] = src[i];
}
__global__ void k_fill(const int* __restrict__ ei, int E, int N,
                       int* __restrict__ cursor, int* __restrict__ csr_src){
  int e = blockIdx.x * blockDim.x + threadIdx.x;
  if(e >= E + N) return;
  int s, d;
  if(e < E){ s = ei[e]; d = ei[E + e]; } else { s = e - E; d = s; }
  int pos = atomicAdd(&cursor[d], 1);
  csr_src[pos] = s;
}
__global__ void k_dinv(const int* __restrict__ deg, float* __restrict__ dinv, int N){
  int i = blockIdx.x * blockDim.x + threadIdx.x;
  if(i < N) dinv[i] = rsqrtf((float)deg[i]);   // deg >= 1 (self-loop)
}

// ======================= fused GAT aggregation: one wave per dst =======================
// out[d,:] = elu( sum_e alpha_e * h[src_e,:] + bias ), alpha = edge-softmax over dst
__global__ void k_gat_agg(const int* __restrict__ rowptr, const int* __restrict__ csr_src,
                          const float* __restrict__ as_, const float* __restrict__ ad_,
                          const float* __restrict__ h, const float* __restrict__ bias,
                          float* __restrict__ out, int N){
  int w = (int)(((long)blockIdx.x * blockDim.x + threadIdx.x) >> 6);
  int lane = threadIdx.x & 63;
  if(w >= N) return;
  int start = rowptr[w], end = rowptr[w + 1];
  float add = ad_[w];

  // phase A: per-lane online (max, expsum) over strided edges
  float m = -INFINITY, ssum = 0.f;
  for(int e = start + lane; e < end; e += 64){
    int s = csr_src[e];
    float l = lrelu(as_[s] + add);
    if(l > m){ ssum = ssum * expf(m - l) + 1.f; m = l; }
    else       ssum += expf(l - m);
  }
  // wave merge
  #pragma unroll
  for(int off = 32; off > 0; off >>= 1){
    float mo = __shfl_xor(m, off);
    float so = __shfl_xor(ssum, off);
    float mn = fmaxf(m, mo);
    float ea = (m  > -INFINITY) ? expf(m  - mn) : 0.f;
    float eb = (mo > -INFINITY) ? expf(mo - mn) : 0.f;
    ssum = ssum * ea + so * eb;
    m = mn;
  }
  float inv = 1.f / (ssum + 1e-16f);

  // phase B: serial edges, all lanes accumulate 2 features each
  float acc0 = 0.f, acc1 = 0.f;
  for(int e = start; e < end; ++e){
    int s = csr_src[e];                         // wave-uniform -> broadcast
    float l = lrelu(as_[s] + add);
    float alpha = expf(l - m) * inv;
    const float* hr = h + (long)s * 128;
    acc0 = fmaf(alpha, hr[lane],      acc0);
    acc1 = fmaf(alpha, hr[lane + 64], acc1);
  }
  out[(long)w * 128 + lane]      = eluf(acc0 + bias[lane]);
  out[(long)w * 128 + lane + 64] = eluf(acc1 + bias[lane + 64]);
}

// ======================= fused GCN aggregation: one wave per dst =======================
template<int F>
__global__ void k_gcn_agg(const int* __restrict__ rowptr, const int* __restrict__ csr_src,
                          const float* __restrict__ dinv, const float* __restrict__ h,
                          const float* __restrict__ bias, float* __restrict__ out, int N){
  int w = (int)(((long)blockIdx.x * blockDim.x + threadIdx.x) >> 6);
  int lane = threadIdx.x & 63;
  if(w >= N) return;
  int start = rowptr[w], end = rowptr[w + 1];
  float dd = dinv[w];
  float acc = 0.f;
  for(int e = start; e < end; ++e){
    int s = csr_src[e];
    float nrm = dd * dinv[s];
    if(lane < F) acc = fmaf(nrm, h[(long)s * F + lane], acc);
  }
  if(lane < F) out[(long)w * F + lane] = eluf(acc + bias[lane]);
}

// ============ per-graph softmax aggregation: one block per graph (batch sorted) ============
__global__ void k_batch_agg(const float* __restrict__ h, const int* __restrict__ batch,
                            const float* __restrict__ t, float* __restrict__ g, int N){
  int b = blockIdx.x;
  __shared__ int s_lo, s_hi;
  __shared__ float red[8][32];
  if(threadIdx.x == 0){
    int lo = 0, hi = N;
    while(lo < hi){ int mid = (lo + hi) >> 1; if(batch[mid] < b) lo = mid + 1; else hi = mid; }
    s_lo = lo;
    int lo2 = lo, hi2 = N;
    while(lo2 < hi2){ int mid = (lo2 + hi2) >> 1; if(batch[mid] < b + 1) lo2 = mid + 1; else hi2 = mid; }
    s_hi = lo2;
  }
  __syncthreads();
  int lo = s_lo, hi = s_hi;
  float tv = t[0];
  int c = threadIdx.x & 31, r = threadIdx.x >> 5;   // 8 rows x 32 channels

  // pass 1: max
  float m = -INFINITY;
  for(int i = lo + r; i < hi; i += 8) m = fmaxf(m, h[(long)i * 32 + c] * tv);
  red[r][c] = m; __syncthreads();
  if(r == 0){
    float mm = red[0][c];
    #pragma unroll
    for(int k = 1; k < 8; ++k) mm = fmaxf(mm, red[k][c]);
    red[0][c] = (mm == -INFINITY) ? 0.f : mm;       // empty-segment guard (ref)
  }
  __syncthreads();
  m = red[0][c];
  __syncthreads();

  // pass 2: sum of exp
  float ssum = 0.f;
  for(int i = lo + r; i < hi; i += 8) ssum += expf(h[(long)i * 32 + c] * tv - m);
  red[r][c] = ssum; __syncthreads();
  if(r == 0){
    float tot = red[0][c];
    #pragma unroll
    for(int k = 1; k < 8; ++k) tot += red[k][c];
    red[0][c] = tot;
  }
  __syncthreads();
  float inv = 1.f / (red[0][c] + 1e-16f);
  __syncthreads();

  // pass 3: weighted sum
  float acc = 0.f;
  for(int i = lo + r; i < hi; i += 8){
    float hv = h[(long)i * 32 + c];
    acc += expf(hv * tv - m) * inv * hv;
  }
  red[r][c] = acc; __syncthreads();
  if(r == 0){
    float tot = red[0][c];
    #pragma unroll
    for(int k = 1; k < 8; ++k) tot += red[k][c];
    g[b * 32 + c] = tot;
  }
}

// ---- heads: elu(g@Wl1+bl1) @ Wl2 + bl2 -> log_softmax ----
__global__ void k_head(const float* __restrict__ g, const float* __restrict__ Wl1,
                       const float* __restrict__ bl1, const float* __restrict__ Wl2,
                       const float* __restrict__ bl2, float* __restrict__ out, int B){
  int b = blockIdx.x * blockDim.x + threadIdx.x;
  if(b >= B) return;
  float gr[32];
  #pragma unroll
  for(int k = 0; k < 32; ++k) gr[k] = g[b * 32 + k];
  float h1[16];
  #pragma unroll
  for(int j = 0; j < 16; ++j){
    float acc = bl1[j];
    #pragma unroll
    for(int k = 0; k < 32; ++k) acc = fmaf(gr[k], Wl1[k * 16 + j], acc);
    h1[j] = eluf(acc);
  }
  float l0 = bl2[0], l1 = bl2[1];
  #pragma unroll
  for(int k = 0; k < 16; ++k){
    l0 = fmaf(h1[k], Wl2[k * 2 + 0], l0);
    l1 = fmaf(h1[k], Wl2[k * 2 + 1], l1);
  }
  float mx = fmaxf(l0, l1);
  float lse = mx + logf(expf(l0 - mx) + expf(l1 - mx));
  out[b * 2 + 0] = l0 - lse;
  out[b * 2 + 1] = l1 - lse;
}

extern "C" void kernel_launch(void* const* d_in, const int* in_sizes, int n_in,
                              void* d_out, int out_size, void* d_ws, size_t ws_size,
                              hipStream_t stream){
  const float* x     = (const float*)d_in[0];
  const int*   ei    = (const int*)d_in[1];
  const int*   batch = (const int*)d_in[2];
  const float* W1 = (const float*)d_in[3];
  const float* a1s = (const float*)d_in[4];
  const float* a1d = (const float*)d_in[5];
  const float* b1 = (const float*)d_in[6];
  const float* W2 = (const float*)d_in[7];
  const float* a2s = (const float*)d_in[8];
  const float* a2d = (const float*)d_in[9];
  const float* b2 = (const float*)d_in[10];
  const float* W3 = (const float*)d_in[11];
  const float* a3s = (const float*)d_in[12];
  const float* a3d = (const float*)d_in[13];
  const float* b3 = (const float*)d_in[14];
  const float* Wg1 = (const float*)d_in[15];
  const float* bg1 = (const float*)d_in[16];
  const float* Wg2 = (const float*)d_in[17];
  const float* bg2 = (const float*)d_in[18];
  const float* t   = (const float*)d_in[19];
  const float* Wl1 = (const float*)d_in[20];
  const float* bl1 = (const float*)d_in[21];
  const float* Wl2 = (const float*)d_in[22];
  const float* bl2 = (const float*)d_in[23];

  const int N = in_sizes[0];
  const int E = in_sizes[1] / 2;
  const int B = out_size / 2;
  const int ET = E + N;
  float* out = (float*)d_out;

  // workspace layout
  float* A      = (float*)d_ws;                  // [N,128] layer io
  float* Bf     = A + (size_t)N * 128;           // [N,128] gemm out
  float* as_    = Bf + (size_t)N * 128;          // [N]
  float* ad_    = as_ + N;                       // [N]
  float* dinv   = ad_ + N;                       // [N]
  int*   deg    = (int*)(dinv + N);              // [N]
  int*   rowptr = deg + N;                       // [N+1]
  int*   cursor = rowptr + N + 1;                // [N]
  int*   csr    = cursor + N;                    // [E+N]
  float* g      = (float*)(csr + ET);            // [B*32]

  const int T = 256;
  const int gN  = cdiv(N, T);
  const int gE  = cdiv(E, T);
  const int gET = cdiv(ET, T);
  const int gW  = cdiv((long)N * 64, T);         // wave-per-dst grids

  // ---------- CSR build (shared by all graph layers) ----------
  k_deg_init<<<dim3(gN), dim3(T), 0, stream>>>(deg, N);
  k_deg_count<<<dim3(gE), dim3(T), 0, stream>>>(ei, E, deg);
  k_scan<<<dim3(1), dim3(1024), 0, stream>>>(deg, rowptr, N);
  k_copy_i32<<<dim3(gN), dim3(T), 0, stream>>>(rowptr, cursor, N);
  k_fill<<<dim3(gET), dim3(T), 0, stream>>>(ei, E, N, cursor, csr);
  k_dinv<<<dim3(gN), dim3(T), 0, stream>>>(deg, dinv, N);

  // ---------- GAT layer 1 (1 -> 128) ----------
  k_gemm<1,128><<<dim3(4096), dim3(T), 0, stream>>>(x, W1, Bf, N);
  k_attn_dots<<<dim3(gN), dim3(T), 0, stream>>>(Bf, a1s, a1d, as_, ad_, N);
  k_gat_agg<<<dim3(gW), dim3(T), 0, stream>>>(rowptr, csr, as_, ad_, Bf, b1, A, N);

  // ---------- GAT layer 2 (128 -> 128) ----------
  k_gemm<128,128><<<dim3(4096), dim3(T), 0, stream>>>(A, W2, Bf, N);
  k_attn_dots<<<dim3(gN), dim3(T), 0, stream>>>(Bf, a2s, a2d, as_, ad_, N);
  k_gat_agg<<<dim3(gW), dim3(T), 0, stream>>>(rowptr, csr, as_, ad_, Bf, b2, A, N);

  // ---------- GAT layer 3 (128 -> 128) ----------
  k_gemm<128,128><<<dim3(4096), dim3(T), 0, stream>>>(A, W3, Bf, N);
  k_attn_dots<<<dim3(gN), dim3(T), 0, stream>>>(Bf, a3s, a3d, as_, ad_, N);
  k_gat_agg<<<dim3(gW), dim3(T), 0, stream>>>(rowptr, csr, as_, ad_, Bf, b3, A, N);

  // ---------- GCN layer 1 (128 -> 64) ----------
  k_gemm<128,64><<<dim3(4096), dim3(T), 0, stream>>>(A, Wg1, Bf, N);
  k_gcn_agg<64><<<dim3(gW), dim3(T), 0, stream>>>(rowptr, csr, dinv, Bf, bg1, A, N);

  // ---------- GCN layer 2 (64 -> 32) ----------
  k_gemm<64,32><<<dim3(4096), dim3(T), 0, stream>>>(A, Wg2, Bf, N);
  k_gcn_agg<32><<<dim3(gW), dim3(T), 0, stream>>>(rowptr, csr, dinv, Bf, bg2, A, N);

  // ---------- per-graph softmax aggregation ----------
  k_batch_agg<<<dim3(B), dim3(T), 0, stream>>>(A, batch, t, g, N);

  // ---------- MLP heads + log_softmax ----------
  k_head<<<dim3(cdiv(B, 64)), dim3(64), 0, stream>>>(g, Wl1, bl1, Wl2, bl2, out, B);
}

// Round 3
// 692.055 us; speedup vs baseline: 3.0041x; 1.5174x over previous
//
#include <hip/hip_runtime.h>
#include <math.h>

static inline int cdiv(long a, long b){ return (int)((a + b - 1) / b); }
static inline char* alignp(char* p, size_t a){ return (char*)(((uintptr_t)p + a - 1) & ~(uintptr_t)(a - 1)); }

typedef __attribute__((ext_vector_type(8))) short bf16x8;
typedef __attribute__((ext_vector_type(4))) float f32x4;

__device__ __forceinline__ float lrelu(float x){ return x > 0.f ? x : 0.2f * x; }
__device__ __forceinline__ float eluf(float x){ return x > 0.f ? x : expm1f(x); }
__device__ __forceinline__ short f2bf(float f){            // RNE f32 -> bf16 bits
  unsigned u = __float_as_uint(f);
  return (short)((u + 0x7FFFu + ((u >> 16) & 1u)) >> 16);
}

// ======================= MFMA GEMM: out[N,FOUT] = Abf[N,K] @ W[K,FOUT] =======================
// W pre-packed into B-fragment order: Wp[((ks*NCT+ct)*64+lane)*8+j] = bf16(W[ks*32+(lane>>4)*8+j][ct*16+(lane&15)])
template<int K, int FOUT>
__global__ void k_gemm_mfma(const short* __restrict__ Abf, const short* __restrict__ Wp,
                            float* __restrict__ out, int N){
  constexpr int NKS = K / 32, NCT = FOUT / 16;
  int wid  = threadIdx.x >> 6;
  int lane = threadIdx.x & 63;
  int rowbase = (blockIdx.x * 4 + wid) * 16;
  if(rowbase >= N) return;
  int arow = rowbase + (lane & 15);
  if(arow >= N) arow = N - 1;                     // clamp; clamped rows never stored
  f32x4 acc[NCT] = {};
  const short* ap = Abf + (long)arow * K + (lane >> 4) * 8;
  #pragma unroll
  for(int ks = 0; ks < NKS; ++ks){
    bf16x8 a = *(const bf16x8*)(ap + ks * 32);
    #pragma unroll
    for(int ct = 0; ct < NCT; ++ct){
      bf16x8 b = *(const bf16x8*)(Wp + ((ks * NCT + ct) * 64 + lane) * 8);
      acc[ct] = __builtin_amdgcn_mfma_f32_16x16x32_bf16(a, b, acc[ct], 0, 0, 0);
    }
  }
  int r0 = rowbase + (lane >> 4) * 4;             // D: row=(lane>>4)*4+j, col=lane&15
  int c0 = lane & 15;
  #pragma unroll
  for(int j = 0; j < 4; ++j){
    int r = r0 + j;
    if(r < N){
      #pragma unroll
      for(int ct = 0; ct < NCT; ++ct)
        out[(long)r * FOUT + ct * 16 + c0] = acc[ct][j];
    }
  }
}

template<int K, int FOUT>
__global__ void k_pack_w(const float* __restrict__ W, short* __restrict__ Wp){
  constexpr int NKS = K / 32, NCT = FOUT / 16;
  int idx = blockIdx.x * blockDim.x + threadIdx.x;
  if(idx >= NKS * NCT * 64) return;
  int lane = idx & 63;
  int ct = (idx >> 6) % NCT;
  int ks = (idx >> 6) / NCT;
  int col = ct * 16 + (lane & 15);
  int kb  = ks * 32 + (lane >> 4) * 8;
  #pragma unroll
  for(int j = 0; j < 8; ++j) Wp[idx * 8 + j] = f2bf(W[(kb + j) * FOUT + col]);
}

// ======================= layer 1: outer product + dots =======================
__global__ void k_dot128(const float* __restrict__ W1, const float* __restrict__ a1s,
                         const float* __restrict__ a1d, float* __restrict__ S){
  __shared__ float s1[128], s2[128];
  int t = threadIdx.x;
  float w = W1[t];
  s1[t] = w * a1s[t]; s2[t] = w * a1d[t];
  __syncthreads();
  for(int off = 64; off > 0; off >>= 1){
    if(t < off){ s1[t] += s1[t + off]; s2[t] += s2[t + off]; }
    __syncthreads();
  }
  if(t == 0){ S[0] = s1[0]; S[1] = s2[0]; }
}
__global__ void k_l1(const float* __restrict__ x, const float* __restrict__ W1,
                     float* __restrict__ out, int N){
  long idx = (long)blockIdx.x * blockDim.x + threadIdx.x;
  if(idx >= (long)N * 128) return;
  out[idx] = x[idx >> 7] * W1[idx & 127];
}
__global__ void k_l1dots(const float* __restrict__ x, const float* __restrict__ S,
                         float* __restrict__ as_, float* __restrict__ ad_, int N){
  int i = blockIdx.x * blockDim.x + threadIdx.x;
  if(i >= N) return;
  float xv = x[i];
  as_[i] = xv * S[0]; ad_[i] = xv * S[1];
}

// ---- per-node attention dots: as_[i] = h[i,:]·a_s ; ad_[i] = h[i,:]·a_d  (F=128) ----
__global__ void k_attn_dots(const float* __restrict__ h, const float* __restrict__ a_s,
                            const float* __restrict__ a_d, float* __restrict__ outs,
                            float* __restrict__ outd, int N){
  int i = blockIdx.x * blockDim.x + threadIdx.x;
  if(i >= N) return;
  const float4* hp  = (const float4*)(h + (long)i * 128);
  const float4* asp = (const float4*)a_s;
  const float4* adp = (const float4*)a_d;
  float ss = 0.f, sd = 0.f;
  #pragma unroll
  for(int k = 0; k < 32; ++k){
    float4 v = hp[k], xa = asp[k], ya = adp[k];
    ss += v.x*xa.x + v.y*xa.y + v.z*xa.z + v.w*xa.w;
    sd += v.x*ya.x + v.y*ya.y + v.z*ya.z + v.w*ya.w;
  }
  outs[i] = ss; outd[i] = sd;
}

// ======================= CSR build (dst-sorted, with self-loops) =======================
__global__ void k_deg_init(int* __restrict__ deg, int N){
  int i = blockIdx.x * blockDim.x + threadIdx.x;
  if(i < N) deg[i] = 1;
}
__global__ void k_deg_count(const int* __restrict__ ei, int E, int* __restrict__ deg){
  int e = blockIdx.x * blockDim.x + threadIdx.x;
  if(e < E) atomicAdd(&deg[ei[E + e]], 1);
}
__global__ void k_scan(const int* __restrict__ deg, int* __restrict__ rowptr, int N){
  __shared__ int buf[1024];
  __shared__ int carry;
  if(threadIdx.x == 0) carry = 0;
  __syncthreads();
  for(int base = 0; base < N; base += 1024){
    int i = base + threadIdx.x;
    int v = (i < N) ? deg[i] : 0;
    buf[threadIdx.x] = v;
    __syncthreads();
    for(int off = 1; off < 1024; off <<= 1){
      int t = (threadIdx.x >= off) ? buf[threadIdx.x - off] : 0;
      __syncthreads();
      buf[threadIdx.x] += t;
      __syncthreads();
    }
    if(i < N) rowptr[i] = carry + buf[threadIdx.x] - v;
    __syncthreads();
    if(threadIdx.x == 0) carry += buf[1023];
    __syncthreads();
  }
  if(threadIdx.x == 0) rowptr[N] = carry;
}
__global__ void k_copy_i32(const int* __restrict__ src, int* __restrict__ dst, int N){
  int i = blockIdx.x * blockDim.x + threadIdx.x;
  if(i < N) dst[i] = src[i];
}
__global__ void k_fill(const int* __restrict__ ei, int E, int N,
                       int* __restrict__ cursor, int* __restrict__ csr_src){
  int e = blockIdx.x * blockDim.x + threadIdx.x;
  if(e >= E + N) return;
  int s, d;
  if(e < E){ s = ei[e]; d = ei[E + e]; } else { s = e - E; d = s; }
  int pos = atomicAdd(&cursor[d], 1);
  csr_src[pos] = s;
}
__global__ void k_dinv(const int* __restrict__ deg, float* __restrict__ dinv, int N){
  int i = blockIdx.x * blockDim.x + threadIdx.x;
  if(i < N) dinv[i] = rsqrtf((float)deg[i]);
}

// ======================= fused GAT aggregation: one wave per dst, bf16 out =======================
__global__ void k_gat_agg(const int* __restrict__ rowptr, const int* __restrict__ csr_src,
                          const float* __restrict__ as_, const float* __restrict__ ad_,
                          const float* __restrict__ h, const float* __restrict__ bias,
                          short* __restrict__ out_bf, int N){
  int w = (int)(((long)blockIdx.x * blockDim.x + threadIdx.x) >> 6);
  int lane = threadIdx.x & 63;
  if(w >= N) return;
  int start = rowptr[w], end = rowptr[w + 1];
  float add = ad_[w];

  float m = -INFINITY, ssum = 0.f;
  for(int e = start + lane; e < end; e += 64){
    int s = csr_src[e];
    float l = lrelu(as_[s] + add);
    if(l > m){ ssum = ssum * expf(m - l) + 1.f; m = l; }
    else       ssum += expf(l - m);
  }
  #pragma unroll
  for(int off = 32; off > 0; off >>= 1){
    float mo = __shfl_xor(m, off);
    float so = __shfl_xor(ssum, off);
    float mn = fmaxf(m, mo);
    float ea = (m  > -INFINITY) ? expf(m  - mn) : 0.f;
    float eb = (mo > -INFINITY) ? expf(mo - mn) : 0.f;
    ssum = ssum * ea + so * eb;
    m = mn;
  }
  float inv = 1.f / (ssum + 1e-16f);

  float acc0 = 0.f, acc1 = 0.f;
  for(int e = start; e < end; ++e){
    int s = csr_src[e];
    float l = lrelu(as_[s] + add);
    float alpha = expf(l - m) * inv;
    const float* hr = h + (long)s * 128;
    acc0 = fmaf(alpha, hr[lane],      acc0);
    acc1 = fmaf(alpha, hr[lane + 64], acc1);
  }
  out_bf[(long)w * 128 + lane]      = f2bf(eluf(acc0 + bias[lane]));
  out_bf[(long)w * 128 + lane + 64] = f2bf(eluf(acc1 + bias[lane + 64]));
}

// ======================= fused GCN aggregation: one wave per dst =======================
template<int F, bool BFOUT>
__global__ void k_gcn_agg(const int* __restrict__ rowptr, const int* __restrict__ csr_src,
                          const float* __restrict__ dinv, const float* __restrict__ h,
                          const float* __restrict__ bias, short* __restrict__ out_bf,
                          float* __restrict__ out_f, int N){
  int w = (int)(((long)blockIdx.x * blockDim.x + threadIdx.x) >> 6);
  int lane = threadIdx.x & 63;
  if(w >= N) return;
  int start = rowptr[w], end = rowptr[w + 1];
  float dd = dinv[w];
  float acc = 0.f;
  for(int e = start; e < end; ++e){
    int s = csr_src[e];
    float nrm = dd * dinv[s];
    if(lane < F) acc = fmaf(nrm, h[(long)s * F + lane], acc);
  }
  if(lane < F){
    float v = eluf(acc + bias[lane]);
    if(BFOUT) out_bf[(long)w * F + lane] = f2bf(v);
    else      out_f [(long)w * F + lane] = v;
  }
}

// ============ per-graph softmax aggregation: one block per graph (batch sorted) ============
__global__ void k_batch_agg(const float* __restrict__ h, const int* __restrict__ batch,
                            const float* __restrict__ t, float* __restrict__ g, int N){
  int b = blockIdx.x;
  __shared__ int s_lo, s_hi;
  __shared__ float red[8][32];
  if(threadIdx.x == 0){
    int lo = 0, hi = N;
    while(lo < hi){ int mid = (lo + hi) >> 1; if(batch[mid] < b) lo = mid + 1; else hi = mid; }
    s_lo = lo;
    int lo2 = lo, hi2 = N;
    while(lo2 < hi2){ int mid = (lo2 + hi2) >> 1; if(batch[mid] < b + 1) lo2 = mid + 1; else hi2 = mid; }
    s_hi = lo2;
  }
  __syncthreads();
  int lo = s_lo, hi = s_hi;
  float tv = t[0];
  int c = threadIdx.x & 31, r = threadIdx.x >> 5;

  float m = -INFINITY;
  for(int i = lo + r; i < hi; i += 8) m = fmaxf(m, h[(long)i * 32 + c] * tv);
  red[r][c] = m; __syncthreads();
  if(r == 0){
    float mm = red[0][c];
    #pragma unroll
    for(int k = 1; k < 8; ++k) mm = fmaxf(mm, red[k][c]);
    red[0][c] = (mm == -INFINITY) ? 0.f : mm;
  }
  __syncthreads();
  m = red[0][c];
  __syncthreads();

  float ssum = 0.f;
  for(int i = lo + r; i < hi; i += 8) ssum += expf(h[(long)i * 32 + c] * tv - m);
  red[r][c] = ssum; __syncthreads();
  if(r == 0){
    float tot = red[0][c];
    #pragma unroll
    for(int k = 1; k < 8; ++k) tot += red[k][c];
    red[0][c] = tot;
  }
  __syncthreads();
  float inv = 1.f / (red[0][c] + 1e-16f);
  __syncthreads();

  float acc = 0.f;
  for(int i = lo + r; i < hi; i += 8){
    float hv = h[(long)i * 32 + c];
    acc += expf(hv * tv - m) * inv * hv;
  }
  red[r][c] = acc; __syncthreads();
  if(r == 0){
    float tot = red[0][c];
    #pragma unroll
    for(int k = 1; k < 8; ++k) tot += red[k][c];
    g[b * 32 + c] = tot;
  }
}

// ---- heads ----
__global__ void k_head(const float* __restrict__ g, const float* __restrict__ Wl1,
                       const float* __restrict__ bl1, const float* __restrict__ Wl2,
                       const float* __restrict__ bl2, float* __restrict__ out, int B){
  int b = blockIdx.x * blockDim.x + threadIdx.x;
  if(b >= B) return;
  float gr[32];
  #pragma unroll
  for(int k = 0; k < 32; ++k) gr[k] = g[b * 32 + k];
  float h1[16];
  #pragma unroll
  for(int j = 0; j < 16; ++j){
    float acc = bl1[j];
    #pragma unroll
    for(int k = 0; k < 32; ++k) acc = fmaf(gr[k], Wl1[k * 16 + j], acc);
    h1[j] = eluf(acc);
  }
  float l0 = bl2[0], l1 = bl2[1];
  #pragma unroll
  for(int k = 0; k < 16; ++k){
    l0 = fmaf(h1[k], Wl2[k * 2 + 0], l0);
    l1 = fmaf(h1[k], Wl2[k * 2 + 1], l1);
  }
  float mx = fmaxf(l0, l1);
  float lse = mx + logf(expf(l0 - mx) + expf(l1 - mx));
  out[b * 2 + 0] = l0 - lse;
  out[b * 2 + 1] = l1 - lse;
}

extern "C" void kernel_launch(void* const* d_in, const int* in_sizes, int n_in,
                              void* d_out, int out_size, void* d_ws, size_t ws_size,
                              hipStream_t stream){
  const float* x     = (const float*)d_in[0];
  const int*   ei    = (const int*)d_in[1];
  const int*   batch = (const int*)d_in[2];
  const float* W1 = (const float*)d_in[3];
  const float* a1s = (const float*)d_in[4];
  const float* a1d = (const float*)d_in[5];
  const float* b1 = (const float*)d_in[6];
  const float* W2 = (const float*)d_in[7];
  const float* a2s = (const float*)d_in[8];
  const float* a2d = (const float*)d_in[9];
  const float* b2 = (const float*)d_in[10];
  const float* W3 = (const float*)d_in[11];
  const float* a3s = (const float*)d_in[12];
  const float* a3d = (const float*)d_in[13];
  const float* b3 = (const float*)d_in[14];
  const float* Wg1 = (const float*)d_in[15];
  const float* bg1 = (const float*)d_in[16];
  const float* Wg2 = (const float*)d_in[17];
  const float* bg2 = (const float*)d_in[18];
  const float* t   = (const float*)d_in[19];
  const float* Wl1 = (const float*)d_in[20];
  const float* bl1 = (const float*)d_in[21];
  const float* Wl2 = (const float*)d_in[22];
  const float* bl2 = (const float*)d_in[23];

  const int N = in_sizes[0];
  const int E = in_sizes[1] / 2;
  const int B = out_size / 2;
  const int ET = E + N;
  float* out = (float*)d_out;

  // ---- workspace layout (16B-aligned partitions) ----
  char* p = (char*)d_ws;
  float* Bf   = (float*)p;            p += (size_t)N * 128 * 4;   // gemm out (fp32)
  short* Abf  = (short*)p;            p += (size_t)N * 128 * 2;   // activations (bf16)
  float* A32  = (float*)p;            p += (size_t)N * 32 * 4;    // final GCN out (fp32)
  float* as_  = (float*)p;            p += (size_t)N * 4;
  float* ad_  = (float*)p;            p += (size_t)N * 4;
  float* dinv = (float*)p;            p += (size_t)N * 4;
  int*   deg    = (int*)p;            p += (size_t)N * 4;
  int*   rowptr = (int*)p;            p += (size_t)(N + 1) * 4;
  int*   cursor = (int*)p;            p += (size_t)N * 4;
  int*   csr    = (int*)p;            p += (size_t)ET * 4;
  p = alignp(p, 16);
  short* Wp2  = (short*)p;            p += 128 * 128 * 2;
  short* Wp3  = (short*)p;            p += 128 * 128 * 2;
  short* Wpg1 = (short*)p;            p += 128 * 64 * 2;
  short* Wpg2 = (short*)p;            p += 64 * 32 * 2;
  p = alignp(p, 16);
  float* S    = (float*)p;            p += 16 * 4;
  float* g    = (float*)p;

  const int T = 256;
  const int gN  = cdiv(N, T);
  const int gE  = cdiv(E, T);
  const int gET = cdiv(ET, T);
  const int gW  = cdiv((long)N * 64, T);         // wave-per-dst grids
  const int gG  = cdiv(N, 64);                   // mfma gemm: 64 rows/block

  // ---------- CSR build + weight packs (independent prep) ----------
  k_deg_init<<<dim3(gN), dim3(T), 0, stream>>>(deg, N);
  k_deg_count<<<dim3(gE), dim3(T), 0, stream>>>(ei, E, deg);
  k_scan<<<dim3(1), dim3(1024), 0, stream>>>(deg, rowptr, N);
  k_copy_i32<<<dim3(gN), dim3(T), 0, stream>>>(rowptr, cursor, N);
  k_fill<<<dim3(gET), dim3(T), 0, stream>>>(ei, E, N, cursor, csr);
  k_dinv<<<dim3(gN), dim3(T), 0, stream>>>(deg, dinv, N);
  k_pack_w<128,128><<<dim3(8), dim3(T), 0, stream>>>(W2, Wp2);
  k_pack_w<128,128><<<dim3(8), dim3(T), 0, stream>>>(W3, Wp3);
  k_pack_w<128, 64><<<dim3(4), dim3(T), 0, stream>>>(Wg1, Wpg1);
  k_pack_w< 64, 32><<<dim3(1), dim3(T), 0, stream>>>(Wg2, Wpg2);
  k_dot128<<<dim3(1), dim3(128), 0, stream>>>(W1, a1s, a1d, S);

  // ---------- GAT layer 1 (1 -> 128): outer product ----------
  k_l1<<<dim3(cdiv((long)N * 128, T)), dim3(T), 0, stream>>>(x, W1, Bf, N);
  k_l1dots<<<dim3(gN), dim3(T), 0, stream>>>(x, S, as_, ad_, N);
  k_gat_agg<<<dim3(gW), dim3(T), 0, stream>>>(rowptr, csr, as_, ad_, Bf, b1, Abf, N);

  // ---------- GAT layer 2 (128 -> 128) ----------
  k_gemm_mfma<128,128><<<dim3(gG), dim3(T), 0, stream>>>(Abf, Wp2, Bf, N);
  k_attn_dots<<<dim3(gN), dim3(T), 0, stream>>>(Bf, a2s, a2d, as_, ad_, N);
  k_gat_agg<<<dim3(gW), dim3(T), 0, stream>>>(rowptr, csr, as_, ad_, Bf, b2, Abf, N);

  // ---------- GAT layer 3 (128 -> 128) ----------
  k_gemm_mfma<128,128><<<dim3(gG), dim3(T), 0, stream>>>(Abf, Wp3, Bf, N);
  k_attn_dots<<<dim3(gN), dim3(T), 0, stream>>>(Bf, a3s, a3d, as_, ad_, N);
  k_gat_agg<<<dim3(gW), dim3(T), 0, stream>>>(rowptr, csr, as_, ad_, Bf, b3, Abf, N);

  // ---------- GCN layer 1 (128 -> 64) ----------
  k_gemm_mfma<128,64><<<dim3(gG), dim3(T), 0, stream>>>(Abf, Wpg1, Bf, N);
  k_gcn_agg<64,true><<<dim3(gW), dim3(T), 0, stream>>>(rowptr, csr, dinv, Bf, bg1, Abf, (float*)nullptr, N);

  // ---------- GCN layer 2 (64 -> 32) ----------
  k_gemm_mfma<64,32><<<dim3(gG), dim3(T), 0, stream>>>(Abf, Wpg2, Bf, N);
  k_gcn_agg<32,false><<<dim3(gW), dim3(T), 0, stream>>>(rowptr, csr, dinv, Bf, bg2, (short*)nullptr, A32, N);

  // ---------- per-graph softmax aggregation ----------
  k_batch_agg<<<dim3(B), dim3(T), 0, stream>>>(A32, batch, t, g, N);

  // ---------- MLP heads + log_softmax ----------
  k_head<<<dim3(cdiv(B, 64)), dim3(64), 0, stream>>>(g, Wl1, bl1, Wl2, bl2, out, B);
}

// Round 4
// 548.928 us; speedup vs baseline: 3.7874x; 1.2607x over previous
//
#include <hip/hip_runtime.h>
#include <math.h>

static inline int cdiv(long a, long b){ return (int)((a + b - 1) / b); }
static inline char* alignp(char* p, size_t a){ return (char*)(((uintptr_t)p + a - 1) & ~(uintptr_t)(a - 1)); }

typedef __attribute__((ext_vector_type(8))) short bf16x8;
typedef __attribute__((ext_vector_type(4))) float f32x4;

__device__ __forceinline__ float lrelu(float x){ return x > 0.f ? x : 0.2f * x; }
__device__ __forceinline__ float eluf(float x){ return x > 0.f ? x : expm1f(x); }
__device__ __forceinline__ short f2bf(float f){            // RNE f32 -> bf16 bits
  unsigned u = __float_as_uint(f);
  return (short)((u + 0x7FFFu + ((u >> 16) & 1u)) >> 16);
}
__device__ __forceinline__ float bflo(unsigned v){ return __uint_as_float(v << 16); }
__device__ __forceinline__ float bfhi(unsigned v){ return __uint_as_float(v & 0xFFFF0000u); }

// ======================= MFMA GEMM: outb[N,FOUT](bf16) = Abf[N,K] @ W[K,FOUT] =======================
// Optional fused attention dots: as_[r] = h[r,:]·av_s ; ad_[r] = h[r,:]·av_d
template<int K, int FOUT, bool DOTS>
__global__ void k_gemm_mfma(const short* __restrict__ Abf, const short* __restrict__ Wp,
                            short* __restrict__ outb,
                            const float* __restrict__ av_s, const float* __restrict__ av_d,
                            float* __restrict__ as_, float* __restrict__ ad_, int N){
  constexpr int NKS = K / 32, NCT = FOUT / 16;
  int wid  = threadIdx.x >> 6;
  int lane = threadIdx.x & 63;
  int rowbase = (blockIdx.x * 4 + wid) * 16;
  if(rowbase >= N) return;
  int arow = rowbase + (lane & 15);
  if(arow >= N) arow = N - 1;                     // clamp; clamped rows never stored
  f32x4 acc[NCT] = {};
  const short* ap = Abf + (long)arow * K + (lane >> 4) * 8;
  #pragma unroll
  for(int ks = 0; ks < NKS; ++ks){
    bf16x8 a = *(const bf16x8*)(ap + ks * 32);
    #pragma unroll
    for(int ct = 0; ct < NCT; ++ct){
      bf16x8 b = *(const bf16x8*)(Wp + ((ks * NCT + ct) * 64 + lane) * 8);
      acc[ct] = __builtin_amdgcn_mfma_f32_16x16x32_bf16(a, b, acc[ct], 0, 0, 0);
    }
  }
  int r0 = rowbase + (lane >> 4) * 4;             // D: row=(lane>>4)*4+j, col=lane&15
  int c0 = lane & 15;
  #pragma unroll
  for(int j = 0; j < 4; ++j){
    int r = r0 + j;
    if(r < N){
      #pragma unroll
      for(int ct = 0; ct < NCT; ++ct)
        outb[(long)r * FOUT + ct * 16 + c0] = f2bf(acc[ct][j]);
    }
  }
  if(DOTS){
    float avs[NCT], avd[NCT];
    #pragma unroll
    for(int ct = 0; ct < NCT; ++ct){ avs[ct] = av_s[ct * 16 + c0]; avd[ct] = av_d[ct * 16 + c0]; }
    #pragma unroll
    for(int j = 0; j < 4; ++j){
      float ps = 0.f, pd = 0.f;
      #pragma unroll
      for(int ct = 0; ct < NCT; ++ct){
        float hv = acc[ct][j];
        ps = fmaf(hv, avs[ct], ps);
        pd = fmaf(hv, avd[ct], pd);
      }
      #pragma unroll
      for(int off = 1; off < 16; off <<= 1){
        ps += __shfl_xor(ps, off);
        pd += __shfl_xor(pd, off);
      }
      int r = r0 + j;
      if(c0 == 0 && r < N){ as_[r] = ps; ad_[r] = pd; }
    }
  }
}

template<int K, int FOUT>
__global__ void k_pack_w(const float* __restrict__ W, short* __restrict__ Wp){
  constexpr int NKS = K / 32, NCT = FOUT / 16;
  int idx = blockIdx.x * blockDim.x + threadIdx.x;
  if(idx >= NKS * NCT * 64) return;
  int lane = idx & 63;
  int ct = (idx >> 6) % NCT;
  int ks = (idx >> 6) / NCT;
  int col = ct * 16 + (lane & 15);
  int kb  = ks * 32 + (lane >> 4) * 8;
  #pragma unroll
  for(int j = 0; j < 8; ++j) Wp[idx * 8 + j] = f2bf(W[(kb + j) * FOUT + col]);
}

// ======================= layer 1: outer product + dots =======================
__global__ void k_dot128(const float* __restrict__ W1, const float* __restrict__ a1s,
                         const float* __restrict__ a1d, float* __restrict__ S){
  __shared__ float s1[128], s2[128];
  int t = threadIdx.x;
  float w = W1[t];
  s1[t] = w * a1s[t]; s2[t] = w * a1d[t];
  __syncthreads();
  for(int off = 64; off > 0; off >>= 1){
    if(t < off){ s1[t] += s1[t + off]; s2[t] += s2[t + off]; }
    __syncthreads();
  }
  if(t == 0){ S[0] = s1[0]; S[1] = s2[0]; }
}
__global__ void k_l1(const float* __restrict__ x, const float* __restrict__ W1,
                     short* __restrict__ outb, int N){
  long idx = (long)blockIdx.x * blockDim.x + threadIdx.x;
  if(idx >= (long)N * 128) return;
  outb[idx] = f2bf(x[idx >> 7] * W1[idx & 127]);
}
__global__ void k_l1dots(const float* __restrict__ x, const float* __restrict__ S,
                         float* __restrict__ as_, float* __restrict__ ad_, int N){
  int i = blockIdx.x * blockDim.x + threadIdx.x;
  if(i >= N) return;
  float xv = x[i];
  as_[i] = xv * S[0]; ad_[i] = xv * S[1];
}

// ======================= CSR build (dst-sorted, with self-loops) =======================
__global__ void k_deg_init(int* __restrict__ deg, int N){
  int i = blockIdx.x * blockDim.x + threadIdx.x;
  if(i < N) deg[i] = 1;
}
__global__ void k_deg_count(const int* __restrict__ ei, int E, int* __restrict__ deg){
  int e = blockIdx.x * blockDim.x + threadIdx.x;
  if(e < E) atomicAdd(&deg[ei[E + e]], 1);
}
// chunk-per-thread exclusive scan, single block of 1024; also emits cursor copy
__global__ void k_scan(const int* __restrict__ deg, int* __restrict__ rowptr,
                       int* __restrict__ cursor, int N){
  __shared__ int sums[1024];
  int t = threadIdx.x;
  int C = (N + 1023) >> 10;
  int lo = t * C, hi = lo + C; if(hi > N) hi = N;
  int s = 0;
  for(int i = lo; i < hi; ++i) s += deg[i];
  sums[t] = s;
  __syncthreads();
  for(int off = 1; off < 1024; off <<= 1){
    int v = (t >= off) ? sums[t - off] : 0;
    __syncthreads();
    sums[t] += v;
    __syncthreads();
  }
  int prefix = (t == 0) ? 0 : sums[t - 1];
  for(int i = lo; i < hi; ++i){
    rowptr[i] = prefix; cursor[i] = prefix;
    prefix += deg[i];
  }
  if(t == 1023) rowptr[N] = prefix;
}
__global__ void k_fill(const int* __restrict__ ei, int E, int N,
                       int* __restrict__ cursor, int* __restrict__ csr_src){
  int e = blockIdx.x * blockDim.x + threadIdx.x;
  if(e >= E + N) return;
  int s, d;
  if(e < E){ s = ei[e]; d = ei[E + e]; } else { s = e - E; d = s; }
  int pos = atomicAdd(&cursor[d], 1);
  csr_src[pos] = s;
}
__global__ void k_dinv(const int* __restrict__ deg, float* __restrict__ dinv, int N){
  int i = blockIdx.x * blockDim.x + threadIdx.x;
  if(i < N) dinv[i] = rsqrtf((float)deg[i]);
}

// ======================= fused GAT aggregation: one wave per dst, bf16 h =======================
__global__ void k_gat_agg(const int* __restrict__ rowptr, const int* __restrict__ csr,
                          const float* __restrict__ as_, const float* __restrict__ ad_,
                          const short* __restrict__ h, const float* __restrict__ bias,
                          short* __restrict__ out, int N){
  int w = (int)(((long)blockIdx.x * blockDim.x + threadIdx.x) >> 6);
  int lane = threadIdx.x & 63;
  if(w >= N) return;
  int start = rowptr[w], end = rowptr[w + 1];
  int deg = end - start;
  float add = ad_[w];

  // phase A: lane l caches edge start+l (src, logit); online (max,expsum) incl. strided tail
  int s_reg = 0; float logit = -INFINITY;
  float m = -INFINITY, ssum = 0.f;
  if(lane < deg){
    s_reg = csr[start + lane];
    logit = lrelu(as_[s_reg] + add);
    m = logit; ssum = 1.f;
    for(int e = start + lane + 64; e < end; e += 64){
      int s = csr[e];
      float l = lrelu(as_[s] + add);
      if(l > m){ ssum = ssum * __expf(m - l) + 1.f; m = l; }
      else       ssum += __expf(l - m);
    }
  }
  #pragma unroll
  for(int off = 32; off > 0; off >>= 1){
    float mo = __shfl_xor(m, off);
    float so = __shfl_xor(ssum, off);
    float mn = fmaxf(m, mo);
    float ea = (m  > -INFINITY) ? __expf(m  - mn) : 0.f;
    float eb = (mo > -INFINITY) ? __expf(mo - mn) : 0.f;
    ssum = ssum * ea + so * eb;
    m = mn;
  }
  float inv = 1.f / (ssum + 1e-16f);
  float alpha_reg = __expf(logit - m) * inv;      // -INF logit -> 0

  // phase B: shfl-driven; lane covers features {2*lane, 2*lane+1}
  float acc0 = 0.f, acc1 = 0.f;
  int nb = deg < 64 ? deg : 64;
  for(int k = 0; k < nb; ++k){
    float a = __shfl(alpha_reg, k);
    int s   = __shfl(s_reg, k);
    unsigned hv = *(const unsigned*)(h + (long)s * 128 + lane * 2);
    acc0 = fmaf(a, bflo(hv), acc0);
    acc1 = fmaf(a, bfhi(hv), acc1);
  }
  for(int e = start + 64; e < end; ++e){          // rare overflow path
    int s = csr[e];
    float l = lrelu(as_[s] + add);
    float a = __expf(l - m) * inv;
    unsigned hv = *(const unsigned*)(h + (long)s * 128 + lane * 2);
    acc0 = fmaf(a, bflo(hv), acc0);
    acc1 = fmaf(a, bfhi(hv), acc1);
  }
  float2 bv = *(const float2*)(bias + lane * 2);
  out[(long)w * 128 + lane * 2]     = f2bf(eluf(acc0 + bv.x));
  out[(long)w * 128 + lane * 2 + 1] = f2bf(eluf(acc1 + bv.y));
}

// ======================= fused GCN aggregation: one wave per dst, bf16 h =======================
template<int F, bool BFOUT>
__global__ void k_gcn_agg(const int* __restrict__ rowptr, const int* __restrict__ csr,
                          const float* __restrict__ dinv, const short* __restrict__ h,
                          const float* __restrict__ bias, short* __restrict__ out_bf,
                          float* __restrict__ out_f, int N){
  int w = (int)(((long)blockIdx.x * blockDim.x + threadIdx.x) >> 6);
  int lane = threadIdx.x & 63;
  if(w >= N) return;
  int start = rowptr[w], end = rowptr[w + 1];
  int deg = end - start;
  float dd = dinv[w];
  int s_reg = 0; float dv_reg = 0.f;
  if(lane < deg){
    s_reg = csr[start + lane];
    dv_reg = dinv[s_reg];
  }
  float acc = 0.f;
  int nb = deg < 64 ? deg : 64;
  for(int k = 0; k < nb; ++k){
    int s = __shfl(s_reg, k);
    float nrm = dd * __shfl(dv_reg, k);
    if(lane < F){
      unsigned short hb = *(const unsigned short*)(h + (long)s * F + lane);
      acc = fmaf(nrm, bflo(hb), acc);
    }
  }
  for(int e = start + 64; e < end; ++e){
    int s = csr[e];
    float nrm = dd * dinv[s];
    if(lane < F){
      unsigned short hb = *(const unsigned short*)(h + (long)s * F + lane);
      acc = fmaf(nrm, bflo(hb), acc);
    }
  }
  if(lane < F){
    float v = eluf(acc + bias[lane]);
    if(BFOUT) out_bf[(long)w * F + lane] = f2bf(v);
    else      out_f [(long)w * F + lane] = v;
  }
}

// ============ per-graph softmax aggregation: one block per graph (batch sorted) ============
__global__ void k_batch_agg(const float* __restrict__ h, const int* __restrict__ batch,
                            const float* __restrict__ t, float* __restrict__ g, int N){
  int b = blockIdx.x;
  __shared__ int s_lo, s_hi;
  __shared__ float red[8][32];
  if(threadIdx.x == 0){
    int lo = 0, hi = N;
    while(lo < hi){ int mid = (lo + hi) >> 1; if(batch[mid] < b) lo = mid + 1; else hi = mid; }
    s_lo = lo;
    int lo2 = lo, hi2 = N;
    while(lo2 < hi2){ int mid = (lo2 + hi2) >> 1; if(batch[mid] < b + 1) lo2 = mid + 1; else hi2 = mid; }
    s_hi = lo2;
  }
  __syncthreads();
  int lo = s_lo, hi = s_hi;
  float tv = t[0];
  int c = threadIdx.x & 31, r = threadIdx.x >> 5;

  float m = -INFINITY;
  for(int i = lo + r; i < hi; i += 8) m = fmaxf(m, h[(long)i * 32 + c] * tv);
  red[r][c] = m; __syncthreads();
  if(r == 0){
    float mm = red[0][c];
    #pragma unroll
    for(int k = 1; k < 8; ++k) mm = fmaxf(mm, red[k][c]);
    red[0][c] = (mm == -INFINITY) ? 0.f : mm;
  }
  __syncthreads();
  m = red[0][c];
  __syncthreads();

  float ssum = 0.f;
  for(int i = lo + r; i < hi; i += 8) ssum += __expf(h[(long)i * 32 + c] * tv - m);
  red[r][c] = ssum; __syncthreads();
  if(r == 0){
    float tot = red[0][c];
    #pragma unroll
    for(int k = 1; k < 8; ++k) tot += red[k][c];
    red[0][c] = tot;
  }
  __syncthreads();
  float inv = 1.f / (red[0][c] + 1e-16f);
  __syncthreads();

  float acc = 0.f;
  for(int i = lo + r; i < hi; i += 8){
    float hv = h[(long)i * 32 + c];
    acc += __expf(hv * tv - m) * inv * hv;
  }
  red[r][c] = acc; __syncthreads();
  if(r == 0){
    float tot = red[0][c];
    #pragma unroll
    for(int k = 1; k < 8; ++k) tot += red[k][c];
    g[b * 32 + c] = tot;
  }
}

// ---- heads ----
__global__ void k_head(const float* __restrict__ g, const float* __restrict__ Wl1,
                       const float* __restrict__ bl1, const float* __restrict__ Wl2,
                       const float* __restrict__ bl2, float* __restrict__ out, int B){
  int b = blockIdx.x * blockDim.x + threadIdx.x;
  if(b >= B) return;
  float gr[32];
  #pragma unroll
  for(int k = 0; k < 32; ++k) gr[k] = g[b * 32 + k];
  float h1[16];
  #pragma unroll
  for(int j = 0; j < 16; ++j){
    float acc = bl1[j];
    #pragma unroll
    for(int k = 0; k < 32; ++k) acc = fmaf(gr[k], Wl1[k * 16 + j], acc);
    h1[j] = eluf(acc);
  }
  float l0 = bl2[0], l1 = bl2[1];
  #pragma unroll
  for(int k = 0; k < 16; ++k){
    l0 = fmaf(h1[k], Wl2[k * 2 + 0], l0);
    l1 = fmaf(h1[k], Wl2[k * 2 + 1], l1);
  }
  float mx = fmaxf(l0, l1);
  float lse = mx + __logf(__expf(l0 - mx) + __expf(l1 - mx));
  out[b * 2 + 0] = l0 - lse;
  out[b * 2 + 1] = l1 - lse;
}

extern "C" void kernel_launch(void* const* d_in, const int* in_sizes, int n_in,
                              void* d_out, int out_size, void* d_ws, size_t ws_size,
                              hipStream_t stream){
  const float* x     = (const float*)d_in[0];
  const int*   ei    = (const int*)d_in[1];
  const int*   batch = (const int*)d_in[2];
  const float* W1 = (const float*)d_in[3];
  const float* a1s = (const float*)d_in[4];
  const float* a1d = (const float*)d_in[5];
  const float* b1 = (const float*)d_in[6];
  const float* W2 = (const float*)d_in[7];
  const float* a2s = (const float*)d_in[8];
  const float* a2d = (const float*)d_in[9];
  const float* b2 = (const float*)d_in[10];
  const float* W3 = (const float*)d_in[11];
  const float* a3s = (const float*)d_in[12];
  const float* a3d = (const float*)d_in[13];
  const float* b3 = (const float*)d_in[14];
  const float* Wg1 = (const float*)d_in[15];
  const float* bg1 = (const float*)d_in[16];
  const float* Wg2 = (const float*)d_in[17];
  const float* bg2 = (const float*)d_in[18];
  const float* t   = (const float*)d_in[19];
  const float* Wl1 = (const float*)d_in[20];
  const float* bl1 = (const float*)d_in[21];
  const float* Wl2 = (const float*)d_in[22];
  const float* bl2 = (const float*)d_in[23];

  const int N = in_sizes[0];
  const int E = in_sizes[1] / 2;
  const int B = out_size / 2;
  const int ET = E + N;
  float* out = (float*)d_out;

  // ---- workspace layout ----
  char* p = (char*)d_ws;
  short* Hbf  = (short*)p;            p += (size_t)N * 128 * 2;   // gemm/layer out (bf16)
  short* Abf  = (short*)p;            p += (size_t)N * 128 * 2;   // agg out (bf16)
  float* A32  = (float*)p;            p += (size_t)N * 32 * 4;    // final GCN out (fp32)
  float* as_  = (float*)p;            p += (size_t)N * 4;
  float* ad_  = (float*)p;            p += (size_t)N * 4;
  float* dinv = (float*)p;            p += (size_t)N * 4;
  int*   deg    = (int*)p;            p += (size_t)N * 4;
  int*   rowptr = (int*)p;            p += (size_t)(N + 1) * 4;
  int*   cursor = (int*)p;            p += (size_t)N * 4;
  int*   csr    = (int*)p;            p += (size_t)ET * 4;
  p = alignp(p, 16);
  short* Wp2  = (short*)p;            p += 128 * 128 * 2;
  short* Wp3  = (short*)p;            p += 128 * 128 * 2;
  short* Wpg1 = (short*)p;            p += 128 * 64 * 2;
  short* Wpg2 = (short*)p;            p += 64 * 32 * 2;
  p = alignp(p, 16);
  float* S    = (float*)p;            p += 16 * 4;
  float* g    = (float*)p;

  const int T = 256;
  const int gN  = cdiv(N, T);
  const int gE  = cdiv(E, T);
  const int gET = cdiv(ET, T);
  const int gW  = cdiv((long)N * 64, T);         // wave-per-dst grids
  const int gG  = cdiv(N, 64);                   // mfma gemm: 64 rows/block

  // ---------- CSR build + weight packs ----------
  k_deg_init<<<dim3(gN), dim3(T), 0, stream>>>(deg, N);
  k_deg_count<<<dim3(gE), dim3(T), 0, stream>>>(ei, E, deg);
  k_scan<<<dim3(1), dim3(1024), 0, stream>>>(deg, rowptr, cursor, N);
  k_fill<<<dim3(gET), dim3(T), 0, stream>>>(ei, E, N, cursor, csr);
  k_dinv<<<dim3(gN), dim3(T), 0, stream>>>(deg, dinv, N);
  k_pack_w<128,128><<<dim3(8), dim3(T), 0, stream>>>(W2, Wp2);
  k_pack_w<128,128><<<dim3(8), dim3(T), 0, stream>>>(W3, Wp3);
  k_pack_w<128, 64><<<dim3(4), dim3(T), 0, stream>>>(Wg1, Wpg1);
  k_pack_w< 64, 32><<<dim3(1), dim3(T), 0, stream>>>(Wg2, Wpg2);
  k_dot128<<<dim3(1), dim3(128), 0, stream>>>(W1, a1s, a1d, S);

  // ---------- GAT layer 1 (1 -> 128): outer product ----------
  k_l1<<<dim3(cdiv((long)N * 128, T)), dim3(T), 0, stream>>>(x, W1, Hbf, N);
  k_l1dots<<<dim3(gN), dim3(T), 0, stream>>>(x, S, as_, ad_, N);
  k_gat_agg<<<dim3(gW), dim3(T), 0, stream>>>(rowptr, csr, as_, ad_, Hbf, b1, Abf, N);

  // ---------- GAT layer 2 (128 -> 128) ----------
  k_gemm_mfma<128,128,true><<<dim3(gG), dim3(T), 0, stream>>>(Abf, Wp2, Hbf, a2s, a2d, as_, ad_, N);
  k_gat_agg<<<dim3(gW), dim3(T), 0, stream>>>(rowptr, csr, as_, ad_, Hbf, b2, Abf, N);

  // ---------- GAT layer 3 (128 -> 128) ----------
  k_gemm_mfma<128,128,true><<<dim3(gG), dim3(T), 0, stream>>>(Abf, Wp3, Hbf, a3s, a3d, as_, ad_, N);
  k_gat_agg<<<dim3(gW), dim3(T), 0, stream>>>(rowptr, csr, as_, ad_, Hbf, b3, Abf, N);

  // ---------- GCN layer 1 (128 -> 64) ----------
  k_gemm_mfma<128,64,false><<<dim3(gG), dim3(T), 0, stream>>>(Abf, Wpg1, Hbf, nullptr, nullptr, nullptr, nullptr, N);
  k_gcn_agg<64,true><<<dim3(gW), dim3(T), 0, stream>>>(rowptr, csr, dinv, Hbf, bg1, Abf, (float*)nullptr, N);

  // ---------- GCN layer 2 (64 -> 32) ----------
  k_gemm_mfma<64,32,false><<<dim3(gG), dim3(T), 0, stream>>>(Abf, Wpg2, Hbf, nullptr, nullptr, nullptr, nullptr, N);
  k_gcn_agg<32,false><<<dim3(gW), dim3(T), 0, stream>>>(rowptr, csr, dinv, Hbf, bg2, (short*)nullptr, A32, N);

  // ---------- per-graph softmax aggregation ----------
  k_batch_agg<<<dim3(B), dim3(T), 0, stream>>>(A32, batch, t, g, N);

  // ---------- MLP heads + log_softmax ----------
  k_head<<<dim3(cdiv(B, 64)), dim3(64), 0, stream>>>(g, Wl1, bl1, Wl2, bl2, out, B);
}

// Round 5
// 450.097 us; speedup vs baseline: 4.6190x; 1.2196x over previous
//
#include <hip/hip_runtime.h>
#include <math.h>

static inline int cdiv(long a, long b){ return (int)((a + b - 1) / b); }
static inline char* alignp(char* p, size_t a){ return (char*)(((uintptr_t)p + a - 1) & ~(uintptr_t)(a - 1)); }

typedef __attribute__((ext_vector_type(8))) short bf16x8;
typedef __attribute__((ext_vector_type(4))) float f32x4;

__device__ __forceinline__ float lrelu(float x){ return x > 0.f ? x : 0.2f * x; }
__device__ __forceinline__ float eluf(float x){ return x > 0.f ? x : expm1f(x); }
__device__ __forceinline__ short f2bf(float f){            // RNE f32 -> bf16 bits
  unsigned u = __float_as_uint(f);
  return (short)((u + 0x7FFFu + ((u >> 16) & 1u)) >> 16);
}
__device__ __forceinline__ float bflo(unsigned v){ return __uint_as_float(v << 16); }
__device__ __forceinline__ float bfhi(unsigned v){ return __uint_as_float(v & 0xFFFF0000u); }

// ======================= MFMA GEMM: outb[N,FOUT](bf16) = Abf[N,K] @ W[K,FOUT] =======================
// Optional fused attention dots: as_[r] = h[r,:]·av_s ; ad_[r] = h[r,:]·av_d
template<int K, int FOUT, bool DOTS>
__global__ void k_gemm_mfma(const short* __restrict__ Abf, const short* __restrict__ Wp,
                            short* __restrict__ outb,
                            const float* __restrict__ av_s, const float* __restrict__ av_d,
                            float* __restrict__ as_, float* __restrict__ ad_, int N){
  constexpr int NKS = K / 32, NCT = FOUT / 16;
  int wid  = threadIdx.x >> 6;
  int lane = threadIdx.x & 63;
  int rowbase = (blockIdx.x * 4 + wid) * 16;
  if(rowbase >= N) return;
  int arow = rowbase + (lane & 15);
  if(arow >= N) arow = N - 1;                     // clamp; clamped rows never stored
  f32x4 acc[NCT] = {};
  const short* ap = Abf + (long)arow * K + (lane >> 4) * 8;
  #pragma unroll
  for(int ks = 0; ks < NKS; ++ks){
    bf16x8 a = *(const bf16x8*)(ap + ks * 32);
    #pragma unroll
    for(int ct = 0; ct < NCT; ++ct){
      bf16x8 b = *(const bf16x8*)(Wp + ((ks * NCT + ct) * 64 + lane) * 8);
      acc[ct] = __builtin_amdgcn_mfma_f32_16x16x32_bf16(a, b, acc[ct], 0, 0, 0);
    }
  }
  int r0 = rowbase + (lane >> 4) * 4;             // D: row=(lane>>4)*4+j, col=lane&15
  int c0 = lane & 15;
  #pragma unroll
  for(int j = 0; j < 4; ++j){
    int r = r0 + j;
    if(r < N){
      #pragma unroll
      for(int ct = 0; ct < NCT; ++ct)
        outb[(long)r * FOUT + ct * 16 + c0] = f2bf(acc[ct][j]);
    }
  }
  if(DOTS){
    float avs[NCT], avd[NCT];
    #pragma unroll
    for(int ct = 0; ct < NCT; ++ct){ avs[ct] = av_s[ct * 16 + c0]; avd[ct] = av_d[ct * 16 + c0]; }
    #pragma unroll
    for(int j = 0; j < 4; ++j){
      float ps = 0.f, pd = 0.f;
      #pragma unroll
      for(int ct = 0; ct < NCT; ++ct){
        float hv = acc[ct][j];
        ps = fmaf(hv, avs[ct], ps);
        pd = fmaf(hv, avd[ct], pd);
      }
      #pragma unroll
      for(int off = 1; off < 16; off <<= 1){
        ps += __shfl_xor(ps, off);
        pd += __shfl_xor(pd, off);
      }
      int r = r0 + j;
      if(c0 == 0 && r < N){ as_[r] = ps; ad_[r] = pd; }
    }
  }
}

template<int K, int FOUT>
__global__ void k_pack_w(const float* __restrict__ W, short* __restrict__ Wp){
  constexpr int NKS = K / 32, NCT = FOUT / 16;
  int idx = blockIdx.x * blockDim.x + threadIdx.x;
  if(idx >= NKS * NCT * 64) return;
  int lane = idx & 63;
  int ct = (idx >> 6) % NCT;
  int ks = (idx >> 6) / NCT;
  int col = ct * 16 + (lane & 15);
  int kb  = ks * 32 + (lane >> 4) * 8;
  #pragma unroll
  for(int j = 0; j < 8; ++j) Wp[idx * 8 + j] = f2bf(W[(kb + j) * FOUT + col]);
}

// ======================= layer 1: outer product + dots =======================
__global__ void k_dot128(const float* __restrict__ W1, const float* __restrict__ a1s,
                         const float* __restrict__ a1d, float* __restrict__ S){
  __shared__ float s1[128], s2[128];
  int t = threadIdx.x;
  float w = W1[t];
  s1[t] = w * a1s[t]; s2[t] = w * a1d[t];
  __syncthreads();
  for(int off = 64; off > 0; off >>= 1){
    if(t < off){ s1[t] += s1[t + off]; s2[t] += s2[t + off]; }
    __syncthreads();
  }
  if(t == 0){ S[0] = s1[0]; S[1] = s2[0]; }
}
__global__ void k_l1(const float* __restrict__ x, const float* __restrict__ W1,
                     short* __restrict__ outb, int N){
  long idx = (long)blockIdx.x * blockDim.x + threadIdx.x;
  if(idx >= (long)N * 128) return;
  outb[idx] = f2bf(x[idx >> 7] * W1[idx & 127]);
}
__global__ void k_l1dots(const float* __restrict__ x, const float* __restrict__ S,
                         float* __restrict__ as_, float* __restrict__ ad_, int N){
  int i = blockIdx.x * blockDim.x + threadIdx.x;
  if(i >= N) return;
  float xv = x[i];
  as_[i] = xv * S[0]; ad_[i] = xv * S[1];
}

// ======================= CSR build (dst-sorted, with self-loops) =======================
__global__ void k_deg_init(int* __restrict__ deg, int N){
  int i = blockIdx.x * blockDim.x + threadIdx.x;
  if(i < N) deg[i] = 1;
}
__global__ void k_deg_count(const int* __restrict__ ei, int E, int* __restrict__ deg){
  int e = blockIdx.x * blockDim.x + threadIdx.x;
  if(e < E) atomicAdd(&deg[ei[E + e]], 1);
}

// ---- hierarchical exclusive scan of deg[N] -> rowptr[N+1], cursor[N] ----
// pass 1: per-block (256 elems) reduce
__global__ void k_scan_part(const int* __restrict__ deg, int* __restrict__ bsum, int N){
  __shared__ int red[256];
  int i = blockIdx.x * 256 + threadIdx.x;
  int v = (i < N) ? deg[i] : 0;
  red[threadIdx.x] = v;
  __syncthreads();
  #pragma unroll
  for(int off = 128; off > 0; off >>= 1){
    if(threadIdx.x < off) red[threadIdx.x] += red[threadIdx.x + off];
    __syncthreads();
  }
  if(threadIdx.x == 0) bsum[blockIdx.x] = red[0];
}
// pass 2: single small block scans block sums (exclusive, in place), writes rowptr[N]
__global__ void k_scan_mid(int* __restrict__ bsum, int NB, int* __restrict__ rowptr, int N){
  __shared__ int buf[1024];
  int t = threadIdx.x;
  int v = (t < NB) ? bsum[t] : 0;
  buf[t] = v;
  __syncthreads();
  for(int off = 1; off < 1024; off <<= 1){
    int u = (t >= off) ? buf[t - off] : 0;
    __syncthreads();
    buf[t] += u;
    __syncthreads();
  }
  if(t < NB) bsum[t] = buf[t] - v;                // exclusive
  if(t == 1023) rowptr[N] = buf[1023];
}
// pass 3: per-block exclusive scan + offset -> rowptr, cursor
__global__ void k_scan_fin(const int* __restrict__ deg, const int* __restrict__ bsum,
                           int* __restrict__ rowptr, int* __restrict__ cursor, int N){
  __shared__ int buf[256];
  int i = blockIdx.x * 256 + threadIdx.x;
  int t = threadIdx.x;
  int v = (i < N) ? deg[i] : 0;
  buf[t] = v;
  __syncthreads();
  #pragma unroll
  for(int off = 1; off < 256; off <<= 1){
    int u = (t >= off) ? buf[t - off] : 0;
    __syncthreads();
    buf[t] += u;
    __syncthreads();
  }
  if(i < N){
    int ex = buf[t] - v + bsum[blockIdx.x];
    rowptr[i] = ex; cursor[i] = ex;
  }
}

__global__ void k_fill(const int* __restrict__ ei, int E, int N,
                       int* __restrict__ cursor, int* __restrict__ csr_src){
  int e = blockIdx.x * blockDim.x + threadIdx.x;
  if(e >= E + N) return;
  int s, d;
  if(e < E){ s = ei[e]; d = ei[E + e]; } else { s = e - E; d = s; }
  int pos = atomicAdd(&cursor[d], 1);
  csr_src[pos] = s;
}
__global__ void k_dinv(const int* __restrict__ deg, float* __restrict__ dinv, int N){
  int i = blockIdx.x * blockDim.x + threadIdx.x;
  if(i < N) dinv[i] = rsqrtf((float)deg[i]);
}

// ======================= fused GAT aggregation: one wave per dst, bf16 h =======================
__global__ void k_gat_agg(const int* __restrict__ rowptr, const int* __restrict__ csr,
                          const float* __restrict__ as_, const float* __restrict__ ad_,
                          const short* __restrict__ h, const float* __restrict__ bias,
                          short* __restrict__ out, int N){
  int w = (int)(((long)blockIdx.x * blockDim.x + threadIdx.x) >> 6);
  int lane = threadIdx.x & 63;
  if(w >= N) return;
  int start = rowptr[w], end = rowptr[w + 1];
  int deg = end - start;
  float add = ad_[w];

  // phase A: lane l caches edge start+l (src, logit); online (max,expsum) incl. strided tail
  int s_reg = 0; float logit = -INFINITY;
  float m = -INFINITY, ssum = 0.f;
  if(lane < deg){
    s_reg = csr[start + lane];
    logit = lrelu(as_[s_reg] + add);
    m = logit; ssum = 1.f;
    for(int e = start + lane + 64; e < end; e += 64){
      int s = csr[e];
      float l = lrelu(as_[s] + add);
      if(l > m){ ssum = ssum * __expf(m - l) + 1.f; m = l; }
      else       ssum += __expf(l - m);
    }
  }
  #pragma unroll
  for(int off = 32; off > 0; off >>= 1){
    float mo = __shfl_xor(m, off);
    float so = __shfl_xor(ssum, off);
    float mn = fmaxf(m, mo);
    float ea = (m  > -INFINITY) ? __expf(m  - mn) : 0.f;
    float eb = (mo > -INFINITY) ? __expf(mo - mn) : 0.f;
    ssum = ssum * ea + so * eb;
    m = mn;
  }
  float inv = 1.f / (ssum + 1e-16f);
  float alpha_reg = __expf(logit - m) * inv;      // -INF logit -> 0

  // phase B: shfl-driven; lane covers features {2*lane, 2*lane+1}
  float acc0 = 0.f, acc1 = 0.f;
  int nb = deg < 64 ? deg : 64;
  for(int k = 0; k < nb; ++k){
    float a = __shfl(alpha_reg, k);
    int s   = __shfl(s_reg, k);
    unsigned hv = *(const unsigned*)(h + (long)s * 128 + lane * 2);
    acc0 = fmaf(a, bflo(hv), acc0);
    acc1 = fmaf(a, bfhi(hv), acc1);
  }
  for(int e = start + 64; e < end; ++e){          // rare overflow path
    int s = csr[e];
    float l = lrelu(as_[s] + add);
    float a = __expf(l - m) * inv;
    unsigned hv = *(const unsigned*)(h + (long)s * 128 + lane * 2);
    acc0 = fmaf(a, bflo(hv), acc0);
    acc1 = fmaf(a, bfhi(hv), acc1);
  }
  float2 bv = *(const float2*)(bias + lane * 2);
  out[(long)w * 128 + lane * 2]     = f2bf(eluf(acc0 + bv.x));
  out[(long)w * 128 + lane * 2 + 1] = f2bf(eluf(acc1 + bv.y));
}

// ======================= fused GCN aggregation: one wave per dst, bf16 h =======================
template<int F, bool BFOUT>
__global__ void k_gcn_agg(const int* __restrict__ rowptr, const int* __restrict__ csr,
                          const float* __restrict__ dinv, const short* __restrict__ h,
                          const float* __restrict__ bias, short* __restrict__ out_bf,
                          float* __restrict__ out_f, int N){
  int w = (int)(((long)blockIdx.x * blockDim.x + threadIdx.x) >> 6);
  int lane = threadIdx.x & 63;
  if(w >= N) return;
  int start = rowptr[w], end = rowptr[w + 1];
  int deg = end - start;
  float dd = dinv[w];
  int s_reg = 0; float dv_reg = 0.f;
  if(lane < deg){
    s_reg = csr[start + lane];
    dv_reg = dinv[s_reg];
  }
  float acc = 0.f;
  int nb = deg < 64 ? deg : 64;
  for(int k = 0; k < nb; ++k){
    int s = __shfl(s_reg, k);
    float nrm = dd * __shfl(dv_reg, k);
    if(lane < F){
      unsigned short hb = *(const unsigned short*)(h + (long)s * F + lane);
      acc = fmaf(nrm, bflo(hb), acc);
    }
  }
  for(int e = start + 64; e < end; ++e){
    int s = csr[e];
    float nrm = dd * dinv[s];
    if(lane < F){
      unsigned short hb = *(const unsigned short*)(h + (long)s * F + lane);
      acc = fmaf(nrm, bflo(hb), acc);
    }
  }
  if(lane < F){
    float v = eluf(acc + bias[lane]);
    if(BFOUT) out_bf[(long)w * F + lane] = f2bf(v);
    else      out_f [(long)w * F + lane] = v;
  }
}

// ============ per-graph softmax aggregation: one block per graph (batch sorted) ============
__global__ void k_batch_agg(const float* __restrict__ h, const int* __restrict__ batch,
                            const float* __restrict__ t, float* __restrict__ g, int N){
  int b = blockIdx.x;
  __shared__ int s_lo, s_hi;
  __shared__ float red[8][32];
  if(threadIdx.x == 0){
    int lo = 0, hi = N;
    while(lo < hi){ int mid = (lo + hi) >> 1; if(batch[mid] < b) lo = mid + 1; else hi = mid; }
    s_lo = lo;
    int lo2 = lo, hi2 = N;
    while(lo2 < hi2){ int mid = (lo2 + hi2) >> 1; if(batch[mid] < b + 1) lo2 = mid + 1; else hi2 = mid; }
    s_hi = lo2;
  }
  __syncthreads();
  int lo = s_lo, hi = s_hi;
  float tv = t[0];
  int c = threadIdx.x & 31, r = threadIdx.x >> 5;

  float m = -INFINITY;
  for(int i = lo + r; i < hi; i += 8) m = fmaxf(m, h[(long)i * 32 + c] * tv);
  red[r][c] = m; __syncthreads();
  if(r == 0){
    float mm = red[0][c];
    #pragma unroll
    for(int k = 1; k < 8; ++k) mm = fmaxf(mm, red[k][c]);
    red[0][c] = (mm == -INFINITY) ? 0.f : mm;
  }
  __syncthreads();
  m = red[0][c];
  __syncthreads();

  float ssum = 0.f;
  for(int i = lo + r; i < hi; i += 8) ssum += __expf(h[(long)i * 32 + c] * tv - m);
  red[r][c] = ssum; __syncthreads();
  if(r == 0){
    float tot = red[0][c];
    #pragma unroll
    for(int k = 1; k < 8; ++k) tot += red[k][c];
    red[0][c] = tot;
  }
  __syncthreads();
  float inv = 1.f / (red[0][c] + 1e-16f);
  __syncthreads();

  float acc = 0.f;
  for(int i = lo + r; i < hi; i += 8){
    float hv = h[(long)i * 32 + c];
    acc += __expf(hv * tv - m) * inv * hv;
  }
  red[r][c] = acc; __syncthreads();
  if(r == 0){
    float tot = red[0][c];
    #pragma unroll
    for(int k = 1; k < 8; ++k) tot += red[k][c];
    g[b * 32 + c] = tot;
  }
}

// ---- heads ----
__global__ void k_head(const float* __restrict__ g, const float* __restrict__ Wl1,
                       const float* __restrict__ bl1, const float* __restrict__ Wl2,
                       const float* __restrict__ bl2, float* __restrict__ out, int B){
  int b = blockIdx.x * blockDim.x + threadIdx.x;
  if(b >= B) return;
  float gr[32];
  #pragma unroll
  for(int k = 0; k < 32; ++k) gr[k] = g[b * 32 + k];
  float h1[16];
  #pragma unroll
  for(int j = 0; j < 16; ++j){
    float acc = bl1[j];
    #pragma unroll
    for(int k = 0; k < 32; ++k) acc = fmaf(gr[k], Wl1[k * 16 + j], acc);
    h1[j] = eluf(acc);
  }
  float l0 = bl2[0], l1 = bl2[1];
  #pragma unroll
  for(int k = 0; k < 16; ++k){
    l0 = fmaf(h1[k], Wl2[k * 2 + 0], l0);
    l1 = fmaf(h1[k], Wl2[k * 2 + 1], l1);
  }
  float mx = fmaxf(l0, l1);
  float lse = mx + __logf(__expf(l0 - mx) + __expf(l1 - mx));
  out[b * 2 + 0] = l0 - lse;
  out[b * 2 + 1] = l1 - lse;
}

extern "C" void kernel_launch(void* const* d_in, const int* in_sizes, int n_in,
                              void* d_out, int out_size, void* d_ws, size_t ws_size,
                              hipStream_t stream){
  const float* x     = (const float*)d_in[0];
  const int*   ei    = (const int*)d_in[1];
  const int*   batch = (const int*)d_in[2];
  const float* W1 = (const float*)d_in[3];
  const float* a1s = (const float*)d_in[4];
  const float* a1d = (const float*)d_in[5];
  const float* b1 = (const float*)d_in[6];
  const float* W2 = (const float*)d_in[7];
  const float* a2s = (const float*)d_in[8];
  const float* a2d = (const float*)d_in[9];
  const float* b2 = (const float*)d_in[10];
  const float* W3 = (const float*)d_in[11];
  const float* a3s = (const float*)d_in[12];
  const float* a3d = (const float*)d_in[13];
  const float* b3 = (const float*)d_in[14];
  const float* Wg1 = (const float*)d_in[15];
  const float* bg1 = (const float*)d_in[16];
  const float* Wg2 = (const float*)d_in[17];
  const float* bg2 = (const float*)d_in[18];
  const float* t   = (const float*)d_in[19];
  const float* Wl1 = (const float*)d_in[20];
  const float* bl1 = (const float*)d_in[21];
  const float* Wl2 = (const float*)d_in[22];
  const float* bl2 = (const float*)d_in[23];

  const int N = in_sizes[0];
  const int E = in_sizes[1] / 2;
  const int B = out_size / 2;
  const int ET = E + N;
  float* out = (float*)d_out;

  // ---- workspace layout ----
  char* p = (char*)d_ws;
  short* Hbf  = (short*)p;            p += (size_t)N * 128 * 2;   // gemm/layer out (bf16)
  short* Abf  = (short*)p;            p += (size_t)N * 128 * 2;   // agg out (bf16)
  float* A32  = (float*)p;            p += (size_t)N * 32 * 4;    // final GCN out (fp32)
  float* as_  = (float*)p;            p += (size_t)N * 4;
  float* ad_  = (float*)p;            p += (size_t)N * 4;
  float* dinv = (float*)p;            p += (size_t)N * 4;
  int*   deg    = (int*)p;            p += (size_t)N * 4;
  int*   rowptr = (int*)p;            p += (size_t)(N + 1) * 4;
  int*   cursor = (int*)p;            p += (size_t)N * 4;
  int*   csr    = (int*)p;            p += (size_t)ET * 4;
  int*   bsum   = (int*)p;            p += (size_t)1024 * 4;
  p = alignp(p, 16);
  short* Wp2  = (short*)p;            p += 128 * 128 * 2;
  short* Wp3  = (short*)p;            p += 128 * 128 * 2;
  short* Wpg1 = (short*)p;            p += 128 * 64 * 2;
  short* Wpg2 = (short*)p;            p += 64 * 32 * 2;
  p = alignp(p, 16);
  float* S    = (float*)p;            p += 16 * 4;
  float* g    = (float*)p;

  const int T = 256;
  const int gN  = cdiv(N, T);
  const int gE  = cdiv(E, T);
  const int gET = cdiv(ET, T);
  const int gW  = cdiv((long)N * 64, T);         // wave-per-dst grids
  const int gG  = cdiv(N, 64);                   // mfma gemm: 64 rows/block
  const int NB  = cdiv(N, 256);                  // scan blocks (<=1024)

  // ---------- CSR build + weight packs ----------
  k_deg_init<<<dim3(gN), dim3(T), 0, stream>>>(deg, N);
  k_deg_count<<<dim3(gE), dim3(T), 0, stream>>>(ei, E, deg);
  k_scan_part<<<dim3(NB), dim3(256), 0, stream>>>(deg, bsum, N);
  k_scan_mid<<<dim3(1), dim3(1024), 0, stream>>>(bsum, NB, rowptr, N);
  k_scan_fin<<<dim3(NB), dim3(256), 0, stream>>>(deg, bsum, rowptr, cursor, N);
  k_fill<<<dim3(gET), dim3(T), 0, stream>>>(ei, E, N, cursor, csr);
  k_dinv<<<dim3(gN), dim3(T), 0, stream>>>(deg, dinv, N);
  k_pack_w<128,128><<<dim3(8), dim3(T), 0, stream>>>(W2, Wp2);
  k_pack_w<128,128><<<dim3(8), dim3(T), 0, stream>>>(W3, Wp3);
  k_pack_w<128, 64><<<dim3(4), dim3(T), 0, stream>>>(Wg1, Wpg1);
  k_pack_w< 64, 32><<<dim3(1), dim3(T), 0, stream>>>(Wg2, Wpg2);
  k_dot128<<<dim3(1), dim3(128), 0, stream>>>(W1, a1s, a1d, S);

  // ---------- GAT layer 1 (1 -> 128): outer product ----------
  k_l1<<<dim3(cdiv((long)N * 128, T)), dim3(T), 0, stream>>>(x, W1, Hbf, N);
  k_l1dots<<<dim3(gN), dim3(T), 0, stream>>>(x, S, as_, ad_, N);
  k_gat_agg<<<dim3(gW), dim3(T), 0, stream>>>(rowptr, csr, as_, ad_, Hbf, b1, Abf, N);

  // ---------- GAT layer 2 (128 -> 128) ----------
  k_gemm_mfma<128,128,true><<<dim3(gG), dim3(T), 0, stream>>>(Abf, Wp2, Hbf, a2s, a2d, as_, ad_, N);
  k_gat_agg<<<dim3(gW), dim3(T), 0, stream>>>(rowptr, csr, as_, ad_, Hbf, b2, Abf, N);

  // ---------- GAT layer 3 (128 -> 128) ----------
  k_gemm_mfma<128,128,true><<<dim3(gG), dim3(T), 0, stream>>>(Abf, Wp3, Hbf, a3s, a3d, as_, ad_, N);
  k_gat_agg<<<dim3(gW), dim3(T), 0, stream>>>(rowptr, csr, as_, ad_, Hbf, b3, Abf, N);

  // ---------- GCN layer 1 (128 -> 64) ----------
  k_gemm_mfma<128,64,false><<<dim3(gG), dim3(T), 0, stream>>>(Abf, Wpg1, Hbf, nullptr, nullptr, nullptr, nullptr, N);
  k_gcn_agg<64,true><<<dim3(gW), dim3(T), 0, stream>>>(rowptr, csr, dinv, Hbf, bg1, Abf, (float*)nullptr, N);

  // ---------- GCN layer 2 (64 -> 32) ----------
  k_gemm_mfma<64,32,false><<<dim3(gG), dim3(T), 0, stream>>>(Abf, Wpg2, Hbf, nullptr, nullptr, nullptr, nullptr, N);
  k_gcn_agg<32,false><<<dim3(gW), dim3(T), 0, stream>>>(rowptr, csr, dinv, Hbf, bg2, (short*)nullptr, A32, N);

  // ---------- per-graph softmax aggregation ----------
  k_batch_agg<<<dim3(B), dim3(T), 0, stream>>>(A32, batch, t, g, N);

  // ---------- MLP heads + log_softmax ----------
  k_head<<<dim3(cdiv(B, 64)), dim3(64), 0, stream>>>(g, Wl1, bl1, Wl2, bl2, out, B);
}

// Round 6
// 370.661 us; speedup vs baseline: 5.6089x; 1.2143x over previous
//
#include <hip/hip_runtime.h>
#include <math.h>

static inline int cdiv(long a, long b){ return (int)((a + b - 1) / b); }
static inline char* alignp(char* p, size_t a){ return (char*)(((uintptr_t)p + a - 1) & ~(uintptr_t)(a - 1)); }

typedef __attribute__((ext_vector_type(8))) short bf16x8;
typedef __attribute__((ext_vector_type(4))) short bf16x4;
typedef __attribute__((ext_vector_type(4))) float f32x4;

__device__ __forceinline__ float lrelu(float x){ return x > 0.f ? x : 0.2f * x; }
__device__ __forceinline__ float eluf(float x){ return x > 0.f ? x : expm1f(x); }
__device__ __forceinline__ short f2bf(float f){            // RNE f32 -> bf16 bits
  unsigned u = __float_as_uint(f);
  return (short)((u + 0x7FFFu + ((u >> 16) & 1u)) >> 16);
}
__device__ __forceinline__ float bflo(unsigned v){ return __uint_as_float(v << 16); }
__device__ __forceinline__ float bfhi(unsigned v){ return __uint_as_float(v & 0xFFFF0000u); }

// ======================= MFMA GEMM: outb[N,FOUT](bf16) = Abf[N,K] @ W[K,FOUT] =======================
// Optional fused attention dots: as_[r] = h[r,:]·av_s ; ad_[r] = h[r,:]·av_d
template<int K, int FOUT, bool DOTS>
__global__ void k_gemm_mfma(const short* __restrict__ Abf, const short* __restrict__ Wp,
                            short* __restrict__ outb,
                            const float* __restrict__ av_s, const float* __restrict__ av_d,
                            float* __restrict__ as_, float* __restrict__ ad_, int N){
  constexpr int NKS = K / 32, NCT = FOUT / 16;
  int wid  = threadIdx.x >> 6;
  int lane = threadIdx.x & 63;
  int rowbase = (blockIdx.x * 4 + wid) * 16;
  if(rowbase >= N) return;
  int arow = rowbase + (lane & 15);
  if(arow >= N) arow = N - 1;                     // clamp; clamped rows never stored
  f32x4 acc[NCT] = {};
  const short* ap = Abf + (long)arow * K + (lane >> 4) * 8;
  #pragma unroll
  for(int ks = 0; ks < NKS; ++ks){
    bf16x8 a = *(const bf16x8*)(ap + ks * 32);
    #pragma unroll
    for(int ct = 0; ct < NCT; ++ct){
      bf16x8 b = *(const bf16x8*)(Wp + ((ks * NCT + ct) * 64 + lane) * 8);
      acc[ct] = __builtin_amdgcn_mfma_f32_16x16x32_bf16(a, b, acc[ct], 0, 0, 0);
    }
  }
  int r0 = rowbase + (lane >> 4) * 4;             // D: row=(lane>>4)*4+j, col=lane&15
  int c0 = lane & 15;
  #pragma unroll
  for(int j = 0; j < 4; ++j){
    int r = r0 + j;
    if(r < N){
      #pragma unroll
      for(int ct = 0; ct < NCT; ++ct)
        outb[(long)r * FOUT + ct * 16 + c0] = f2bf(acc[ct][j]);
    }
  }
  if(DOTS){
    float avs[NCT], avd[NCT];
    #pragma unroll
    for(int ct = 0; ct < NCT; ++ct){ avs[ct] = av_s[ct * 16 + c0]; avd[ct] = av_d[ct * 16 + c0]; }
    #pragma unroll
    for(int j = 0; j < 4; ++j){
      float ps = 0.f, pd = 0.f;
      #pragma unroll
      for(int ct = 0; ct < NCT; ++ct){
        float hv = acc[ct][j];
        ps = fmaf(hv, avs[ct], ps);
        pd = fmaf(hv, avd[ct], pd);
      }
      #pragma unroll
      for(int off = 1; off < 16; off <<= 1){
        ps += __shfl_xor(ps, off);
        pd += __shfl_xor(pd, off);
      }
      int r = r0 + j;
      if(c0 == 0 && r < N){ as_[r] = ps; ad_[r] = pd; }
    }
  }
}

template<int K, int FOUT>
__global__ void k_pack_w(const float* __restrict__ W, short* __restrict__ Wp){
  constexpr int NKS = K / 32, NCT = FOUT / 16;
  int idx = blockIdx.x * blockDim.x + threadIdx.x;
  if(idx >= NKS * NCT * 64) return;
  int lane = idx & 63;
  int ct = (idx >> 6) % NCT;
  int ks = (idx >> 6) / NCT;
  int col = ct * 16 + (lane & 15);
  int kb  = ks * 32 + (lane >> 4) * 8;
  #pragma unroll
  for(int j = 0; j < 8; ++j) Wp[idx * 8 + j] = f2bf(W[(kb + j) * FOUT + col]);
}

// ======================= layer 1: outer product + dots =======================
__global__ void k_dot128(const float* __restrict__ W1, const float* __restrict__ a1s,
                         const float* __restrict__ a1d, float* __restrict__ S){
  __shared__ float s1[128], s2[128];
  int t = threadIdx.x;
  float w = W1[t];
  s1[t] = w * a1s[t]; s2[t] = w * a1d[t];
  __syncthreads();
  for(int off = 64; off > 0; off >>= 1){
    if(t < off){ s1[t] += s1[t + off]; s2[t] += s2[t + off]; }
    __syncthreads();
  }
  if(t == 0){ S[0] = s1[0]; S[1] = s2[0]; }
}
// vectorized: thread per 8 features; 16B stores
__global__ void k_l1v(const float* __restrict__ x, const float* __restrict__ W1,
                      short* __restrict__ outb, int N){
  long idx = (long)blockIdx.x * blockDim.x + threadIdx.x;
  if(idx >= (long)N * 16) return;
  int node = (int)(idx >> 4), j8 = ((int)idx & 15) * 8;
  float xv = x[node];
  float4 w0 = *(const float4*)(W1 + j8);
  float4 w1 = *(const float4*)(W1 + j8 + 4);
  bf16x8 v;
  v[0] = f2bf(xv * w0.x); v[1] = f2bf(xv * w0.y);
  v[2] = f2bf(xv * w0.z); v[3] = f2bf(xv * w0.w);
  v[4] = f2bf(xv * w1.x); v[5] = f2bf(xv * w1.y);
  v[6] = f2bf(xv * w1.z); v[7] = f2bf(xv * w1.w);
  *(bf16x8*)(outb + (long)node * 128 + j8) = v;
}
__global__ void k_l1dots(const float* __restrict__ x, const float* __restrict__ S,
                         float* __restrict__ as_, float* __restrict__ ad_, int N){
  int i = blockIdx.x * blockDim.x + threadIdx.x;
  if(i >= N) return;
  float xv = x[i];
  as_[i] = xv * S[0]; ad_[i] = xv * S[1];
}

// ======================= CSR build (dst-sorted, with self-loops) =======================
__global__ void k_deg_init(int* __restrict__ deg, int N){
  int i = blockIdx.x * blockDim.x + threadIdx.x;
  if(i < N) deg[i] = 1;
}
__global__ void k_deg_count(const int* __restrict__ ei, int E, int* __restrict__ deg){
  int e = blockIdx.x * blockDim.x + threadIdx.x;
  if(e < E) atomicAdd(&deg[ei[E + e]], 1);
}

// ---- hierarchical exclusive scan of deg[N] -> rowptr[N+1], cursor[N] ----
__global__ void k_scan_part(const int* __restrict__ deg, int* __restrict__ bsum, int N){
  __shared__ int red[256];
  int i = blockIdx.x * 256 + threadIdx.x;
  int v = (i < N) ? deg[i] : 0;
  red[threadIdx.x] = v;
  __syncthreads();
  #pragma unroll
  for(int off = 128; off > 0; off >>= 1){
    if(threadIdx.x < off) red[threadIdx.x] += red[threadIdx.x + off];
    __syncthreads();
  }
  if(threadIdx.x == 0) bsum[blockIdx.x] = red[0];
}
__global__ void k_scan_mid(int* __restrict__ bsum, int NB, int* __restrict__ rowptr, int N){
  __shared__ int buf[1024];
  int t = threadIdx.x;
  int v = (t < NB) ? bsum[t] : 0;
  buf[t] = v;
  __syncthreads();
  for(int off = 1; off < 1024; off <<= 1){
    int u = (t >= off) ? buf[t - off] : 0;
    __syncthreads();
    buf[t] += u;
    __syncthreads();
  }
  if(t < NB) bsum[t] = buf[t] - v;                // exclusive
  if(t == 1023) rowptr[N] = buf[1023];
}
__global__ void k_scan_fin(const int* __restrict__ deg, const int* __restrict__ bsum,
                           int* __restrict__ rowptr, int* __restrict__ cursor, int N){
  __shared__ int buf[256];
  int i = blockIdx.x * 256 + threadIdx.x;
  int t = threadIdx.x;
  int v = (i < N) ? deg[i] : 0;
  buf[t] = v;
  __syncthreads();
  #pragma unroll
  for(int off = 1; off < 256; off <<= 1){
    int u = (t >= off) ? buf[t - off] : 0;
    __syncthreads();
    buf[t] += u;
    __syncthreads();
  }
  if(i < N){
    int ex = buf[t] - v + bsum[blockIdx.x];
    rowptr[i] = ex; cursor[i] = ex;
  }
}

__global__ void k_fill(const int* __restrict__ ei, int E, int N,
                       int* __restrict__ cursor, int* __restrict__ csr_src){
  int e = blockIdx.x * blockDim.x + threadIdx.x;
  if(e >= E + N) return;
  int s, d;
  if(e < E){ s = ei[e]; d = ei[E + e]; } else { s = e - E; d = s; }
  int pos = atomicAdd(&cursor[d], 1);
  csr_src[pos] = s;
}
__global__ void k_dinv(const int* __restrict__ deg, float* __restrict__ dinv, int N){
  int i = blockIdx.x * blockDim.x + threadIdx.x;
  if(i < N) dinv[i] = rsqrtf((float)deg[i]);
}

// ======================= fused GAT aggregation: one wave per dst, bf16 h =======================
// phase B: 4 edges/iter; lane group g=lane>>4 takes edge k+g; lane loads 8 features (16B)
__global__ void k_gat_agg(const int* __restrict__ rowptr, const int* __restrict__ csr,
                          const float* __restrict__ as_, const float* __restrict__ ad_,
                          const short* __restrict__ h, const float* __restrict__ bias,
                          short* __restrict__ out, int N){
  int w = (int)(((long)blockIdx.x * blockDim.x + threadIdx.x) >> 6);
  int lane = threadIdx.x & 63;
  if(w >= N) return;
  int start = rowptr[w], end = rowptr[w + 1];
  int deg = end - start;
  float add = ad_[w];

  // phase A: lane l caches edge start+l (src, logit); online (max,expsum) incl. strided tail
  int s_reg = 0; float logit = -INFINITY;
  float m = -INFINITY, ssum = 0.f;
  if(lane < deg){
    s_reg = csr[start + lane];
    logit = lrelu(as_[s_reg] + add);
    m = logit; ssum = 1.f;
    for(int e = start + lane + 64; e < end; e += 64){
      int s = csr[e];
      float l = lrelu(as_[s] + add);
      if(l > m){ ssum = ssum * __expf(m - l) + 1.f; m = l; }
      else       ssum += __expf(l - m);
    }
  }
  #pragma unroll
  for(int off = 32; off > 0; off >>= 1){
    float mo = __shfl_xor(m, off);
    float so = __shfl_xor(ssum, off);
    float mn = fmaxf(m, mo);
    float ea = (m  > -INFINITY) ? __expf(m  - mn) : 0.f;
    float eb = (mo > -INFINITY) ? __expf(mo - mn) : 0.f;
    ssum = ssum * ea + so * eb;
    m = mn;
  }
  float inv = 1.f / (ssum + 1e-16f);
  float alpha_reg = __expf(logit - m) * inv;      // -INF logit -> 0

  // phase B: 4 edges per iteration, 16B row-slices; group g handles edge k+g
  float acc[8] = {};
  int nb = deg < 64 ? deg : 64;
  int g  = lane >> 4;
  int fo = (lane & 15) * 8;
  const short* hf = h + fo;
  for(int k = 0; k < nb; k += 4){
    int idx = k + g;
    if(idx < nb){
      float a = __shfl(alpha_reg, idx);
      int s   = __shfl(s_reg, idx);
      uint4 hv = *(const uint4*)(hf + (long)s * 128);
      acc[0] = fmaf(a, bflo(hv.x), acc[0]);
      acc[1] = fmaf(a, bfhi(hv.x), acc[1]);
      acc[2] = fmaf(a, bflo(hv.y), acc[2]);
      acc[3] = fmaf(a, bfhi(hv.y), acc[3]);
      acc[4] = fmaf(a, bflo(hv.z), acc[4]);
      acc[5] = fmaf(a, bfhi(hv.z), acc[5]);
      acc[6] = fmaf(a, bflo(hv.w), acc[6]);
      acc[7] = fmaf(a, bfhi(hv.w), acc[7]);
    }
  }
  for(int e = start + 64; e < end; ++e){          // rare overflow path (group 0 only)
    if(lane < 16){
      int s = csr[e];
      float l = lrelu(as_[s] + add);
      float a = __expf(l - m) * inv;
      uint4 hv = *(const uint4*)(hf + (long)s * 128);
      acc[0] = fmaf(a, bflo(hv.x), acc[0]);
      acc[1] = fmaf(a, bfhi(hv.x), acc[1]);
      acc[2] = fmaf(a, bflo(hv.y), acc[2]);
      acc[3] = fmaf(a, bfhi(hv.y), acc[3]);
      acc[4] = fmaf(a, bflo(hv.z), acc[4]);
      acc[5] = fmaf(a, bfhi(hv.z), acc[5]);
      acc[6] = fmaf(a, bflo(hv.w), acc[6]);
      acc[7] = fmaf(a, bfhi(hv.w), acc[7]);
    }
  }
  #pragma unroll
  for(int j = 0; j < 8; ++j){
    acc[j] += __shfl_xor(acc[j], 16);
    acc[j] += __shfl_xor(acc[j], 32);
  }
  if(lane < 16){
    float4 b0 = *(const float4*)(bias + fo);
    float4 b1 = *(const float4*)(bias + fo + 4);
    bf16x8 v;
    v[0] = f2bf(eluf(acc[0] + b0.x)); v[1] = f2bf(eluf(acc[1] + b0.y));
    v[2] = f2bf(eluf(acc[2] + b0.z)); v[3] = f2bf(eluf(acc[3] + b0.w));
    v[4] = f2bf(eluf(acc[4] + b1.x)); v[5] = f2bf(eluf(acc[5] + b1.y));
    v[6] = f2bf(eluf(acc[6] + b1.z)); v[7] = f2bf(eluf(acc[7] + b1.w));
    *(bf16x8*)(out + (long)w * 128 + fo) = v;
  }
}

// ======================= fused GCN aggregation: one wave per dst, bf16 h =======================
template<int F, bool BFOUT>
__global__ void k_gcn_agg(const int* __restrict__ rowptr, const int* __restrict__ csr,
                          const float* __restrict__ dinv, const short* __restrict__ h,
                          const float* __restrict__ bias, short* __restrict__ out_bf,
                          float* __restrict__ out_f, int N){
  constexpr int FPL = F / 16;                     // features per lane (4 or 2)
  int w = (int)(((long)blockIdx.x * blockDim.x + threadIdx.x) >> 6);
  int lane = threadIdx.x & 63;
  if(w >= N) return;
  int start = rowptr[w], end = rowptr[w + 1];
  int deg = end - start;
  float dd = dinv[w];
  int s_reg = 0; float dv_reg = 0.f;
  if(lane < deg){
    s_reg = csr[start + lane];
    dv_reg = dinv[s_reg];
  }
  float acc[FPL] = {};
  int nb = deg < 64 ? deg : 64;
  int g  = lane >> 4;
  int fo = (lane & 15) * FPL;
  const short* hf = h + fo;
  for(int k = 0; k < nb; k += 4){
    int idx = k + g;
    if(idx < nb){
      int s = __shfl(s_reg, idx);
      float nrm = dd * __shfl(dv_reg, idx);
      if(FPL == 4){
        uint2 hv = *(const uint2*)(hf + (long)s * F);
        acc[0] = fmaf(nrm, bflo(hv.x), acc[0]);
        acc[1] = fmaf(nrm, bfhi(hv.x), acc[1]);
        acc[2] = fmaf(nrm, bflo(hv.y), acc[2]);
        acc[3] = fmaf(nrm, bfhi(hv.y), acc[3]);
      }else{
        unsigned hv = *(const unsigned*)(hf + (long)s * F);
        acc[0] = fmaf(nrm, bflo(hv), acc[0]);
        acc[1] = fmaf(nrm, bfhi(hv), acc[1]);
      }
    }
  }
  for(int e = start + 64; e < end; ++e){          // rare overflow (group 0 only)
    if(lane < 16){
      int s = csr[e];
      float nrm = dd * dinv[s];
      if(FPL == 4){
        uint2 hv = *(const uint2*)(hf + (long)s * F);
        acc[0] = fmaf(nrm, bflo(hv.x), acc[0]);
        acc[1] = fmaf(nrm, bfhi(hv.x), acc[1]);
        acc[2] = fmaf(nrm, bflo(hv.y), acc[2]);
        acc[3] = fmaf(nrm, bfhi(hv.y), acc[3]);
      }else{
        unsigned hv = *(const unsigned*)(hf + (long)s * F);
        acc[0] = fmaf(nrm, bflo(hv), acc[0]);
        acc[1] = fmaf(nrm, bfhi(hv), acc[1]);
      }
    }
  }
  #pragma unroll
  for(int j = 0; j < FPL; ++j){
    acc[j] += __shfl_xor(acc[j], 16);
    acc[j] += __shfl_xor(acc[j], 32);
  }
  if(lane < 16){
    if(BFOUT){
      if(FPL == 4){
        bf16x4 v;
        #pragma unroll
        for(int j = 0; j < 4; ++j) v[j] = f2bf(eluf(acc[j] + bias[fo + j]));
        *(bf16x4*)(out_bf + (long)w * F + fo) = v;
      }else{
        #pragma unroll
        for(int j = 0; j < FPL; ++j)
          out_bf[(long)w * F + fo + j] = f2bf(eluf(acc[j] + bias[fo + j]));
      }
    }else{
      if(FPL == 2){
        float2 v2 = make_float2(eluf(acc[0] + bias[fo]), eluf(acc[1] + bias[fo + 1]));
        *(float2*)(out_f + (long)w * F + fo) = v2;
      }else{
        #pragma unroll
        for(int j = 0; j < FPL; ++j)
          out_f[(long)w * F + fo + j] = eluf(acc[j] + bias[fo + j]);
      }
    }
  }
}

// ============ per-graph softmax aggregation: one block per graph (batch sorted) ============
__global__ void k_batch_agg(const float* __restrict__ h, const int* __restrict__ batch,
                            const float* __restrict__ t, float* __restrict__ g, int N){
  int b = blockIdx.x;
  __shared__ int s_lo, s_hi;
  __shared__ float red[8][32];
  if(threadIdx.x == 0){
    int lo = 0, hi = N;
    while(lo < hi){ int mid = (lo + hi) >> 1; if(batch[mid] < b) lo = mid + 1; else hi = mid; }
    s_lo = lo;
    int lo2 = lo, hi2 = N;
    while(lo2 < hi2){ int mid = (lo2 + hi2) >> 1; if(batch[mid] < b + 1) lo2 = mid + 1; else hi2 = mid; }
    s_hi = lo2;
  }
  __syncthreads();
  int lo = s_lo, hi = s_hi;
  float tv = t[0];
  int c = threadIdx.x & 31, r = threadIdx.x >> 5;

  float m = -INFINITY;
  for(int i = lo + r; i < hi; i += 8) m = fmaxf(m, h[(long)i * 32 + c] * tv);
  red[r][c] = m; __syncthreads();
  if(r == 0){
    float mm = red[0][c];
    #pragma unroll
    for(int k = 1; k < 8; ++k) mm = fmaxf(mm, red[k][c]);
    red[0][c] = (mm == -INFINITY) ? 0.f : mm;
  }
  __syncthreads();
  m = red[0][c];
  __syncthreads();

  float ssum = 0.f;
  for(int i = lo + r; i < hi; i += 8) ssum += __expf(h[(long)i * 32 + c] * tv - m);
  red[r][c] = ssum; __syncthreads();
  if(r == 0){
    float tot = red[0][c];
    #pragma unroll
    for(int k = 1; k < 8; ++k) tot += red[k][c];
    red[0][c] = tot;
  }
  __syncthreads();
  float inv = 1.f / (red[0][c] + 1e-16f);
  __syncthreads();

  float acc = 0.f;
  for(int i = lo + r; i < hi; i += 8){
    float hv = h[(long)i * 32 + c];
    acc += __expf(hv * tv - m) * inv * hv;
  }
  red[r][c] = acc; __syncthreads();
  if(r == 0){
    float tot = red[0][c];
    #pragma unroll
    for(int k = 1; k < 8; ++k) tot += red[k][c];
    g[b * 32 + c] = tot;
  }
}

// ---- heads ----
__global__ void k_head(const float* __restrict__ g, const float* __restrict__ Wl1,
                       const float* __restrict__ bl1, const float* __restrict__ Wl2,
                       const float* __restrict__ bl2, float* __restrict__ out, int B){
  int b = blockIdx.x * blockDim.x + threadIdx.x;
  if(b >= B) return;
  float gr[32];
  #pragma unroll
  for(int k = 0; k < 32; ++k) gr[k] = g[b * 32 + k];
  float h1[16];
  #pragma unroll
  for(int j = 0; j < 16; ++j){
    float acc = bl1[j];
    #pragma unroll
    for(int k = 0; k < 32; ++k) acc = fmaf(gr[k], Wl1[k * 16 + j], acc);
    h1[j] = eluf(acc);
  }
  float l0 = bl2[0], l1 = bl2[1];
  #pragma unroll
  for(int k = 0; k < 16; ++k){
    l0 = fmaf(h1[k], Wl2[k * 2 + 0], l0);
    l1 = fmaf(h1[k], Wl2[k * 2 + 1], l1);
  }
  float mx = fmaxf(l0, l1);
  float lse = mx + __logf(__expf(l0 - mx) + __expf(l1 - mx));
  out[b * 2 + 0] = l0 - lse;
  out[b * 2 + 1] = l1 - lse;
}

extern "C" void kernel_launch(void* const* d_in, const int* in_sizes, int n_in,
                              void* d_out, int out_size, void* d_ws, size_t ws_size,
                              hipStream_t stream){
  const float* x     = (const float*)d_in[0];
  const int*   ei    = (const int*)d_in[1];
  const int*   batch = (const int*)d_in[2];
  const float* W1 = (const float*)d_in[3];
  const float* a1s = (const float*)d_in[4];
  const float* a1d = (const float*)d_in[5];
  const float* b1 = (const float*)d_in[6];
  const float* W2 = (const float*)d_in[7];
  const float* a2s = (const float*)d_in[8];
  const float* a2d = (const float*)d_in[9];
  const float* b2 = (const float*)d_in[10];
  const float* W3 = (const float*)d_in[11];
  const float* a3s = (const float*)d_in[12];
  const float* a3d = (const float*)d_in[13];
  const float* b3 = (const float*)d_in[14];
  const float* Wg1 = (const float*)d_in[15];
  const float* bg1 = (const float*)d_in[16];
  const float* Wg2 = (const float*)d_in[17];
  const float* bg2 = (const float*)d_in[18];
  const float* t   = (const float*)d_in[19];
  const float* Wl1 = (const float*)d_in[20];
  const float* bl1 = (const float*)d_in[21];
  const float* Wl2 = (const float*)d_in[22];
  const float* bl2 = (const float*)d_in[23];

  const int N = in_sizes[0];
  const int E = in_sizes[1] / 2;
  const int B = out_size / 2;
  const int ET = E + N;
  float* out = (float*)d_out;

  // ---- workspace layout ----
  char* p = (char*)d_ws;
  short* Hbf  = (short*)p;            p += (size_t)N * 128 * 2;   // gemm/layer out (bf16)
  short* Abf  = (short*)p;            p += (size_t)N * 128 * 2;   // agg out (bf16)
  float* A32  = (float*)p;            p += (size_t)N * 32 * 4;    // final GCN out (fp32)
  float* as_  = (float*)p;            p += (size_t)N * 4;
  float* ad_  = (float*)p;            p += (size_t)N * 4;
  float* dinv = (float*)p;            p += (size_t)N * 4;
  int*   deg    = (int*)p;            p += (size_t)N * 4;
  int*   rowptr = (int*)p;            p += (size_t)(N + 1) * 4;
  int*   cursor = (int*)p;            p += (size_t)N * 4;
  int*   csr    = (int*)p;            p += (size_t)ET * 4;
  int*   bsum   = (int*)p;            p += (size_t)1024 * 4;
  p = alignp(p, 16);
  short* Wp2  = (short*)p;            p += 128 * 128 * 2;
  short* Wp3  = (short*)p;            p += 128 * 128 * 2;
  short* Wpg1 = (short*)p;            p += 128 * 64 * 2;
  short* Wpg2 = (short*)p;            p += 64 * 32 * 2;
  p = alignp(p, 16);
  float* S    = (float*)p;            p += 16 * 4;
  float* g    = (float*)p;

  const int T = 256;
  const int gN  = cdiv(N, T);
  const int gE  = cdiv(E, T);
  const int gET = cdiv(ET, T);
  const int gW  = cdiv((long)N * 64, T);         // wave-per-dst grids
  const int gG  = cdiv(N, 64);                   // mfma gemm: 64 rows/block
  const int NB  = cdiv(N, 256);                  // scan blocks (<=1024)

  // ---------- CSR build + weight packs ----------
  k_deg_init<<<dim3(gN), dim3(T), 0, stream>>>(deg, N);
  k_deg_count<<<dim3(gE), dim3(T), 0, stream>>>(ei, E, deg);
  k_scan_part<<<dim3(NB), dim3(256), 0, stream>>>(deg, bsum, N);
  k_scan_mid<<<dim3(1), dim3(1024), 0, stream>>>(bsum, NB, rowptr, N);
  k_scan_fin<<<dim3(NB), dim3(256), 0, stream>>>(deg, bsum, rowptr, cursor, N);
  k_fill<<<dim3(gET), dim3(T), 0, stream>>>(ei, E, N, cursor, csr);
  k_dinv<<<dim3(gN), dim3(T), 0, stream>>>(deg, dinv, N);
  k_pack_w<128,128><<<dim3(8), dim3(T), 0, stream>>>(W2, Wp2);
  k_pack_w<128,128><<<dim3(8), dim3(T), 0, stream>>>(W3, Wp3);
  k_pack_w<128, 64><<<dim3(4), dim3(T), 0, stream>>>(Wg1, Wpg1);
  k_pack_w< 64, 32><<<dim3(1), dim3(T), 0, stream>>>(Wg2, Wpg2);
  k_dot128<<<dim3(1), dim3(128), 0, stream>>>(W1, a1s, a1d, S);

  // ---------- GAT layer 1 (1 -> 128): outer product ----------
  k_l1v<<<dim3(cdiv((long)N * 16, T)), dim3(T), 0, stream>>>(x, W1, Hbf, N);
  k_l1dots<<<dim3(gN), dim3(T), 0, stream>>>(x, S, as_, ad_, N);
  k_gat_agg<<<dim3(gW), dim3(T), 0, stream>>>(rowptr, csr, as_, ad_, Hbf, b1, Abf, N);

  // ---------- GAT layer 2 (128 -> 128) ----------
  k_gemm_mfma<128,128,true><<<dim3(gG), dim3(T), 0, stream>>>(Abf, Wp2, Hbf, a2s, a2d, as_, ad_, N);
  k_gat_agg<<<dim3(gW), dim3(T), 0, stream>>>(rowptr, csr, as_, ad_, Hbf, b2, Abf, N);

  // ---------- GAT layer 3 (128 -> 128) ----------
  k_gemm_mfma<128,128,true><<<dim3(gG), dim3(T), 0, stream>>>(Abf, Wp3, Hbf, a3s, a3d, as_, ad_, N);
  k_gat_agg<<<dim3(gW), dim3(T), 0, stream>>>(rowptr, csr, as_, ad_, Hbf, b3, Abf, N);

  // ---------- GCN layer 1 (128 -> 64) ----------
  k_gemm_mfma<128,64,false><<<dim3(gG), dim3(T), 0, stream>>>(Abf, Wpg1, Hbf, nullptr, nullptr, nullptr, nullptr, N);
  k_gcn_agg<64,true><<<dim3(gW), dim3(T), 0, stream>>>(rowptr, csr, dinv, Hbf, bg1, Abf, (float*)nullptr, N);

  // ---------- GCN layer 2 (64 -> 32) ----------
  k_gemm_mfma<64,32,false><<<dim3(gG), dim3(T), 0, stream>>>(Abf, Wpg2, Hbf, nullptr, nullptr, nullptr, nullptr, N);
  k_gcn_agg<32,false><<<dim3(gW), dim3(T), 0, stream>>>(rowptr, csr, dinv, Hbf, bg2, (short*)nullptr, A32, N);

  // ---------- per-graph softmax aggregation ----------
  k_batch_agg<<<dim3(B), dim3(T), 0, stream>>>(A32, batch, t, g, N);

  // ---------- MLP heads + log_softmax ----------
  k_head<<<dim3(cdiv(B, 64)), dim3(64), 0, stream>>>(g, Wl1, bl1, Wl2, bl2, out, B);
}

// Round 7
// 340.240 us; speedup vs baseline: 6.1104x; 1.0894x over previous
//
#include <hip/hip_runtime.h>
#include <math.h>

static inline int cdiv(long a, long b){ return (int)((a + b - 1) / b); }
static inline char* alignp(char* p, size_t a){ return (char*)(((uintptr_t)p + a - 1) & ~(uintptr_t)(a - 1)); }

typedef __attribute__((ext_vector_type(8))) short bf16x8;
typedef __attribute__((ext_vector_type(4))) short bf16x4;
typedef __attribute__((ext_vector_type(4))) float f32x4;

__device__ __forceinline__ float lrelu(float x){ return x > 0.f ? x : 0.2f * x; }
__device__ __forceinline__ float eluf(float x){ return x > 0.f ? x : expm1f(x); }
__device__ __forceinline__ short f2bf(float f){            // RNE f32 -> bf16 bits
  unsigned u = __float_as_uint(f);
  return (short)((u + 0x7FFFu + ((u >> 16) & 1u)) >> 16);
}
__device__ __forceinline__ float bflo(unsigned v){ return __uint_as_float(v << 16); }
__device__ __forceinline__ float bfhi(unsigned v){ return __uint_as_float(v & 0xFFFF0000u); }

// ======================= MFMA GEMM: outb[N,FOUT](bf16) = Abf[N,K] @ W[K,FOUT] =======================
// Optional fused attention dots: as_[r] = h[r,:]·av_s ; ad_[r] = h[r,:]·av_d
template<int K, int FOUT, bool DOTS>
__global__ void k_gemm_mfma(const short* __restrict__ Abf, const short* __restrict__ Wp,
                            short* __restrict__ outb,
                            const float* __restrict__ av_s, const float* __restrict__ av_d,
                            float* __restrict__ as_, float* __restrict__ ad_, int N){
  constexpr int NKS = K / 32, NCT = FOUT / 16;
  int wid  = threadIdx.x >> 6;
  int lane = threadIdx.x & 63;
  int rowbase = (blockIdx.x * 4 + wid) * 16;
  if(rowbase >= N) return;
  int arow = rowbase + (lane & 15);
  if(arow >= N) arow = N - 1;                     // clamp; clamped rows never stored
  f32x4 acc[NCT] = {};
  const short* ap = Abf + (long)arow * K + (lane >> 4) * 8;
  #pragma unroll
  for(int ks = 0; ks < NKS; ++ks){
    bf16x8 a = *(const bf16x8*)(ap + ks * 32);
    #pragma unroll
    for(int ct = 0; ct < NCT; ++ct){
      bf16x8 b = *(const bf16x8*)(Wp + ((ks * NCT + ct) * 64 + lane) * 8);
      acc[ct] = __builtin_amdgcn_mfma_f32_16x16x32_bf16(a, b, acc[ct], 0, 0, 0);
    }
  }
  int r0 = rowbase + (lane >> 4) * 4;             // D: row=(lane>>4)*4+j, col=lane&15
  int c0 = lane & 15;
  #pragma unroll
  for(int j = 0; j < 4; ++j){
    int r = r0 + j;
    if(r < N){
      #pragma unroll
      for(int ct = 0; ct < NCT; ++ct)
        outb[(long)r * FOUT + ct * 16 + c0] = f2bf(acc[ct][j]);
    }
  }
  if(DOTS){
    float avs[NCT], avd[NCT];
    #pragma unroll
    for(int ct = 0; ct < NCT; ++ct){ avs[ct] = av_s[ct * 16 + c0]; avd[ct] = av_d[ct * 16 + c0]; }
    #pragma unroll
    for(int j = 0; j < 4; ++j){
      float ps = 0.f, pd = 0.f;
      #pragma unroll
      for(int ct = 0; ct < NCT; ++ct){
        float hv = acc[ct][j];
        ps = fmaf(hv, avs[ct], ps);
        pd = fmaf(hv, avd[ct], pd);
      }
      #pragma unroll
      for(int off = 1; off < 16; off <<= 1){
        ps += __shfl_xor(ps, off);
        pd += __shfl_xor(pd, off);
      }
      int r = r0 + j;
      if(c0 == 0 && r < N){ as_[r] = ps; ad_[r] = pd; }
    }
  }
}

template<int K, int FOUT>
__global__ void k_pack_w(const float* __restrict__ W, short* __restrict__ Wp){
  constexpr int NKS = K / 32, NCT = FOUT / 16;
  int idx = blockIdx.x * blockDim.x + threadIdx.x;
  if(idx >= NKS * NCT * 64) return;
  int lane = idx & 63;
  int ct = (idx >> 6) % NCT;
  int ks = (idx >> 6) / NCT;
  int col = ct * 16 + (lane & 15);
  int kb  = ks * 32 + (lane >> 4) * 8;
  #pragma unroll
  for(int j = 0; j < 8; ++j) Wp[idx * 8 + j] = f2bf(W[(kb + j) * FOUT + col]);
}

// ======================= layer 1: outer product + dots =======================
__global__ void k_dot128(const float* __restrict__ W1, const float* __restrict__ a1s,
                         const float* __restrict__ a1d, float* __restrict__ S){
  __shared__ float s1[128], s2[128];
  int t = threadIdx.x;
  float w = W1[t];
  s1[t] = w * a1s[t]; s2[t] = w * a1d[t];
  __syncthreads();
  for(int off = 64; off > 0; off >>= 1){
    if(t < off){ s1[t] += s1[t + off]; s2[t] += s2[t + off]; }
    __syncthreads();
  }
  if(t == 0){ S[0] = s1[0]; S[1] = s2[0]; }
}
// vectorized: thread per 8 features; 16B stores
__global__ void k_l1v(const float* __restrict__ x, const float* __restrict__ W1,
                      short* __restrict__ outb, int N){
  long idx = (long)blockIdx.x * blockDim.x + threadIdx.x;
  if(idx >= (long)N * 16) return;
  int node = (int)(idx >> 4), j8 = ((int)idx & 15) * 8;
  float xv = x[node];
  float4 w0 = *(const float4*)(W1 + j8);
  float4 w1 = *(const float4*)(W1 + j8 + 4);
  bf16x8 v;
  v[0] = f2bf(xv * w0.x); v[1] = f2bf(xv * w0.y);
  v[2] = f2bf(xv * w0.z); v[3] = f2bf(xv * w0.w);
  v[4] = f2bf(xv * w1.x); v[5] = f2bf(xv * w1.y);
  v[6] = f2bf(xv * w1.z); v[7] = f2bf(xv * w1.w);
  *(bf16x8*)(outb + (long)node * 128 + j8) = v;
}
__global__ void k_l1dots(const float* __restrict__ x, const float* __restrict__ S,
                         float* __restrict__ as_, float* __restrict__ ad_, int N){
  int i = blockIdx.x * blockDim.x + threadIdx.x;
  if(i >= N) return;
  float xv = x[i];
  as_[i] = xv * S[0]; ad_[i] = xv * S[1];
}

// ======================= CSR build (dst-sorted, with self-loops) =======================
__global__ void k_deg_init(int* __restrict__ deg, int N){
  int i = blockIdx.x * blockDim.x + threadIdx.x;
  if(i < N) deg[i] = 1;
}
__global__ void k_deg_count(const int* __restrict__ ei, int E, int* __restrict__ deg){
  int e = blockIdx.x * blockDim.x + threadIdx.x;
  if(e < E) atomicAdd(&deg[ei[E + e]], 1);
}

// ---- hierarchical exclusive scan of deg[N] -> rowptr[N+1], cursor[N] ----
__global__ void k_scan_part(const int* __restrict__ deg, int* __restrict__ bsum, int N){
  __shared__ int red[256];
  int i = blockIdx.x * 256 + threadIdx.x;
  int v = (i < N) ? deg[i] : 0;
  red[threadIdx.x] = v;
  __syncthreads();
  #pragma unroll
  for(int off = 128; off > 0; off >>= 1){
    if(threadIdx.x < off) red[threadIdx.x] += red[threadIdx.x + off];
    __syncthreads();
  }
  if(threadIdx.x == 0) bsum[blockIdx.x] = red[0];
}
__global__ void k_scan_mid(int* __restrict__ bsum, int NB, int* __restrict__ rowptr, int N){
  __shared__ int buf[1024];
  int t = threadIdx.x;
  int v = (t < NB) ? bsum[t] : 0;
  buf[t] = v;
  __syncthreads();
  for(int off = 1; off < 1024; off <<= 1){
    int u = (t >= off) ? buf[t - off] : 0;
    __syncthreads();
    buf[t] += u;
    __syncthreads();
  }
  if(t < NB) bsum[t] = buf[t] - v;                // exclusive
  if(t == 1023) rowptr[N] = buf[1023];
}
__global__ void k_scan_fin(const int* __restrict__ deg, const int* __restrict__ bsum,
                           int* __restrict__ rowptr, int* __restrict__ cursor, int N){
  __shared__ int buf[256];
  int i = blockIdx.x * 256 + threadIdx.x;
  int t = threadIdx.x;
  int v = (i < N) ? deg[i] : 0;
  buf[t] = v;
  __syncthreads();
  #pragma unroll
  for(int off = 1; off < 256; off <<= 1){
    int u = (t >= off) ? buf[t - off] : 0;
    __syncthreads();
    buf[t] += u;
    __syncthreads();
  }
  if(i < N){
    int ex = buf[t] - v + bsum[blockIdx.x];
    rowptr[i] = ex; cursor[i] = ex;
  }
}

__global__ void k_fill(const int* __restrict__ ei, int E, int N,
                       int* __restrict__ cursor, int* __restrict__ csr_src){
  int e = blockIdx.x * blockDim.x + threadIdx.x;
  if(e >= E + N) return;
  int s, d;
  if(e < E){ s = ei[e]; d = ei[E + e]; } else { s = e - E; d = s; }
  int pos = atomicAdd(&cursor[d], 1);
  csr_src[pos] = s;
}
__global__ void k_dinv(const int* __restrict__ deg, float* __restrict__ dinv, int N){
  int i = blockIdx.x * blockDim.x + threadIdx.x;
  if(i < N) dinv[i] = rsqrtf((float)deg[i]);
}

// ======================= fused GAT aggregation: one wave per dst, bf16 h =======================
// phase B: 4 edges/iter; lane group g=lane>>4 takes edge k+g; lane loads 8 features (16B)
__global__ void k_gat_agg(const int* __restrict__ rowptr, const int* __restrict__ csr,
                          const float* __restrict__ as_, const float* __restrict__ ad_,
                          const short* __restrict__ h, const float* __restrict__ bias,
                          short* __restrict__ out, int N){
  int w = (int)(((long)blockIdx.x * blockDim.x + threadIdx.x) >> 6);
  int lane = threadIdx.x & 63;
  if(w >= N) return;
  int start = rowptr[w], end = rowptr[w + 1];
  int deg = end - start;
  float add = ad_[w];

  // phase A: lane l caches edge start+l (src, logit); online (max,expsum) incl. strided tail
  int s_reg = 0; float logit = -INFINITY;
  float m = -INFINITY, ssum = 0.f;
  if(lane < deg){
    s_reg = csr[start + lane];
    logit = lrelu(as_[s_reg] + add);
    m = logit; ssum = 1.f;
    for(int e = start + lane + 64; e < end; e += 64){
      int s = csr[e];
      float l = lrelu(as_[s] + add);
      if(l > m){ ssum = ssum * __expf(m - l) + 1.f; m = l; }
      else       ssum += __expf(l - m);
    }
  }
  #pragma unroll
  for(int off = 32; off > 0; off >>= 1){
    float mo = __shfl_xor(m, off);
    float so = __shfl_xor(ssum, off);
    float mn = fmaxf(m, mo);
    float ea = (m  > -INFINITY) ? __expf(m  - mn) : 0.f;
    float eb = (mo > -INFINITY) ? __expf(mo - mn) : 0.f;
    ssum = ssum * ea + so * eb;
    m = mn;
  }
  float inv = 1.f / (ssum + 1e-16f);
  float alpha_reg = __expf(logit - m) * inv;      // -INF logit -> 0

  // phase B: 4 edges per iteration, 16B row-slices; group g handles edge k+g
  float acc[8] = {};
  int nb = deg < 64 ? deg : 64;
  int g  = lane >> 4;
  int fo = (lane & 15) * 8;
  const short* hf = h + fo;
  for(int k = 0; k < nb; k += 4){
    int idx = k + g;
    if(idx < nb){
      float a = __shfl(alpha_reg, idx);
      int s   = __shfl(s_reg, idx);
      uint4 hv = *(const uint4*)(hf + (long)s * 128);
      acc[0] = fmaf(a, bflo(hv.x), acc[0]);
      acc[1] = fmaf(a, bfhi(hv.x), acc[1]);
      acc[2] = fmaf(a, bflo(hv.y), acc[2]);
      acc[3] = fmaf(a, bfhi(hv.y), acc[3]);
      acc[4] = fmaf(a, bflo(hv.z), acc[4]);
      acc[5] = fmaf(a, bfhi(hv.z), acc[5]);
      acc[6] = fmaf(a, bflo(hv.w), acc[6]);
      acc[7] = fmaf(a, bfhi(hv.w), acc[7]);
    }
  }
  for(int e = start + 64; e < end; ++e){          // rare overflow path (group 0 only)
    if(lane < 16){
      int s = csr[e];
      float l = lrelu(as_[s] + add);
      float a = __expf(l - m) * inv;
      uint4 hv = *(const uint4*)(hf + (long)s * 128);
      acc[0] = fmaf(a, bflo(hv.x), acc[0]);
      acc[1] = fmaf(a, bfhi(hv.x), acc[1]);
      acc[2] = fmaf(a, bflo(hv.y), acc[2]);
      acc[3] = fmaf(a, bfhi(hv.y), acc[3]);
      acc[4] = fmaf(a, bflo(hv.z), acc[4]);
      acc[5] = fmaf(a, bfhi(hv.z), acc[5]);
      acc[6] = fmaf(a, bflo(hv.w), acc[6]);
      acc[7] = fmaf(a, bfhi(hv.w), acc[7]);
    }
  }
  #pragma unroll
  for(int j = 0; j < 8; ++j){
    acc[j] += __shfl_xor(acc[j], 16);
    acc[j] += __shfl_xor(acc[j], 32);
  }
  if(lane < 16){
    float4 b0 = *(const float4*)(bias + fo);
    float4 b1 = *(const float4*)(bias + fo + 4);
    bf16x8 v;
    v[0] = f2bf(eluf(acc[0] + b0.x)); v[1] = f2bf(eluf(acc[1] + b0.y));
    v[2] = f2bf(eluf(acc[2] + b0.z)); v[3] = f2bf(eluf(acc[3] + b0.w));
    v[4] = f2bf(eluf(acc[4] + b1.x)); v[5] = f2bf(eluf(acc[5] + b1.y));
    v[6] = f2bf(eluf(acc[6] + b1.z)); v[7] = f2bf(eluf(acc[7] + b1.w));
    *(bf16x8*)(out + (long)w * 128 + fo) = v;
  }
}

// ======================= fused GCN aggregation: one wave per dst, bf16 h =======================
template<int F, bool BFOUT>
__global__ void k_gcn_agg(const int* __restrict__ rowptr, const int* __restrict__ csr,
                          const float* __restrict__ dinv, const short* __restrict__ h,
                          const float* __restrict__ bias, short* __restrict__ out_bf,
                          float* __restrict__ out_f, int N){
  constexpr int FPL = F / 16;                     // features per lane (4 or 2)
  int w = (int)(((long)blockIdx.x * blockDim.x + threadIdx.x) >> 6);
  int lane = threadIdx.x & 63;
  if(w >= N) return;
  int start = rowptr[w], end = rowptr[w + 1];
  int deg = end - start;
  float dd = dinv[w];
  int s_reg = 0; float dv_reg = 0.f;
  if(lane < deg){
    s_reg = csr[start + lane];
    dv_reg = dinv[s_reg];
  }
  float acc[FPL] = {};
  int nb = deg < 64 ? deg : 64;
  int g  = lane >> 4;
  int fo = (lane & 15) * FPL;
  const short* hf = h + fo;
  for(int k = 0; k < nb; k += 4){
    int idx = k + g;
    if(idx < nb){
      int s = __shfl(s_reg, idx);
      float nrm = dd * __shfl(dv_reg, idx);
      if(FPL == 4){
        uint2 hv = *(const uint2*)(hf + (long)s * F);
        acc[0] = fmaf(nrm, bflo(hv.x), acc[0]);
        acc[1] = fmaf(nrm, bfhi(hv.x), acc[1]);
        acc[2] = fmaf(nrm, bflo(hv.y), acc[2]);
        acc[3] = fmaf(nrm, bfhi(hv.y), acc[3]);
      }else{
        unsigned hv = *(const unsigned*)(hf + (long)s * F);
        acc[0] = fmaf(nrm, bflo(hv), acc[0]);
        acc[1] = fmaf(nrm, bfhi(hv), acc[1]);
      }
    }
  }
  for(int e = start + 64; e < end; ++e){          // rare overflow (group 0 only)
    if(lane < 16){
      int s = csr[e];
      float nrm = dd * dinv[s];
      if(FPL == 4){
        uint2 hv = *(const uint2*)(hf + (long)s * F);
        acc[0] = fmaf(nrm, bflo(hv.x), acc[0]);
        acc[1] = fmaf(nrm, bfhi(hv.x), acc[1]);
        acc[2] = fmaf(nrm, bflo(hv.y), acc[2]);
        acc[3] = fmaf(nrm, bfhi(hv.y), acc[3]);
      }else{
        unsigned hv = *(const unsigned*)(hf + (long)s * F);
        acc[0] = fmaf(nrm, bflo(hv), acc[0]);
        acc[1] = fmaf(nrm, bfhi(hv), acc[1]);
      }
    }
  }
  #pragma unroll
  for(int j = 0; j < FPL; ++j){
    acc[j] += __shfl_xor(acc[j], 16);
    acc[j] += __shfl_xor(acc[j], 32);
  }
  if(lane < 16){
    if(BFOUT){
      if(FPL == 4){
        bf16x4 v;
        #pragma unroll
        for(int j = 0; j < 4; ++j) v[j] = f2bf(eluf(acc[j] + bias[fo + j]));
        *(bf16x4*)(out_bf + (long)w * F + fo) = v;
      }else{
        #pragma unroll
        for(int j = 0; j < FPL; ++j)
          out_bf[(long)w * F + fo + j] = f2bf(eluf(acc[j] + bias[fo + j]));
      }
    }else{
      if(FPL == 2){
        float2 v2 = make_float2(eluf(acc[0] + bias[fo]), eluf(acc[1] + bias[fo + 1]));
        *(float2*)(out_f + (long)w * F + fo) = v2;
      }else{
        #pragma unroll
        for(int j = 0; j < FPL; ++j)
          out_f[(long)w * F + fo + j] = eluf(acc[j] + bias[fo + j]);
      }
    }
  }
}

// ============ per-graph softmax aggregation: chunked online (m,s,v) + combine ============
// S chunks per graph; chunk block computes online partials for 32 channels over its sub-range
template<int S>
__global__ void k_bagg_part(const float* __restrict__ h, const int* __restrict__ batch,
                            const float* __restrict__ t, float* __restrict__ pM,
                            float* __restrict__ pS, float* __restrict__ pV, int N){
  int chunk = blockIdx.x;
  int b = chunk / S, s = chunk % S;
  __shared__ int s_lo, s_hi;
  if(threadIdx.x == 0){
    int lo = 0, hi = N;
    while(lo < hi){ int mid = (lo + hi) >> 1; if(batch[mid] < b) lo = mid + 1; else hi = mid; }
    s_lo = lo;
    int lo2 = lo, hi2 = N;
    while(lo2 < hi2){ int mid = (lo2 + hi2) >> 1; if(batch[mid] < b + 1) lo2 = mid + 1; else hi2 = mid; }
    s_hi = lo2;
  }
  __syncthreads();
  int lo = s_lo, hi = s_hi;
  int len = hi - lo;
  int per = (len + S - 1) / S;
  int clo = lo + s * per;
  int chi = clo + per; if(chi > hi) chi = hi;
  float tv = t[0];
  int c = threadIdx.x & 31, r = threadIdx.x >> 5;   // 8 rows x 32 channels

  float m = -INFINITY, ss = 0.f, vv = 0.f;
  for(int i = clo + r; i < chi; i += 8){
    float hv = h[(long)i * 32 + c];
    float l = hv * tv;
    if(l > m){
      float e = (m > -INFINITY) ? __expf(m - l) : 0.f;
      ss = ss * e + 1.f; vv = vv * e + hv; m = l;
    }else{
      float e = __expf(l - m);
      ss += e; vv += e * hv;
    }
  }
  __shared__ float rm[8][32], rs[8][32], rv[8][32];
  rm[r][c] = m; rs[r][c] = ss; rv[r][c] = vv;
  __syncthreads();
  if(r == 0){
    float M = rm[0][c], SS = rs[0][c], VV = rv[0][c];
    #pragma unroll
    for(int k = 1; k < 8; ++k){
      float mo = rm[k][c], so = rs[k][c], vo = rv[k][c];
      float mn = fmaxf(M, mo);
      float ea = (M  > -INFINITY) ? __expf(M  - mn) : 0.f;
      float eb = (mo > -INFINITY) ? __expf(mo - mn) : 0.f;
      SS = SS * ea + so * eb; VV = VV * ea + vo * eb; M = mn;
    }
    pM[chunk * 32 + c] = M; pS[chunk * 32 + c] = SS; pV[chunk * 32 + c] = VV;
  }
}
template<int S>
__global__ void k_bagg_comb(const float* __restrict__ pM, const float* __restrict__ pS,
                            const float* __restrict__ pV, float* __restrict__ g, int B){
  int idx = blockIdx.x * blockDim.x + threadIdx.x;  // b*32 + c
  if(idx >= B * 32) return;
  int b = idx >> 5, c = idx & 31;
  float M = -INFINITY, SS = 0.f, VV = 0.f;
  #pragma unroll 4
  for(int k = 0; k < S; ++k){
    int p = (b * S + k) * 32 + c;
    float mo = pM[p], so = pS[p], vo = pV[p];
    float mn = fmaxf(M, mo);
    float ea = (M  > -INFINITY) ? __expf(M  - mn) : 0.f;
    float eb = (mo > -INFINITY) ? __expf(mo - mn) : 0.f;
    SS = SS * ea + so * eb; VV = VV * ea + vo * eb; M = mn;
  }
  g[idx] = VV / (SS + 1e-16f);
}

// ---- heads ----
__global__ void k_head(const float* __restrict__ g, const float* __restrict__ Wl1,
                       const float* __restrict__ bl1, const float* __restrict__ Wl2,
                       const float* __restrict__ bl2, float* __restrict__ out, int B){
  int b = blockIdx.x * blockDim.x + threadIdx.x;
  if(b >= B) return;
  float gr[32];
  #pragma unroll
  for(int k = 0; k < 32; ++k) gr[k] = g[b * 32 + k];
  float h1[16];
  #pragma unroll
  for(int j = 0; j < 16; ++j){
    float acc = bl1[j];
    #pragma unroll
    for(int k = 0; k < 32; ++k) acc = fmaf(gr[k], Wl1[k * 16 + j], acc);
    h1[j] = eluf(acc);
  }
  float l0 = bl2[0], l1 = bl2[1];
  #pragma unroll
  for(int k = 0; k < 16; ++k){
    l0 = fmaf(h1[k], Wl2[k * 2 + 0], l0);
    l1 = fmaf(h1[k], Wl2[k * 2 + 1], l1);
  }
  float mx = fmaxf(l0, l1);
  float lse = mx + __logf(__expf(l0 - mx) + __expf(l1 - mx));
  out[b * 2 + 0] = l0 - lse;
  out[b * 2 + 1] = l1 - lse;
}

extern "C" void kernel_launch(void* const* d_in, const int* in_sizes, int n_in,
                              void* d_out, int out_size, void* d_ws, size_t ws_size,
                              hipStream_t stream){
  const float* x     = (const float*)d_in[0];
  const int*   ei    = (const int*)d_in[1];
  const int*   batch = (const int*)d_in[2];
  const float* W1 = (const float*)d_in[3];
  const float* a1s = (const float*)d_in[4];
  const float* a1d = (const float*)d_in[5];
  const float* b1 = (const float*)d_in[6];
  const float* W2 = (const float*)d_in[7];
  const float* a2s = (const float*)d_in[8];
  const float* a2d = (const float*)d_in[9];
  const float* b2 = (const float*)d_in[10];
  const float* W3 = (const float*)d_in[11];
  const float* a3s = (const float*)d_in[12];
  const float* a3d = (const float*)d_in[13];
  const float* b3 = (const float*)d_in[14];
  const float* Wg1 = (const float*)d_in[15];
  const float* bg1 = (const float*)d_in[16];
  const float* Wg2 = (const float*)d_in[17];
  const float* bg2 = (const float*)d_in[18];
  const float* t   = (const float*)d_in[19];
  const float* Wl1 = (const float*)d_in[20];
  const float* bl1 = (const float*)d_in[21];
  const float* Wl2 = (const float*)d_in[22];
  const float* bl2 = (const float*)d_in[23];

  const int N = in_sizes[0];
  const int E = in_sizes[1] / 2;
  const int B = out_size / 2;
  const int ET = E + N;
  float* out = (float*)d_out;
  constexpr int BS = 32;                         // chunks per graph for batch agg

  // ---- workspace layout ----
  char* p = (char*)d_ws;
  short* Hbf  = (short*)p;            p += (size_t)N * 128 * 2;   // gemm/layer out (bf16)
  short* Abf  = (short*)p;            p += (size_t)N * 128 * 2;   // agg out (bf16)
  float* A32  = (float*)p;            p += (size_t)N * 32 * 4;    // final GCN out (fp32)
  float* as_  = (float*)p;            p += (size_t)N * 4;
  float* ad_  = (float*)p;            p += (size_t)N * 4;
  float* dinv = (float*)p;            p += (size_t)N * 4;
  int*   deg    = (int*)p;            p += (size_t)N * 4;
  int*   rowptr = (int*)p;            p += (size_t)(N + 1) * 4;
  int*   cursor = (int*)p;            p += (size_t)N * 4;
  int*   csr    = (int*)p;            p += (size_t)ET * 4;
  int*   bsum   = (int*)p;            p += (size_t)1024 * 4;
  p = alignp(p, 16);
  short* Wp2  = (short*)p;            p += 128 * 128 * 2;
  short* Wp3  = (short*)p;            p += 128 * 128 * 2;
  short* Wpg1 = (short*)p;            p += 128 * 64 * 2;
  short* Wpg2 = (short*)p;            p += 64 * 32 * 2;
  p = alignp(p, 16);
  float* S    = (float*)p;            p += 16 * 4;
  float* pM   = (float*)p;            p += (size_t)B * BS * 32 * 4;
  float* pSb  = (float*)p;            p += (size_t)B * BS * 32 * 4;
  float* pV   = (float*)p;            p += (size_t)B * BS * 32 * 4;
  float* g    = (float*)p;

  const int T = 256;
  const int gN  = cdiv(N, T);
  const int gE  = cdiv(E, T);
  const int gET = cdiv(ET, T);
  const int gW  = cdiv((long)N * 64, T);         // wave-per-dst grids
  const int gG  = cdiv(N, 64);                   // mfma gemm: 64 rows/block
  const int NB  = cdiv(N, 256);                  // scan blocks (<=1024)

  // ---------- CSR build + weight packs ----------
  k_deg_init<<<dim3(gN), dim3(T), 0, stream>>>(deg, N);
  k_deg_count<<<dim3(gE), dim3(T), 0, stream>>>(ei, E, deg);
  k_scan_part<<<dim3(NB), dim3(256), 0, stream>>>(deg, bsum, N);
  k_scan_mid<<<dim3(1), dim3(1024), 0, stream>>>(bsum, NB, rowptr, N);
  k_scan_fin<<<dim3(NB), dim3(256), 0, stream>>>(deg, bsum, rowptr, cursor, N);
  k_fill<<<dim3(gET), dim3(T), 0, stream>>>(ei, E, N, cursor, csr);
  k_dinv<<<dim3(gN), dim3(T), 0, stream>>>(deg, dinv, N);
  k_pack_w<128,128><<<dim3(8), dim3(T), 0, stream>>>(W2, Wp2);
  k_pack_w<128,128><<<dim3(8), dim3(T), 0, stream>>>(W3, Wp3);
  k_pack_w<128, 64><<<dim3(4), dim3(T), 0, stream>>>(Wg1, Wpg1);
  k_pack_w< 64, 32><<<dim3(1), dim3(T), 0, stream>>>(Wg2, Wpg2);
  k_dot128<<<dim3(1), dim3(128), 0, stream>>>(W1, a1s, a1d, S);

  // ---------- GAT layer 1 (1 -> 128): outer product ----------
  k_l1v<<<dim3(cdiv((long)N * 16, T)), dim3(T), 0, stream>>>(x, W1, Hbf, N);
  k_l1dots<<<dim3(gN), dim3(T), 0, stream>>>(x, S, as_, ad_, N);
  k_gat_agg<<<dim3(gW), dim3(T), 0, stream>>>(rowptr, csr, as_, ad_, Hbf, b1, Abf, N);

  // ---------- GAT layer 2 (128 -> 128) ----------
  k_gemm_mfma<128,128,true><<<dim3(gG), dim3(T), 0, stream>>>(Abf, Wp2, Hbf, a2s, a2d, as_, ad_, N);
  k_gat_agg<<<dim3(gW), dim3(T), 0, stream>>>(rowptr, csr, as_, ad_, Hbf, b2, Abf, N);

  // ---------- GAT layer 3 (128 -> 128) ----------
  k_gemm_mfma<128,128,true><<<dim3(gG), dim3(T), 0, stream>>>(Abf, Wp3, Hbf, a3s, a3d, as_, ad_, N);
  k_gat_agg<<<dim3(gW), dim3(T), 0, stream>>>(rowptr, csr, as_, ad_, Hbf, b3, Abf, N);

  // ---------- GCN layer 1 (128 -> 64) ----------
  k_gemm_mfma<128,64,false><<<dim3(gG), dim3(T), 0, stream>>>(Abf, Wpg1, Hbf, nullptr, nullptr, nullptr, nullptr, N);
  k_gcn_agg<64,true><<<dim3(gW), dim3(T), 0, stream>>>(rowptr, csr, dinv, Hbf, bg1, Abf, (float*)nullptr, N);

  // ---------- GCN layer 2 (64 -> 32) ----------
  k_gemm_mfma<64,32,false><<<dim3(gG), dim3(T), 0, stream>>>(Abf, Wpg2, Hbf, nullptr, nullptr, nullptr, nullptr, N);
  k_gcn_agg<32,false><<<dim3(gW), dim3(T), 0, stream>>>(rowptr, csr, dinv, Hbf, bg2, (short*)nullptr, A32, N);

  // ---------- per-graph softmax aggregation (chunked online) ----------
  k_bagg_part<BS><<<dim3(B * BS), dim3(256), 0, stream>>>(A32, batch, t, pM, pSb, pV, N);
  k_bagg_comb<BS><<<dim3(cdiv(B * 32, 256)), dim3(256), 0, stream>>>(pM, pSb, pV, g, B);

  // ---------- MLP heads + log_softmax ----------
  k_head<<<dim3(cdiv(B, 64)), dim3(64), 0, stream>>>(g, Wl1, bl1, Wl2, bl2, out, B);
}

// Round 8
// 315.352 us; speedup vs baseline: 6.5927x; 1.0789x over previous
//
#include <hip/hip_runtime.h>
#include <math.h>

static inline int cdiv(long a, long b){ return (int)((a + b - 1) / b); }
static inline char* alignp(char* p, size_t a){ return (char*)(((uintptr_t)p + a - 1) & ~(uintptr_t)(a - 1)); }

typedef __attribute__((ext_vector_type(8))) short bf16x8;
typedef __attribute__((ext_vector_type(4))) short bf16x4;
typedef __attribute__((ext_vector_type(4))) float f32x4;

__device__ __forceinline__ float lrelu(float x){ return x > 0.f ? x : 0.2f * x; }
__device__ __forceinline__ float eluf(float x){ return x > 0.f ? x : __expf(x) - 1.f; }
__device__ __forceinline__ short f2bf(float f){            // RNE f32 -> bf16 bits
  unsigned u = __float_as_uint(f);
  return (short)((u + 0x7FFFu + ((u >> 16) & 1u)) >> 16);
}
__device__ __forceinline__ float bflo(unsigned v){ return __uint_as_float(v << 16); }
__device__ __forceinline__ float bfhi(unsigned v){ return __uint_as_float(v & 0xFFFF0000u); }

// ======================= MFMA GEMM: outb[N,FOUT](bf16) = Abf[N,K] @ W[K,FOUT] =======================
// Optional fused attention dots: as_[r] = h[r,:]·av_s ; ad_[r] = h[r,:]·av_d
template<int K, int FOUT, bool DOTS>
__global__ void k_gemm_mfma(const short* __restrict__ Abf, const short* __restrict__ Wp,
                            short* __restrict__ outb,
                            const float* __restrict__ av_s, const float* __restrict__ av_d,
                            float* __restrict__ as_, float* __restrict__ ad_, int N){
  constexpr int NKS = K / 32, NCT = FOUT / 16;
  int wid  = threadIdx.x >> 6;
  int lane = threadIdx.x & 63;
  int rowbase = (blockIdx.x * 4 + wid) * 16;
  if(rowbase >= N) return;
  int arow = rowbase + (lane & 15);
  if(arow >= N) arow = N - 1;                     // clamp; clamped rows never stored
  f32x4 acc[NCT] = {};
  const short* ap = Abf + (long)arow * K + (lane >> 4) * 8;
  #pragma unroll
  for(int ks = 0; ks < NKS; ++ks){
    bf16x8 a = *(const bf16x8*)(ap + ks * 32);
    #pragma unroll
    for(int ct = 0; ct < NCT; ++ct){
      bf16x8 b = *(const bf16x8*)(Wp + ((ks * NCT + ct) * 64 + lane) * 8);
      acc[ct] = __builtin_amdgcn_mfma_f32_16x16x32_bf16(a, b, acc[ct], 0, 0, 0);
    }
  }
  int r0 = rowbase + (lane >> 4) * 4;             // D: row=(lane>>4)*4+j, col=lane&15
  int c0 = lane & 15;
  #pragma unroll
  for(int j = 0; j < 4; ++j){
    int r = r0 + j;
    if(r < N){
      #pragma unroll
      for(int ct = 0; ct < NCT; ++ct)
        outb[(long)r * FOUT + ct * 16 + c0] = f2bf(acc[ct][j]);
    }
  }
  if(DOTS){
    float avs[NCT], avd[NCT];
    #pragma unroll
    for(int ct = 0; ct < NCT; ++ct){ avs[ct] = av_s[ct * 16 + c0]; avd[ct] = av_d[ct * 16 + c0]; }
    #pragma unroll
    for(int j = 0; j < 4; ++j){
      float ps = 0.f, pd = 0.f;
      #pragma unroll
      for(int ct = 0; ct < NCT; ++ct){
        float hv = acc[ct][j];
        ps = fmaf(hv, avs[ct], ps);
        pd = fmaf(hv, avd[ct], pd);
      }
      #pragma unroll
      for(int off = 1; off < 16; off <<= 1){
        ps += __shfl_xor(ps, off);
        pd += __shfl_xor(pd, off);
      }
      int r = r0 + j;
      if(c0 == 0 && r < N){ as_[r] = ps; ad_[r] = pd; }
    }
  }
}

template<int K, int FOUT>
__global__ void k_pack_w(const float* __restrict__ W, short* __restrict__ Wp){
  constexpr int NKS = K / 32, NCT = FOUT / 16;
  int idx = blockIdx.x * blockDim.x + threadIdx.x;
  if(idx >= NKS * NCT * 64) return;
  int lane = idx & 63;
  int ct = (idx >> 6) % NCT;
  int ks = (idx >> 6) / NCT;
  int col = ct * 16 + (lane & 15);
  int kb  = ks * 32 + (lane >> 4) * 8;
  #pragma unroll
  for(int j = 0; j < 8; ++j) Wp[idx * 8 + j] = f2bf(W[(kb + j) * FOUT + col]);
}

// ======================= layer 1: outer product + dots =======================
__global__ void k_dot128(const float* __restrict__ W1, const float* __restrict__ a1s,
                         const float* __restrict__ a1d, float* __restrict__ S){
  __shared__ float s1[128], s2[128];
  int t = threadIdx.x;
  float w = W1[t];
  s1[t] = w * a1s[t]; s2[t] = w * a1d[t];
  __syncthreads();
  for(int off = 64; off > 0; off >>= 1){
    if(t < off){ s1[t] += s1[t + off]; s2[t] += s2[t + off]; }
    __syncthreads();
  }
  if(t == 0){ S[0] = s1[0]; S[1] = s2[0]; }
}
// vectorized: thread per 8 features; 16B stores
__global__ void k_l1v(const float* __restrict__ x, const float* __restrict__ W1,
                      short* __restrict__ outb, int N){
  long idx = (long)blockIdx.x * blockDim.x + threadIdx.x;
  if(idx >= (long)N * 16) return;
  int node = (int)(idx >> 4), j8 = ((int)idx & 15) * 8;
  float xv = x[node];
  float4 w0 = *(const float4*)(W1 + j8);
  float4 w1 = *(const float4*)(W1 + j8 + 4);
  bf16x8 v;
  v[0] = f2bf(xv * w0.x); v[1] = f2bf(xv * w0.y);
  v[2] = f2bf(xv * w0.z); v[3] = f2bf(xv * w0.w);
  v[4] = f2bf(xv * w1.x); v[5] = f2bf(xv * w1.y);
  v[6] = f2bf(xv * w1.z); v[7] = f2bf(xv * w1.w);
  *(bf16x8*)(outb + (long)node * 128 + j8) = v;
}
__global__ void k_l1dots(const float* __restrict__ x, const float* __restrict__ S,
                         float* __restrict__ as_, float* __restrict__ ad_, int N){
  int i = blockIdx.x * blockDim.x + threadIdx.x;
  if(i >= N) return;
  float xv = x[i];
  as_[i] = xv * S[0]; ad_[i] = xv * S[1];
}

// ======================= CSR build (dst-sorted, with self-loops) =======================
__global__ void k_deg_init(int* __restrict__ deg, int N){
  int i = blockIdx.x * blockDim.x + threadIdx.x;
  if(i < N) deg[i] = 1;
}
__global__ void k_deg_count(const int* __restrict__ ei, int E, int* __restrict__ deg){
  int e = blockIdx.x * blockDim.x + threadIdx.x;
  if(e < E) atomicAdd(&deg[ei[E + e]], 1);
}

// ---- hierarchical exclusive scan of deg[N] -> rowptr[N+1], cursor[N] ----
__global__ void k_scan_part(const int* __restrict__ deg, int* __restrict__ bsum, int N){
  __shared__ int red[256];
  int i = blockIdx.x * 256 + threadIdx.x;
  int v = (i < N) ? deg[i] : 0;
  red[threadIdx.x] = v;
  __syncthreads();
  #pragma unroll
  for(int off = 128; off > 0; off >>= 1){
    if(threadIdx.x < off) red[threadIdx.x] += red[threadIdx.x + off];
    __syncthreads();
  }
  if(threadIdx.x == 0) bsum[blockIdx.x] = red[0];
}
__global__ void k_scan_mid(int* __restrict__ bsum, int NB, int* __restrict__ rowptr, int N){
  __shared__ int buf[1024];
  int t = threadIdx.x;
  int v = (t < NB) ? bsum[t] : 0;
  buf[t] = v;
  __syncthreads();
  for(int off = 1; off < 1024; off <<= 1){
    int u = (t >= off) ? buf[t - off] : 0;
    __syncthreads();
    buf[t] += u;
    __syncthreads();
  }
  if(t < NB) bsum[t] = buf[t] - v;                // exclusive
  if(t == 1023) rowptr[N] = buf[1023];
}
__global__ void k_scan_fin(const int* __restrict__ deg, const int* __restrict__ bsum,
                           int* __restrict__ rowptr, int* __restrict__ cursor, int N){
  __shared__ int buf[256];
  int i = blockIdx.x * 256 + threadIdx.x;
  int t = threadIdx.x;
  int v = (i < N) ? deg[i] : 0;
  buf[t] = v;
  __syncthreads();
  #pragma unroll
  for(int off = 1; off < 256; off <<= 1){
    int u = (t >= off) ? buf[t - off] : 0;
    __syncthreads();
    buf[t] += u;
    __syncthreads();
  }
  if(i < N){
    int ex = buf[t] - v + bsum[blockIdx.x];
    rowptr[i] = ex; cursor[i] = ex;
  }
}

__global__ void k_fill(const int* __restrict__ ei, int E, int N,
                       int* __restrict__ cursor, int* __restrict__ csr_src){
  int e = blockIdx.x * blockDim.x + threadIdx.x;
  if(e >= E + N) return;
  int s, d;
  if(e < E){ s = ei[e]; d = ei[E + e]; } else { s = e - E; d = s; }
  int pos = atomicAdd(&cursor[d], 1);
  csr_src[pos] = s;
}
__global__ void k_dinv(const int* __restrict__ deg, float* __restrict__ dinv, int N){
  int i = blockIdx.x * blockDim.x + threadIdx.x;
  if(i < N) dinv[i] = rsqrtf((float)deg[i]);
}

// ======================= fused GAT aggregation: one wave per dst, bf16 h =======================
__global__ void k_gat_agg(const int* __restrict__ rowptr, const int* __restrict__ csr,
                          const float* __restrict__ as_, const float* __restrict__ ad_,
                          const short* __restrict__ h, const float* __restrict__ bias,
                          short* __restrict__ out, int N){
  int w = (int)(((long)blockIdx.x * blockDim.x + threadIdx.x) >> 6);
  int lane = threadIdx.x & 63;
  if(w >= N) return;
  int start = rowptr[w], end = rowptr[w + 1];
  int deg = end - start;
  float add = ad_[w];

  int s_reg = 0;
  float alpha_reg = 0.f, m, inv;
  if(deg <= 64){
    // ---- fast path: lane l owns edge start+l; 3-phase softmax, 1 exp/lane ----
    float logit = -INFINITY;
    if(lane < deg){
      s_reg = csr[start + lane];
      logit = lrelu(as_[s_reg] + add);
    }
    m = logit;
    #pragma unroll
    for(int off = 32; off > 0; off >>= 1) m = fmaxf(m, __shfl_xor(m, off));
    float e = __expf(logit - m);                  // inactive lanes: exp(-INF)=0
    float ssum = e;
    #pragma unroll
    for(int off = 32; off > 0; off >>= 1) ssum += __shfl_xor(ssum, off);
    inv = 1.f / (ssum + 1e-16f);
    alpha_reg = e * inv;
  }else{
    // ---- rare overflow path: online (max,expsum) with strided tail ----
    float logit = -INFINITY, ssum = 0.f;
    m = -INFINITY;
    if(lane < deg){
      s_reg = csr[start + lane];
      logit = lrelu(as_[s_reg] + add);
      m = logit; ssum = 1.f;
      for(int e = start + lane + 64; e < end; e += 64){
        int s = csr[e];
        float l = lrelu(as_[s] + add);
        if(l > m){ ssum = ssum * __expf(m - l) + 1.f; m = l; }
        else       ssum += __expf(l - m);
      }
    }
    #pragma unroll
    for(int off = 32; off > 0; off >>= 1){
      float mo = __shfl_xor(m, off);
      float so = __shfl_xor(ssum, off);
      float mn = fmaxf(m, mo);
      float ea = (m  > -INFINITY) ? __expf(m  - mn) : 0.f;
      float eb = (mo > -INFINITY) ? __expf(mo - mn) : 0.f;
      ssum = ssum * ea + so * eb;
      m = mn;
    }
    inv = 1.f / (ssum + 1e-16f);
    alpha_reg = __expf(logit - m) * inv;
  }

  // phase B: 4 edges per iteration, 16B row-slices; group g handles edge k+g
  float acc[8] = {};
  int nb = deg < 64 ? deg : 64;
  int g  = lane >> 4;
  int fo = (lane & 15) * 8;
  const short* hf = h + fo;
  for(int k = 0; k < nb; k += 4){
    int idx = k + g;
    if(idx < nb){
      float a = __shfl(alpha_reg, idx);
      int s   = __shfl(s_reg, idx);
      uint4 hv = *(const uint4*)(hf + (long)s * 128);
      acc[0] = fmaf(a, bflo(hv.x), acc[0]);
      acc[1] = fmaf(a, bfhi(hv.x), acc[1]);
      acc[2] = fmaf(a, bflo(hv.y), acc[2]);
      acc[3] = fmaf(a, bfhi(hv.y), acc[3]);
      acc[4] = fmaf(a, bflo(hv.z), acc[4]);
      acc[5] = fmaf(a, bfhi(hv.z), acc[5]);
      acc[6] = fmaf(a, bflo(hv.w), acc[6]);
      acc[7] = fmaf(a, bfhi(hv.w), acc[7]);
    }
  }
  for(int e = start + 64; e < end; ++e){          // rare overflow path (group 0 only)
    if(lane < 16){
      int s = csr[e];
      float l = lrelu(as_[s] + add);
      float a = __expf(l - m) * inv;
      uint4 hv = *(const uint4*)(hf + (long)s * 128);
      acc[0] = fmaf(a, bflo(hv.x), acc[0]);
      acc[1] = fmaf(a, bfhi(hv.x), acc[1]);
      acc[2] = fmaf(a, bflo(hv.y), acc[2]);
      acc[3] = fmaf(a, bfhi(hv.y), acc[3]);
      acc[4] = fmaf(a, bflo(hv.z), acc[4]);
      acc[5] = fmaf(a, bfhi(hv.z), acc[5]);
      acc[6] = fmaf(a, bflo(hv.w), acc[6]);
      acc[7] = fmaf(a, bfhi(hv.w), acc[7]);
    }
  }
  #pragma unroll
  for(int j = 0; j < 8; ++j){
    acc[j] += __shfl_xor(acc[j], 16);
    acc[j] += __shfl_xor(acc[j], 32);
  }
  if(lane < 16){
    float4 b0 = *(const float4*)(bias + fo);
    float4 b1 = *(const float4*)(bias + fo + 4);
    bf16x8 v;
    v[0] = f2bf(eluf(acc[0] + b0.x)); v[1] = f2bf(eluf(acc[1] + b0.y));
    v[2] = f2bf(eluf(acc[2] + b0.z)); v[3] = f2bf(eluf(acc[3] + b0.w));
    v[4] = f2bf(eluf(acc[4] + b1.x)); v[5] = f2bf(eluf(acc[5] + b1.y));
    v[6] = f2bf(eluf(acc[6] + b1.z)); v[7] = f2bf(eluf(acc[7] + b1.w));
    *(bf16x8*)(out + (long)w * 128 + fo) = v;
  }
}

// ======================= fused GCN aggregation: one wave per dst, bf16 h =======================
template<int F, bool BFOUT>
__global__ void k_gcn_agg(const int* __restrict__ rowptr, const int* __restrict__ csr,
                          const float* __restrict__ dinv, const short* __restrict__ h,
                          const float* __restrict__ bias, short* __restrict__ out_bf,
                          float* __restrict__ out_f, int N){
  constexpr int FPL = F / 16;                     // features per lane (4 or 2)
  int w = (int)(((long)blockIdx.x * blockDim.x + threadIdx.x) >> 6);
  int lane = threadIdx.x & 63;
  if(w >= N) return;
  int start = rowptr[w], end = rowptr[w + 1];
  int deg = end - start;
  float dd = dinv[w];
  int s_reg = 0; float dv_reg = 0.f;
  if(lane < deg){
    s_reg = csr[start + lane];
    dv_reg = dinv[s_reg];
  }
  float acc[FPL] = {};
  int nb = deg < 64 ? deg : 64;
  int g  = lane >> 4;
  int fo = (lane & 15) * FPL;
  const short* hf = h + fo;
  for(int k = 0; k < nb; k += 4){
    int idx = k + g;
    if(idx < nb){
      int s = __shfl(s_reg, idx);
      float nrm = dd * __shfl(dv_reg, idx);
      if(FPL == 4){
        uint2 hv = *(const uint2*)(hf + (long)s * F);
        acc[0] = fmaf(nrm, bflo(hv.x), acc[0]);
        acc[1] = fmaf(nrm, bfhi(hv.x), acc[1]);
        acc[2] = fmaf(nrm, bflo(hv.y), acc[2]);
        acc[3] = fmaf(nrm, bfhi(hv.y), acc[3]);
      }else{
        unsigned hv = *(const unsigned*)(hf + (long)s * F);
        acc[0] = fmaf(nrm, bflo(hv), acc[0]);
        acc[1] = fmaf(nrm, bfhi(hv), acc[1]);
      }
    }
  }
  for(int e = start + 64; e < end; ++e){          // rare overflow (group 0 only)
    if(lane < 16){
      int s = csr[e];
      float nrm = dd * dinv[s];
      if(FPL == 4){
        uint2 hv = *(const uint2*)(hf + (long)s * F);
        acc[0] = fmaf(nrm, bflo(hv.x), acc[0]);
        acc[1] = fmaf(nrm, bfhi(hv.x), acc[1]);
        acc[2] = fmaf(nrm, bflo(hv.y), acc[2]);
        acc[3] = fmaf(nrm, bfhi(hv.y), acc[3]);
      }else{
        unsigned hv = *(const unsigned*)(hf + (long)s * F);
        acc[0] = fmaf(nrm, bflo(hv), acc[0]);
        acc[1] = fmaf(nrm, bfhi(hv), acc[1]);
      }
    }
  }
  #pragma unroll
  for(int j = 0; j < FPL; ++j){
    acc[j] += __shfl_xor(acc[j], 16);
    acc[j] += __shfl_xor(acc[j], 32);
  }
  if(lane < 16){
    if(BFOUT){
      if(FPL == 4){
        bf16x4 v;
        #pragma unroll
        for(int j = 0; j < 4; ++j) v[j] = f2bf(eluf(acc[j] + bias[fo + j]));
        *(bf16x4*)(out_bf + (long)w * F + fo) = v;
      }else{
        #pragma unroll
        for(int j = 0; j < FPL; ++j)
          out_bf[(long)w * F + fo + j] = f2bf(eluf(acc[j] + bias[fo + j]));
      }
    }else{
      if(FPL == 2){
        float2 v2 = make_float2(eluf(acc[0] + bias[fo]), eluf(acc[1] + bias[fo + 1]));
        *(float2*)(out_f + (long)w * F + fo) = v2;
      }else{
        #pragma unroll
        for(int j = 0; j < FPL; ++j)
          out_f[(long)w * F + fo + j] = eluf(acc[j] + bias[fo + j]);
      }
    }
  }
}

// ============ per-graph softmax aggregation: chunked online (m,s,v) + combine ============
template<int S>
__global__ void k_bagg_part(const float* __restrict__ h, const int* __restrict__ batch,
                            const float* __restrict__ t, float* __restrict__ pM,
                            float* __restrict__ pS, float* __restrict__ pV, int N){
  int chunk = blockIdx.x;
  int b = chunk / S, s = chunk % S;
  __shared__ int s_lo, s_hi;
  if(threadIdx.x == 0){
    int lo = 0, hi = N;
    while(lo < hi){ int mid = (lo + hi) >> 1; if(batch[mid] < b) lo = mid + 1; else hi = mid; }
    s_lo = lo;
    int lo2 = lo, hi2 = N;
    while(lo2 < hi2){ int mid = (lo2 + hi2) >> 1; if(batch[mid] < b + 1) lo2 = mid + 1; else hi2 = mid; }
    s_hi = lo2;
  }
  __syncthreads();
  int lo = s_lo, hi = s_hi;
  int len = hi - lo;
  int per = (len + S - 1) / S;
  int clo = lo + s * per;
  int chi = clo + per; if(chi > hi) chi = hi;
  float tv = t[0];
  int c = threadIdx.x & 31, r = threadIdx.x >> 5;   // 8 rows x 32 channels

  float m = -INFINITY, ss = 0.f, vv = 0.f;
  for(int i = clo + r; i < chi; i += 8){
    float hv = h[(long)i * 32 + c];
    float l = hv * tv;
    if(l > m){
      float e = (m > -INFINITY) ? __expf(m - l) : 0.f;
      ss = ss * e + 1.f; vv = vv * e + hv; m = l;
    }else{
      float e = __expf(l - m);
      ss += e; vv += e * hv;
    }
  }
  __shared__ float rm[8][32], rs[8][32], rv[8][32];
  rm[r][c] = m; rs[r][c] = ss; rv[r][c] = vv;
  __syncthreads();
  if(r == 0){
    float M = rm[0][c], SS = rs[0][c], VV = rv[0][c];
    #pragma unroll
    for(int k = 1; k < 8; ++k){
      float mo = rm[k][c], so = rs[k][c], vo = rv[k][c];
      float mn = fmaxf(M, mo);
      float ea = (M  > -INFINITY) ? __expf(M  - mn) : 0.f;
      float eb = (mo > -INFINITY) ? __expf(mo - mn) : 0.f;
      SS = SS * ea + so * eb; VV = VV * ea + vo * eb; M = mn;
    }
    pM[chunk * 32 + c] = M; pS[chunk * 32 + c] = SS; pV[chunk * 32 + c] = VV;
  }
}
template<int S>
__global__ void k_bagg_comb(const float* __restrict__ pM, const float* __restrict__ pS,
                            const float* __restrict__ pV, float* __restrict__ g, int B){
  int idx = blockIdx.x * blockDim.x + threadIdx.x;  // b*32 + c
  if(idx >= B * 32) return;
  int b = idx >> 5, c = idx & 31;
  float M = -INFINITY, SS = 0.f, VV = 0.f;
  #pragma unroll 4
  for(int k = 0; k < S; ++k){
    int p = (b * S + k) * 32 + c;
    float mo = pM[p], so = pS[p], vo = pV[p];
    float mn = fmaxf(M, mo);
    float ea = (M  > -INFINITY) ? __expf(M  - mn) : 0.f;
    float eb = (mo > -INFINITY) ? __expf(mo - mn) : 0.f;
    SS = SS * ea + so * eb; VV = VV * ea + vo * eb; M = mn;
  }
  g[idx] = VV / (SS + 1e-16f);
}

// ---- heads ----
__global__ void k_head(const float* __restrict__ g, const float* __restrict__ Wl1,
                       const float* __restrict__ bl1, const float* __restrict__ Wl2,
                       const float* __restrict__ bl2, float* __restrict__ out, int B){
  int b = blockIdx.x * blockDim.x + threadIdx.x;
  if(b >= B) return;
  float gr[32];
  #pragma unroll
  for(int k = 0; k < 32; ++k) gr[k] = g[b * 32 + k];
  float h1[16];
  #pragma unroll
  for(int j = 0; j < 16; ++j){
    float acc = bl1[j];
    #pragma unroll
    for(int k = 0; k < 32; ++k) acc = fmaf(gr[k], Wl1[k * 16 + j], acc);
    h1[j] = eluf(acc);
  }
  float l0 = bl2[0], l1 = bl2[1];
  #pragma unroll
  for(int k = 0; k < 16; ++k){
    l0 = fmaf(h1[k], Wl2[k * 2 + 0], l0);
    l1 = fmaf(h1[k], Wl2[k * 2 + 1], l1);
  }
  float mx = fmaxf(l0, l1);
  float lse = mx + __logf(__expf(l0 - mx) + __expf(l1 - mx));
  out[b * 2 + 0] = l0 - lse;
  out[b * 2 + 1] = l1 - lse;
}

extern "C" void kernel_launch(void* const* d_in, const int* in_sizes, int n_in,
                              void* d_out, int out_size, void* d_ws, size_t ws_size,
                              hipStream_t stream){
  const float* x     = (const float*)d_in[0];
  const int*   ei    = (const int*)d_in[1];
  const int*   batch = (const int*)d_in[2];
  const float* W1 = (const float*)d_in[3];
  const float* a1s = (const float*)d_in[4];
  const float* a1d = (const float*)d_in[5];
  const float* b1 = (const float*)d_in[6];
  const float* W2 = (const float*)d_in[7];
  const float* a2s = (const float*)d_in[8];
  const float* a2d = (const float*)d_in[9];
  const float* b2 = (const float*)d_in[10];
  const float* W3 = (const float*)d_in[11];
  const float* a3s = (const float*)d_in[12];
  const float* a3d = (const float*)d_in[13];
  const float* b3 = (const float*)d_in[14];
  const float* Wg1 = (const float*)d_in[15];
  const float* bg1 = (const float*)d_in[16];
  const float* Wg2 = (const float*)d_in[17];
  const float* bg2 = (const float*)d_in[18];
  const float* t   = (const float*)d_in[19];
  const float* Wl1 = (const float*)d_in[20];
  const float* bl1 = (const float*)d_in[21];
  const float* Wl2 = (const float*)d_in[22];
  const float* bl2 = (const float*)d_in[23];

  const int N = in_sizes[0];
  const int E = in_sizes[1] / 2;
  const int B = out_size / 2;
  const int ET = E + N;
  float* out = (float*)d_out;
  constexpr int BS = 32;                         // chunks per graph for batch agg

  // ---- workspace layout ----
  char* p = (char*)d_ws;
  short* Hbf  = (short*)p;            p += (size_t)N * 128 * 2;   // gemm/layer out (bf16)
  short* Abf  = (short*)p;            p += (size_t)N * 128 * 2;   // agg out (bf16)
  float* A32  = (float*)p;            p += (size_t)N * 32 * 4;    // final GCN out (fp32)
  float* as_  = (float*)p;            p += (size_t)N * 4;
  float* ad_  = (float*)p;            p += (size_t)N * 4;
  float* dinv = (float*)p;            p += (size_t)N * 4;
  int*   deg    = (int*)p;            p += (size_t)N * 4;
  int*   rowptr = (int*)p;            p += (size_t)(N + 1) * 4;
  int*   cursor = (int*)p;            p += (size_t)N * 4;
  int*   csr    = (int*)p;            p += (size_t)ET * 4;
  int*   bsum   = (int*)p;            p += (size_t)1024 * 4;
  p = alignp(p, 16);
  short* Wp2  = (short*)p;            p += 128 * 128 * 2;
  short* Wp3  = (short*)p;            p += 128 * 128 * 2;
  short* Wpg1 = (short*)p;            p += 128 * 64 * 2;
  short* Wpg2 = (short*)p;            p += 64 * 32 * 2;
  p = alignp(p, 16);
  float* S    = (float*)p;            p += 16 * 4;
  float* pM   = (float*)p;            p += (size_t)B * BS * 32 * 4;
  float* pSb  = (float*)p;            p += (size_t)B * BS * 32 * 4;
  float* pV   = (float*)p;            p += (size_t)B * BS * 32 * 4;
  float* g    = (float*)p;

  const int T = 256;
  const int gN  = cdiv(N, T);
  const int gE  = cdiv(E, T);
  const int gET = cdiv(ET, T);
  const int gW  = cdiv((long)N * 64, T);         // wave-per-dst grids
  const int gG  = cdiv(N, 64);                   // mfma gemm: 64 rows/block
  const int NB  = cdiv(N, 256);                  // scan blocks (<=1024)

  // ---------- CSR build + weight packs ----------
  k_deg_init<<<dim3(gN), dim3(T), 0, stream>>>(deg, N);
  k_deg_count<<<dim3(gE), dim3(T), 0, stream>>>(ei, E, deg);
  k_scan_part<<<dim3(NB), dim3(256), 0, stream>>>(deg, bsum, N);
  k_scan_mid<<<dim3(1), dim3(1024), 0, stream>>>(bsum, NB, rowptr, N);
  k_scan_fin<<<dim3(NB), dim3(256), 0, stream>>>(deg, bsum, rowptr, cursor, N);
  k_fill<<<dim3(gET), dim3(T), 0, stream>>>(ei, E, N, cursor, csr);
  k_dinv<<<dim3(gN), dim3(T), 0, stream>>>(deg, dinv, N);
  k_pack_w<128,128><<<dim3(8), dim3(T), 0, stream>>>(W2, Wp2);
  k_pack_w<128,128><<<dim3(8), dim3(T), 0, stream>>>(W3, Wp3);
  k_pack_w<128, 64><<<dim3(4), dim3(T), 0, stream>>>(Wg1, Wpg1);
  k_pack_w< 64, 32><<<dim3(1), dim3(T), 0, stream>>>(Wg2, Wpg2);
  k_dot128<<<dim3(1), dim3(128), 0, stream>>>(W1, a1s, a1d, S);

  // ---------- GAT layer 1 (1 -> 128): outer product ----------
  k_l1v<<<dim3(cdiv((long)N * 16, T)), dim3(T), 0, stream>>>(x, W1, Hbf, N);
  k_l1dots<<<dim3(gN), dim3(T), 0, stream>>>(x, S, as_, ad_, N);
  k_gat_agg<<<dim3(gW), dim3(T), 0, stream>>>(rowptr, csr, as_, ad_, Hbf, b1, Abf, N);

  // ---------- GAT layer 2 (128 -> 128) ----------
  k_gemm_mfma<128,128,true><<<dim3(gG), dim3(T), 0, stream>>>(Abf, Wp2, Hbf, a2s, a2d, as_, ad_, N);
  k_gat_agg<<<dim3(gW), dim3(T), 0, stream>>>(rowptr, csr, as_, ad_, Hbf, b2, Abf, N);

  // ---------- GAT layer 3 (128 -> 128) ----------
  k_gemm_mfma<128,128,true><<<dim3(gG), dim3(T), 0, stream>>>(Abf, Wp3, Hbf, a3s, a3d, as_, ad_, N);
  k_gat_agg<<<dim3(gW), dim3(T), 0, stream>>>(rowptr, csr, as_, ad_, Hbf, b3, Abf, N);

  // ---------- GCN layer 1 (128 -> 64) ----------
  k_gemm_mfma<128,64,false><<<dim3(gG), dim3(T), 0, stream>>>(Abf, Wpg1, Hbf, nullptr, nullptr, nullptr, nullptr, N);
  k_gcn_agg<64,true><<<dim3(gW), dim3(T), 0, stream>>>(rowptr, csr, dinv, Hbf, bg1, Abf, (float*)nullptr, N);

  // ---------- GCN layer 2 (64 -> 32) ----------
  k_gemm_mfma<64,32,false><<<dim3(gG), dim3(T), 0, stream>>>(Abf, Wpg2, Hbf, nullptr, nullptr, nullptr, nullptr, N);
  k_gcn_agg<32,false><<<dim3(gW), dim3(T), 0, stream>>>(rowptr, csr, dinv, Hbf, bg2, (short*)nullptr, A32, N);

  // ---------- per-graph softmax aggregation (chunked online) ----------
  k_bagg_part<BS><<<dim3(B * BS), dim3(256), 0, stream>>>(A32, batch, t, pM, pSb, pV, N);
  k_bagg_comb<BS><<<dim3(cdiv(B * 32, 256)), dim3(256), 0, stream>>>(pM, pSb, pV, g, B);

  // ---------- MLP heads + log_softmax ----------
  k_head<<<dim3(cdiv(B, 64)), dim3(64), 0, stream>>>(g, Wl1, bl1, Wl2, bl2, out, B);
}

// Round 9
// 307.507 us; speedup vs baseline: 6.7609x; 1.0255x over previous
//
#include <hip/hip_runtime.h>
#include <math.h>

static inline int cdiv(long a, long b){ return (int)((a + b - 1) / b); }
static inline char* alignp(char* p, size_t a){ return (char*)(((uintptr_t)p + a - 1) & ~(uintptr_t)(a - 1)); }

typedef __attribute__((ext_vector_type(8))) short bf16x8;
typedef __attribute__((ext_vector_type(4))) short bf16x4;
typedef __attribute__((ext_vector_type(4))) float f32x4;

__device__ __forceinline__ float lrelu(float x){ return x > 0.f ? x : 0.2f * x; }
__device__ __forceinline__ float eluf(float x){ return x > 0.f ? x : __expf(x) - 1.f; }
__device__ __forceinline__ short f2bf(float f){            // RNE f32 -> bf16 bits
  unsigned u = __float_as_uint(f);
  return (short)((u + 0x7FFFu + ((u >> 16) & 1u)) >> 16);
}
__device__ __forceinline__ float bflo(unsigned v){ return __uint_as_float(v << 16); }
__device__ __forceinline__ float bfhi(unsigned v){ return __uint_as_float(v & 0xFFFF0000u); }

// ======================= MFMA GEMM: outb[N,FOUT](bf16) = Abf[N,K] @ W[K,FOUT] =======================
// Optional fused attention dots: as_[r] = h[r,:]·av_s ; ad_[r] = h[r,:]·av_d
template<int K, int FOUT, bool DOTS>
__global__ void k_gemm_mfma(const short* __restrict__ Abf, const short* __restrict__ Wp,
                            short* __restrict__ outb,
                            const float* __restrict__ av_s, const float* __restrict__ av_d,
                            float* __restrict__ as_, float* __restrict__ ad_, int N){
  constexpr int NKS = K / 32, NCT = FOUT / 16;
  int wid  = threadIdx.x >> 6;
  int lane = threadIdx.x & 63;
  int rowbase = (blockIdx.x * 4 + wid) * 16;
  if(rowbase >= N) return;
  int arow = rowbase + (lane & 15);
  if(arow >= N) arow = N - 1;                     // clamp; clamped rows never stored
  f32x4 acc[NCT] = {};
  const short* ap = Abf + (long)arow * K + (lane >> 4) * 8;
  #pragma unroll
  for(int ks = 0; ks < NKS; ++ks){
    bf16x8 a = *(const bf16x8*)(ap + ks * 32);
    #pragma unroll
    for(int ct = 0; ct < NCT; ++ct){
      bf16x8 b = *(const bf16x8*)(Wp + ((ks * NCT + ct) * 64 + lane) * 8);
      acc[ct] = __builtin_amdgcn_mfma_f32_16x16x32_bf16(a, b, acc[ct], 0, 0, 0);
    }
  }
  int r0 = rowbase + (lane >> 4) * 4;             // D: row=(lane>>4)*4+j, col=lane&15
  int c0 = lane & 15;
  #pragma unroll
  for(int j = 0; j < 4; ++j){
    int r = r0 + j;
    if(r < N){
      #pragma unroll
      for(int ct = 0; ct < NCT; ++ct)
        outb[(long)r * FOUT + ct * 16 + c0] = f2bf(acc[ct][j]);
    }
  }
  if(DOTS){
    float avs[NCT], avd[NCT];
    #pragma unroll
    for(int ct = 0; ct < NCT; ++ct){ avs[ct] = av_s[ct * 16 + c0]; avd[ct] = av_d[ct * 16 + c0]; }
    #pragma unroll
    for(int j = 0; j < 4; ++j){
      float ps = 0.f, pd = 0.f;
      #pragma unroll
      for(int ct = 0; ct < NCT; ++ct){
        float hv = acc[ct][j];
        ps = fmaf(hv, avs[ct], ps);
        pd = fmaf(hv, avd[ct], pd);
      }
      #pragma unroll
      for(int off = 1; off < 16; off <<= 1){
        ps += __shfl_xor(ps, off);
        pd += __shfl_xor(pd, off);
      }
      int r = r0 + j;
      if(c0 == 0 && r < N){ as_[r] = ps; ad_[r] = pd; }
    }
  }
}

template<int K, int FOUT>
__global__ void k_pack_w(const float* __restrict__ W, short* __restrict__ Wp){
  constexpr int NKS = K / 32, NCT = FOUT / 16;
  int idx = blockIdx.x * blockDim.x + threadIdx.x;
  if(idx >= NKS * NCT * 64) return;
  int lane = idx & 63;
  int ct = (idx >> 6) % NCT;
  int ks = (idx >> 6) / NCT;
  int col = ct * 16 + (lane & 15);
  int kb  = ks * 32 + (lane >> 4) * 8;
  #pragma unroll
  for(int j = 0; j < 8; ++j) Wp[idx * 8 + j] = f2bf(W[(kb + j) * FOUT + col]);
}

// ======================= layer 1: outer product + dots =======================
__global__ void k_dot128(const float* __restrict__ W1, const float* __restrict__ a1s,
                         const float* __restrict__ a1d, float* __restrict__ S){
  __shared__ float s1[128], s2[128];
  int t = threadIdx.x;
  float w = W1[t];
  s1[t] = w * a1s[t]; s2[t] = w * a1d[t];
  __syncthreads();
  for(int off = 64; off > 0; off >>= 1){
    if(t < off){ s1[t] += s1[t + off]; s2[t] += s2[t + off]; }
    __syncthreads();
  }
  if(t == 0){ S[0] = s1[0]; S[1] = s2[0]; }
}
// vectorized: thread per 8 features; 16B stores
__global__ void k_l1v(const float* __restrict__ x, const float* __restrict__ W1,
                      short* __restrict__ outb, int N){
  long idx = (long)blockIdx.x * blockDim.x + threadIdx.x;
  if(idx >= (long)N * 16) return;
  int node = (int)(idx >> 4), j8 = ((int)idx & 15) * 8;
  float xv = x[node];
  float4 w0 = *(const float4*)(W1 + j8);
  float4 w1 = *(const float4*)(W1 + j8 + 4);
  bf16x8 v;
  v[0] = f2bf(xv * w0.x); v[1] = f2bf(xv * w0.y);
  v[2] = f2bf(xv * w0.z); v[3] = f2bf(xv * w0.w);
  v[4] = f2bf(xv * w1.x); v[5] = f2bf(xv * w1.y);
  v[6] = f2bf(xv * w1.z); v[7] = f2bf(xv * w1.w);
  *(bf16x8*)(outb + (long)node * 128 + j8) = v;
}
__global__ void k_l1dots(const float* __restrict__ x, const float* __restrict__ S,
                         float* __restrict__ as_, float* __restrict__ ad_, int N){
  int i = blockIdx.x * blockDim.x + threadIdx.x;
  if(i >= N) return;
  float xv = x[i];
  as_[i] = xv * S[0]; ad_[i] = xv * S[1];
}

// ======================= CSR build (dst-sorted, with self-loops) =======================
__global__ void k_deg_init(int* __restrict__ deg, int N){
  int i = blockIdx.x * blockDim.x + threadIdx.x;
  if(i < N) deg[i] = 1;
}
// XCD-partitioned: block p=blockIdx&7 handles dst range [p*Pdiv,(p+1)*Pdiv) only,
// so atomics/writes to a given line come from one XCD's L2.
__global__ void k_deg_count8(const int* __restrict__ ei, int E, int Pdiv,
                             int* __restrict__ deg){
  int p = blockIdx.x & 7;
  int lo = p * Pdiv, hi = lo + Pdiv;
  long stride = (long)(gridDim.x >> 3) * blockDim.x;
  for(long e = (long)(blockIdx.x >> 3) * blockDim.x + threadIdx.x; e < E; e += stride){
    int d = ei[E + e];
    if(d >= lo && d < hi) atomicAdd(&deg[d], 1);
  }
}

// ---- hierarchical exclusive scan of deg[N] -> rowptr[N+1], cursor[N], dinv[N] ----
__global__ void k_scan_part(const int* __restrict__ deg, int* __restrict__ bsum, int N){
  __shared__ int red[256];
  int i = blockIdx.x * 256 + threadIdx.x;
  int v = (i < N) ? deg[i] : 0;
  red[threadIdx.x] = v;
  __syncthreads();
  #pragma unroll
  for(int off = 128; off > 0; off >>= 1){
    if(threadIdx.x < off) red[threadIdx.x] += red[threadIdx.x + off];
    __syncthreads();
  }
  if(threadIdx.x == 0) bsum[blockIdx.x] = red[0];
}
__global__ void k_scan_mid(int* __restrict__ bsum, int NB, int* __restrict__ rowptr, int N){
  __shared__ int buf[1024];
  int t = threadIdx.x;
  int v = (t < NB) ? bsum[t] : 0;
  buf[t] = v;
  __syncthreads();
  for(int off = 1; off < 1024; off <<= 1){
    int u = (t >= off) ? buf[t - off] : 0;
    __syncthreads();
    buf[t] += u;
    __syncthreads();
  }
  if(t < NB) bsum[t] = buf[t] - v;                // exclusive
  if(t == 1023) rowptr[N] = buf[1023];
}
__global__ void k_scan_fin(const int* __restrict__ deg, const int* __restrict__ bsum,
                           int* __restrict__ rowptr, int* __restrict__ cursor,
                           float* __restrict__ dinv, int N){
  __shared__ int buf[256];
  int i = blockIdx.x * 256 + threadIdx.x;
  int t = threadIdx.x;
  int v = (i < N) ? deg[i] : 0;
  buf[t] = v;
  __syncthreads();
  #pragma unroll
  for(int off = 1; off < 256; off <<= 1){
    int u = (t >= off) ? buf[t - off] : 0;
    __syncthreads();
    buf[t] += u;
    __syncthreads();
  }
  if(i < N){
    int ex = buf[t] - v + bsum[blockIdx.x];
    rowptr[i] = ex; cursor[i] = ex;
    dinv[i] = rsqrtf((float)v);                   // deg >= 1 (self-loop)
  }
}

// XCD-partitioned CSR fill (see k_deg_count8)
__global__ void k_fill8(const int* __restrict__ ei, int E, int N, int Pdiv,
                        int* __restrict__ cursor, int* __restrict__ csr){
  int p = blockIdx.x & 7;
  int lo = p * Pdiv, hi = lo + Pdiv;
  long ET = (long)E + N;
  long stride = (long)(gridDim.x >> 3) * blockDim.x;
  for(long e = (long)(blockIdx.x >> 3) * blockDim.x + threadIdx.x; e < ET; e += stride){
    int d = (e < E) ? ei[E + e] : (int)(e - E);
    if(d < lo || d >= hi) continue;
    int s = (e < E) ? ei[e] : d;
    int pos = atomicAdd(&cursor[d], 1);
    csr[pos] = s;
  }
}

// ======================= fused GAT aggregation: one wave per dst, bf16 h =======================
__global__ void k_gat_agg(const int* __restrict__ rowptr, const int* __restrict__ csr,
                          const float* __restrict__ as_, const float* __restrict__ ad_,
                          const short* __restrict__ h, const float* __restrict__ bias,
                          short* __restrict__ out, int N){
  int w = (int)(((long)blockIdx.x * blockDim.x + threadIdx.x) >> 6);
  int lane = threadIdx.x & 63;
  if(w >= N) return;
  int start = rowptr[w], end = rowptr[w + 1];
  int deg = end - start;
  float add = ad_[w];

  int s_reg = 0;
  float alpha_reg = 0.f, m, inv;
  if(deg <= 64){
    // ---- fast path: lane l owns edge start+l; 3-phase softmax, 1 exp/lane ----
    float logit = -INFINITY;
    if(lane < deg){
      s_reg = csr[start + lane];
      logit = lrelu(as_[s_reg] + add);
    }
    m = logit;
    #pragma unroll
    for(int off = 32; off > 0; off >>= 1) m = fmaxf(m, __shfl_xor(m, off));
    float e = __expf(logit - m);                  // inactive lanes: exp(-INF)=0
    float ssum = e;
    #pragma unroll
    for(int off = 32; off > 0; off >>= 1) ssum += __shfl_xor(ssum, off);
    inv = 1.f / (ssum + 1e-16f);
    alpha_reg = e * inv;
  }else{
    // ---- rare overflow path: online (max,expsum) with strided tail ----
    float logit = -INFINITY, ssum = 0.f;
    m = -INFINITY;
    if(lane < deg){
      s_reg = csr[start + lane];
      logit = lrelu(as_[s_reg] + add);
      m = logit; ssum = 1.f;
      for(int e = start + lane + 64; e < end; e += 64){
        int s = csr[e];
        float l = lrelu(as_[s] + add);
        if(l > m){ ssum = ssum * __expf(m - l) + 1.f; m = l; }
        else       ssum += __expf(l - m);
      }
    }
    #pragma unroll
    for(int off = 32; off > 0; off >>= 1){
      float mo = __shfl_xor(m, off);
      float so = __shfl_xor(ssum, off);
      float mn = fmaxf(m, mo);
      float ea = (m  > -INFINITY) ? __expf(m  - mn) : 0.f;
      float eb = (mo > -INFINITY) ? __expf(mo - mn) : 0.f;
      ssum = ssum * ea + so * eb;
      m = mn;
    }
    inv = 1.f / (ssum + 1e-16f);
    alpha_reg = __expf(logit - m) * inv;
  }

  // phase B: 4 edges per iteration, 16B row-slices; group g handles edge k+g
  float acc[8] = {};
  int nb = deg < 64 ? deg : 64;
  int g  = lane >> 4;
  int fo = (lane & 15) * 8;
  const short* hf = h + fo;
  for(int k = 0; k < nb; k += 4){
    int idx = k + g;
    if(idx < nb){
      float a = __shfl(alpha_reg, idx);
      int s   = __shfl(s_reg, idx);
      uint4 hv = *(const uint4*)(hf + (long)s * 128);
      acc[0] = fmaf(a, bflo(hv.x), acc[0]);
      acc[1] = fmaf(a, bfhi(hv.x), acc[1]);
      acc[2] = fmaf(a, bflo(hv.y), acc[2]);
      acc[3] = fmaf(a, bfhi(hv.y), acc[3]);
      acc[4] = fmaf(a, bflo(hv.z), acc[4]);
      acc[5] = fmaf(a, bfhi(hv.z), acc[5]);
      acc[6] = fmaf(a, bflo(hv.w), acc[6]);
      acc[7] = fmaf(a, bfhi(hv.w), acc[7]);
    }
  }
  for(int e = start + 64; e < end; ++e){          // rare overflow path (group 0 only)
    if(lane < 16){
      int s = csr[e];
      float l = lrelu(as_[s] + add);
      float a = __expf(l - m) * inv;
      uint4 hv = *(const uint4*)(hf + (long)s * 128);
      acc[0] = fmaf(a, bflo(hv.x), acc[0]);
      acc[1] = fmaf(a, bfhi(hv.x), acc[1]);
      acc[2] = fmaf(a, bflo(hv.y), acc[2]);
      acc[3] = fmaf(a, bfhi(hv.y), acc[3]);
      acc[4] = fmaf(a, bflo(hv.z), acc[4]);
      acc[5] = fmaf(a, bfhi(hv.z), acc[5]);
      acc[6] = fmaf(a, bflo(hv.w), acc[6]);
      acc[7] = fmaf(a, bfhi(hv.w), acc[7]);
    }
  }
  #pragma unroll
  for(int j = 0; j < 8; ++j){
    acc[j] += __shfl_xor(acc[j], 16);
    acc[j] += __shfl_xor(acc[j], 32);
  }
  if(lane < 16){
    float4 b0 = *(const float4*)(bias + fo);
    float4 b1 = *(const float4*)(bias + fo + 4);
    bf16x8 v;
    v[0] = f2bf(eluf(acc[0] + b0.x)); v[1] = f2bf(eluf(acc[1] + b0.y));
    v[2] = f2bf(eluf(acc[2] + b0.z)); v[3] = f2bf(eluf(acc[3] + b0.w));
    v[4] = f2bf(eluf(acc[4] + b1.x)); v[5] = f2bf(eluf(acc[5] + b1.y));
    v[6] = f2bf(eluf(acc[6] + b1.z)); v[7] = f2bf(eluf(acc[7] + b1.w));
    *(bf16x8*)(out + (long)w * 128 + fo) = v;
  }
}

// ======================= fused GCN aggregation: one wave per dst, bf16 h =======================
template<int F, bool BFOUT>
__global__ void k_gcn_agg(const int* __restrict__ rowptr, const int* __restrict__ csr,
                          const float* __restrict__ dinv, const short* __restrict__ h,
                          const float* __restrict__ bias, short* __restrict__ out_bf,
                          float* __restrict__ out_f, int N){
  constexpr int FPL = F / 16;                     // features per lane (4 or 2)
  int w = (int)(((long)blockIdx.x * blockDim.x + threadIdx.x) >> 6);
  int lane = threadIdx.x & 63;
  if(w >= N) return;
  int start = rowptr[w], end = rowptr[w + 1];
  int deg = end - start;
  float dd = dinv[w];
  int s_reg = 0; float dv_reg = 0.f;
  if(lane < deg){
    s_reg = csr[start + lane];
    dv_reg = dinv[s_reg];
  }
  float acc[FPL] = {};
  int nb = deg < 64 ? deg : 64;
  int g  = lane >> 4;
  int fo = (lane & 15) * FPL;
  const short* hf = h + fo;
  for(int k = 0; k < nb; k += 4){
    int idx = k + g;
    if(idx < nb){
      int s = __shfl(s_reg, idx);
      float nrm = dd * __shfl(dv_reg, idx);
      if(FPL == 4){
        uint2 hv = *(const uint2*)(hf + (long)s * F);
        acc[0] = fmaf(nrm, bflo(hv.x), acc[0]);
        acc[1] = fmaf(nrm, bfhi(hv.x), acc[1]);
        acc[2] = fmaf(nrm, bflo(hv.y), acc[2]);
        acc[3] = fmaf(nrm, bfhi(hv.y), acc[3]);
      }else{
        unsigned hv = *(const unsigned*)(hf + (long)s * F);
        acc[0] = fmaf(nrm, bflo(hv), acc[0]);
        acc[1] = fmaf(nrm, bfhi(hv), acc[1]);
      }
    }
  }
  for(int e = start + 64; e < end; ++e){          // rare overflow (group 0 only)
    if(lane < 16){
      int s = csr[e];
      float nrm = dd * dinv[s];
      if(FPL == 4){
        uint2 hv = *(const uint2*)(hf + (long)s * F);
        acc[0] = fmaf(nrm, bflo(hv.x), acc[0]);
        acc[1] = fmaf(nrm, bfhi(hv.x), acc[1]);
        acc[2] = fmaf(nrm, bflo(hv.y), acc[2]);
        acc[3] = fmaf(nrm, bfhi(hv.y), acc[3]);
      }else{
        unsigned hv = *(const unsigned*)(hf + (long)s * F);
        acc[0] = fmaf(nrm, bflo(hv), acc[0]);
        acc[1] = fmaf(nrm, bfhi(hv), acc[1]);
      }
    }
  }
  #pragma unroll
  for(int j = 0; j < FPL; ++j){
    acc[j] += __shfl_xor(acc[j], 16);
    acc[j] += __shfl_xor(acc[j], 32);
  }
  if(lane < 16){
    if(BFOUT){
      if(FPL == 4){
        bf16x4 v;
        #pragma unroll
        for(int j = 0; j < 4; ++j) v[j] = f2bf(eluf(acc[j] + bias[fo + j]));
        *(bf16x4*)(out_bf + (long)w * F + fo) = v;
      }else{
        #pragma unroll
        for(int j = 0; j < FPL; ++j)
          out_bf[(long)w * F + fo + j] = f2bf(eluf(acc[j] + bias[fo + j]));
      }
    }else{
      if(FPL == 2){
        float2 v2 = make_float2(eluf(acc[0] + bias[fo]), eluf(acc[1] + bias[fo + 1]));
        *(float2*)(out_f + (long)w * F + fo) = v2;
      }else{
        #pragma unroll
        for(int j = 0; j < FPL; ++j)
          out_f[(long)w * F + fo + j] = eluf(acc[j] + bias[fo + j]);
      }
    }
  }
}

// ============ per-graph softmax aggregation: chunked online (m,s,v) + combine ============
template<int S>
__global__ void k_bagg_part(const float* __restrict__ h, const int* __restrict__ batch,
                            const float* __restrict__ t, float* __restrict__ pM,
                            float* __restrict__ pS, float* __restrict__ pV, int N){
  int chunk = blockIdx.x;
  int b = chunk / S, s = chunk % S;
  __shared__ int s_lo, s_hi;
  if(threadIdx.x == 0){
    int lo = 0, hi = N;
    while(lo < hi){ int mid = (lo + hi) >> 1; if(batch[mid] < b) lo = mid + 1; else hi = mid; }
    s_lo = lo;
    int lo2 = lo, hi2 = N;
    while(lo2 < hi2){ int mid = (lo2 + hi2) >> 1; if(batch[mid] < b + 1) lo2 = mid + 1; else hi2 = mid; }
    s_hi = lo2;
  }
  __syncthreads();
  int lo = s_lo, hi = s_hi;
  int len = hi - lo;
  int per = (len + S - 1) / S;
  int clo = lo + s * per;
  int chi = clo + per; if(chi > hi) chi = hi;
  float tv = t[0];
  int c = threadIdx.x & 31, r = threadIdx.x >> 5;   // 8 rows x 32 channels

  float m = -INFINITY, ss = 0.f, vv = 0.f;
  for(int i = clo + r; i < chi; i += 8){
    float hv = h[(long)i * 32 + c];
    float l = hv * tv;
    if(l > m){
      float e = (m > -INFINITY) ? __expf(m - l) : 0.f;
      ss = ss * e + 1.f; vv = vv * e + hv; m = l;
    }else{
      float e = __expf(l - m);
      ss += e; vv += e * hv;
    }
  }
  __shared__ float rm[8][32], rs[8][32], rv[8][32];
  rm[r][c] = m; rs[r][c] = ss; rv[r][c] = vv;
  __syncthreads();
  if(r == 0){
    float M = rm[0][c], SS = rs[0][c], VV = rv[0][c];
    #pragma unroll
    for(int k = 1; k < 8; ++k){
      float mo = rm[k][c], so = rs[k][c], vo = rv[k][c];
      float mn = fmaxf(M, mo);
      float ea = (M  > -INFINITY) ? __expf(M  - mn) : 0.f;
      float eb = (mo > -INFINITY) ? __expf(mo - mn) : 0.f;
      SS = SS * ea + so * eb; VV = VV * ea + vo * eb; M = mn;
    }
    pM[chunk * 32 + c] = M; pS[chunk * 32 + c] = SS; pV[chunk * 32 + c] = VV;
  }
}
template<int S>
__global__ void k_bagg_comb(const float* __restrict__ pM, const float* __restrict__ pS,
                            const float* __restrict__ pV, float* __restrict__ g, int B){
  int idx = blockIdx.x * blockDim.x + threadIdx.x;  // b*32 + c
  if(idx >= B * 32) return;
  int b = idx >> 5, c = idx & 31;
  float M = -INFINITY, SS = 0.f, VV = 0.f;
  #pragma unroll 4
  for(int k = 0; k < S; ++k){
    int p = (b * S + k) * 32 + c;
    float mo = pM[p], so = pS[p], vo = pV[p];
    float mn = fmaxf(M, mo);
    float ea = (M  > -INFINITY) ? __expf(M  - mn) : 0.f;
    float eb = (mo > -INFINITY) ? __expf(mo - mn) : 0.f;
    SS = SS * ea + so * eb; VV = VV * ea + vo * eb; M = mn;
  }
  g[idx] = VV / (SS + 1e-16f);
}

// ---- heads ----
__global__ void k_head(const float* __restrict__ g, const float* __restrict__ Wl1,
                       const float* __restrict__ bl1, const float* __restrict__ Wl2,
                       const float* __restrict__ bl2, float* __restrict__ out, int B){
  int b = blockIdx.x * blockDim.x + threadIdx.x;
  if(b >= B) return;
  float gr[32];
  #pragma unroll
  for(int k = 0; k < 32; ++k) gr[k] = g[b * 32 + k];
  float h1[16];
  #pragma unroll
  for(int j = 0; j < 16; ++j){
    float acc = bl1[j];
    #pragma unroll
    for(int k = 0; k < 32; ++k) acc = fmaf(gr[k], Wl1[k * 16 + j], acc);
    h1[j] = eluf(acc);
  }
  float l0 = bl2[0], l1 = bl2[1];
  #pragma unroll
  for(int k = 0; k < 16; ++k){
    l0 = fmaf(h1[k], Wl2[k * 2 + 0], l0);
    l1 = fmaf(h1[k], Wl2[k * 2 + 1], l1);
  }
  float mx = fmaxf(l0, l1);
  float lse = mx + __logf(__expf(l0 - mx) + __expf(l1 - mx));
  out[b * 2 + 0] = l0 - lse;
  out[b * 2 + 1] = l1 - lse;
}

extern "C" void kernel_launch(void* const* d_in, const int* in_sizes, int n_in,
                              void* d_out, int out_size, void* d_ws, size_t ws_size,
                              hipStream_t stream){
  const float* x     = (const float*)d_in[0];
  const int*   ei    = (const int*)d_in[1];
  const int*   batch = (const int*)d_in[2];
  const float* W1 = (const float*)d_in[3];
  const float* a1s = (const float*)d_in[4];
  const float* a1d = (const float*)d_in[5];
  const float* b1 = (const float*)d_in[6];
  const float* W2 = (const float*)d_in[7];
  const float* a2s = (const float*)d_in[8];
  const float* a2d = (const float*)d_in[9];
  const float* b2 = (const float*)d_in[10];
  const float* W3 = (const float*)d_in[11];
  const float* a3s = (const float*)d_in[12];
  const float* a3d = (const float*)d_in[13];
  const float* b3 = (const float*)d_in[14];
  const float* Wg1 = (const float*)d_in[15];
  const float* bg1 = (const float*)d_in[16];
  const float* Wg2 = (const float*)d_in[17];
  const float* bg2 = (const float*)d_in[18];
  const float* t   = (const float*)d_in[19];
  const float* Wl1 = (const float*)d_in[20];
  const float* bl1 = (const float*)d_in[21];
  const float* Wl2 = (const float*)d_in[22];
  const float* bl2 = (const float*)d_in[23];

  const int N = in_sizes[0];
  const int E = in_sizes[1] / 2;
  const int B = out_size / 2;
  const int ET = E + N;
  float* out = (float*)d_out;
  constexpr int BS = 32;                         // chunks per graph for batch agg

  // ---- workspace layout ----
  char* p = (char*)d_ws;
  short* Hbf  = (short*)p;            p += (size_t)N * 128 * 2;   // gemm/layer out (bf16)
  short* Abf  = (short*)p;            p += (size_t)N * 128 * 2;   // agg out (bf16)
  float* A32  = (float*)p;            p += (size_t)N * 32 * 4;    // final GCN out (fp32)
  float* as_  = (float*)p;            p += (size_t)N * 4;
  float* ad_  = (float*)p;            p += (size_t)N * 4;
  float* dinv = (float*)p;            p += (size_t)N * 4;
  int*   deg    = (int*)p;            p += (size_t)N * 4;
  int*   rowptr = (int*)p;            p += (size_t)(N + 1) * 4;
  int*   cursor = (int*)p;            p += (size_t)N * 4;
  int*   csr    = (int*)p;            p += (size_t)ET * 4;
  int*   bsum   = (int*)p;            p += (size_t)1024 * 4;
  p = alignp(p, 16);
  short* Wp2  = (short*)p;            p += 128 * 128 * 2;
  short* Wp3  = (short*)p;            p += 128 * 128 * 2;
  short* Wpg1 = (short*)p;            p += 128 * 64 * 2;
  short* Wpg2 = (short*)p;            p += 64 * 32 * 2;
  p = alignp(p, 16);
  float* S    = (float*)p;            p += 16 * 4;
  float* pM   = (float*)p;            p += (size_t)B * BS * 32 * 4;
  float* pSb  = (float*)p;            p += (size_t)B * BS * 32 * 4;
  float* pV   = (float*)p;            p += (size_t)B * BS * 32 * 4;
  float* g    = (float*)p;

  const int T = 256;
  const int gN  = cdiv(N, T);
  const int gW  = cdiv((long)N * 64, T);         // wave-per-dst grids
  const int gG  = cdiv(N, 64);                   // mfma gemm: 64 rows/block
  const int NB  = cdiv(N, 256);                  // scan blocks (<=1024)
  const int Pdiv = cdiv(N, 8);                   // XCD dst-partition width

  // ---------- CSR build + weight packs ----------
  k_deg_init<<<dim3(gN), dim3(T), 0, stream>>>(deg, N);
  k_deg_count8<<<dim3(2048), dim3(T), 0, stream>>>(ei, E, Pdiv, deg);
  k_scan_part<<<dim3(NB), dim3(256), 0, stream>>>(deg, bsum, N);
  k_scan_mid<<<dim3(1), dim3(1024), 0, stream>>>(bsum, NB, rowptr, N);
  k_scan_fin<<<dim3(NB), dim3(256), 0, stream>>>(deg, bsum, rowptr, cursor, dinv, N);
  k_fill8<<<dim3(2048), dim3(T), 0, stream>>>(ei, E, N, Pdiv, cursor, csr);
  k_pack_w<128,128><<<dim3(8), dim3(T), 0, stream>>>(W2, Wp2);
  k_pack_w<128,128><<<dim3(8), dim3(T), 0, stream>>>(W3, Wp3);
  k_pack_w<128, 64><<<dim3(4), dim3(T), 0, stream>>>(Wg1, Wpg1);
  k_pack_w< 64, 32><<<dim3(1), dim3(T), 0, stream>>>(Wg2, Wpg2);
  k_dot128<<<dim3(1), dim3(128), 0, stream>>>(W1, a1s, a1d, S);

  // ---------- GAT layer 1 (1 -> 128): outer product ----------
  k_l1v<<<dim3(cdiv((long)N * 16, T)), dim3(T), 0, stream>>>(x, W1, Hbf, N);
  k_l1dots<<<dim3(gN), dim3(T), 0, stream>>>(x, S, as_, ad_, N);
  k_gat_agg<<<dim3(gW), dim3(T), 0, stream>>>(rowptr, csr, as_, ad_, Hbf, b1, Abf, N);

  // ---------- GAT layer 2 (128 -> 128) ----------
  k_gemm_mfma<128,128,true><<<dim3(gG), dim3(T), 0, stream>>>(Abf, Wp2, Hbf, a2s, a2d, as_, ad_, N);
  k_gat_agg<<<dim3(gW), dim3(T), 0, stream>>>(rowptr, csr, as_, ad_, Hbf, b2, Abf, N);

  // ---------- GAT layer 3 (128 -> 128) ----------
  k_gemm_mfma<128,128,true><<<dim3(gG), dim3(T), 0, stream>>>(Abf, Wp3, Hbf, a3s, a3d, as_, ad_, N);
  k_gat_agg<<<dim3(gW), dim3(T), 0, stream>>>(rowptr, csr, as_, ad_, Hbf, b3, Abf, N);

  // ---------- GCN layer 1 (128 -> 64) ----------
  k_gemm_mfma<128,64,false><<<dim3(gG), dim3(T), 0, stream>>>(Abf, Wpg1, Hbf, nullptr, nullptr, nullptr, nullptr, N);
  k_gcn_agg<64,true><<<dim3(gW), dim3(T), 0, stream>>>(rowptr, csr, dinv, Hbf, bg1, Abf, (float*)nullptr, N);

  // ---------- GCN layer 2 (64 -> 32) ----------
  k_gemm_mfma<64,32,false><<<dim3(gG), dim3(T), 0, stream>>>(Abf, Wpg2, Hbf, nullptr, nullptr, nullptr, nullptr, N);
  k_gcn_agg<32,false><<<dim3(gW), dim3(T), 0, stream>>>(rowptr, csr, dinv, Hbf, bg2, (short*)nullptr, A32, N);

  // ---------- per-graph softmax aggregation (chunked online) ----------
  k_bagg_part<BS><<<dim3(B * BS), dim3(256), 0, stream>>>(A32, batch, t, pM, pSb, pV, N);
  k_bagg_comb<BS><<<dim3(cdiv(B * 32, 256)), dim3(256), 0, stream>>>(pM, pSb, pV, g, B);

  // ---------- MLP heads + log_softmax ----------
  k_head<<<dim3(cdiv(B, 64)), dim3(64), 0, stream>>>(g, Wl1, bl1, Wl2, bl2, out, B);
}

// Round 10
// 278.417 us; speedup vs baseline: 7.4673x; 1.1045x over previous
//
#include <hip/hip_runtime.h>
#include <math.h>

static inline int cdiv(long a, long b){ return (int)((a + b - 1) / b); }
static inline char* alignp(char* p, size_t a){ return (char*)(((uintptr_t)p + a - 1) & ~(uintptr_t)(a - 1)); }

typedef __attribute__((ext_vector_type(8))) short bf16x8;
typedef __attribute__((ext_vector_type(4))) short bf16x4;
typedef __attribute__((ext_vector_type(4))) float f32x4;

__device__ __forceinline__ float lrelu(float x){ return x > 0.f ? x : 0.2f * x; }
__device__ __forceinline__ float eluf(float x){ return x > 0.f ? x : __expf(x) - 1.f; }
__device__ __forceinline__ short f2bf(float f){            // RNE f32 -> bf16 bits
  unsigned u = __float_as_uint(f);
  return (short)((u + 0x7FFFu + ((u >> 16) & 1u)) >> 16);
}
__device__ __forceinline__ float bflo(unsigned v){ return __uint_as_float(v << 16); }
__device__ __forceinline__ float bfhi(unsigned v){ return __uint_as_float(v & 0xFFFF0000u); }

// ======================= MFMA GEMM: outb[N,FOUT](bf16) = Abf[N,K] @ W[K,FOUT] =======================
template<int K, int FOUT, bool DOTS>
__global__ void k_gemm_mfma(const short* __restrict__ Abf, const short* __restrict__ Wp,
                            short* __restrict__ outb,
                            const float* __restrict__ av_s, const float* __restrict__ av_d,
                            float* __restrict__ as_, float* __restrict__ ad_, int N){
  constexpr int NKS = K / 32, NCT = FOUT / 16;
  int wid  = threadIdx.x >> 6;
  int lane = threadIdx.x & 63;
  int rowbase = (blockIdx.x * 4 + wid) * 16;
  if(rowbase >= N) return;
  int arow = rowbase + (lane & 15);
  if(arow >= N) arow = N - 1;                     // clamp; clamped rows never stored
  f32x4 acc[NCT] = {};
  const short* ap = Abf + (long)arow * K + (lane >> 4) * 8;
  #pragma unroll
  for(int ks = 0; ks < NKS; ++ks){
    bf16x8 a = *(const bf16x8*)(ap + ks * 32);
    #pragma unroll
    for(int ct = 0; ct < NCT; ++ct){
      bf16x8 b = *(const bf16x8*)(Wp + ((ks * NCT + ct) * 64 + lane) * 8);
      acc[ct] = __builtin_amdgcn_mfma_f32_16x16x32_bf16(a, b, acc[ct], 0, 0, 0);
    }
  }
  int r0 = rowbase + (lane >> 4) * 4;             // D: row=(lane>>4)*4+j, col=lane&15
  int c0 = lane & 15;
  #pragma unroll
  for(int j = 0; j < 4; ++j){
    int r = r0 + j;
    if(r < N){
      #pragma unroll
      for(int ct = 0; ct < NCT; ++ct)
        outb[(long)r * FOUT + ct * 16 + c0] = f2bf(acc[ct][j]);
    }
  }
  if(DOTS){
    float avs[NCT], avd[NCT];
    #pragma unroll
    for(int ct = 0; ct < NCT; ++ct){ avs[ct] = av_s[ct * 16 + c0]; avd[ct] = av_d[ct * 16 + c0]; }
    #pragma unroll
    for(int j = 0; j < 4; ++j){
      float ps = 0.f, pd = 0.f;
      #pragma unroll
      for(int ct = 0; ct < NCT; ++ct){
        float hv = acc[ct][j];
        ps = fmaf(hv, avs[ct], ps);
        pd = fmaf(hv, avd[ct], pd);
      }
      #pragma unroll
      for(int off = 1; off < 16; off <<= 1){
        ps += __shfl_xor(ps, off);
        pd += __shfl_xor(pd, off);
      }
      int r = r0 + j;
      if(c0 == 0 && r < N){ as_[r] = ps; ad_[r] = pd; }
    }
  }
}

// ======================= combined weight pack + layer1 dot (one launch) =======================
template<int K, int FOUT>
__device__ __forceinline__ void pack_dev(const float* __restrict__ W, short* __restrict__ Wp, int idx){
  constexpr int NKS = K / 32, NCT = FOUT / 16;
  if(idx >= NKS * NCT * 64) return;
  int lane = idx & 63;
  int ct = (idx >> 6) % NCT;
  int ks = (idx >> 6) / NCT;
  int col = ct * 16 + (lane & 15);
  int kb  = ks * 32 + (lane >> 4) * 8;
  #pragma unroll
  for(int j = 0; j < 8; ++j) Wp[idx * 8 + j] = f2bf(W[(kb + j) * FOUT + col]);
}
__global__ void k_pack_all(const float* __restrict__ W2, const float* __restrict__ W3,
                           const float* __restrict__ Wg1, const float* __restrict__ Wg2,
                           const float* __restrict__ W1, const float* __restrict__ a1s,
                           const float* __restrict__ a1d,
                           short* __restrict__ Wp2, short* __restrict__ Wp3,
                           short* __restrict__ Wpg1, short* __restrict__ Wpg2,
                           float* __restrict__ S){
  int b = blockIdx.x;
  if(b < 8)       pack_dev<128,128>(W2,  Wp2,  b * 256 + threadIdx.x);
  else if(b < 16) pack_dev<128,128>(W3,  Wp3,  (b - 8) * 256 + threadIdx.x);
  else if(b < 20) pack_dev<128, 64>(Wg1, Wpg1, (b - 16) * 256 + threadIdx.x);
  else if(b == 20) pack_dev<64, 32>(Wg2, Wpg2, threadIdx.x);
  else{
    __shared__ float s1[128], s2[128];
    int t = threadIdx.x;
    if(t < 128){ float w = W1[t]; s1[t] = w * a1s[t]; s2[t] = w * a1d[t]; }
    __syncthreads();
    for(int off = 64; off > 0; off >>= 1){
      if(t < off){ s1[t] += s1[t + off]; s2[t] += s2[t + off]; }
      __syncthreads();
    }
    if(t == 0){ S[0] = s1[0]; S[1] = s2[0]; }
  }
}

// layer1 outer product (bf16 out) + fused attention dots
__global__ void k_l1v(const float* __restrict__ x, const float* __restrict__ W1,
                      const float* __restrict__ S, short* __restrict__ outb,
                      float* __restrict__ as_, float* __restrict__ ad_, int N){
  long idx = (long)blockIdx.x * blockDim.x + threadIdx.x;
  if(idx >= (long)N * 16) return;
  int node = (int)(idx >> 4), j8 = ((int)idx & 15) * 8;
  float xv = x[node];
  float4 w0 = *(const float4*)(W1 + j8);
  float4 w1 = *(const float4*)(W1 + j8 + 4);
  bf16x8 v;
  v[0] = f2bf(xv * w0.x); v[1] = f2bf(xv * w0.y);
  v[2] = f2bf(xv * w0.z); v[3] = f2bf(xv * w0.w);
  v[4] = f2bf(xv * w1.x); v[5] = f2bf(xv * w1.y);
  v[6] = f2bf(xv * w1.z); v[7] = f2bf(xv * w1.w);
  *(bf16x8*)(outb + (long)node * 128 + j8) = v;
  if((idx & 15) == 0){ as_[node] = xv * S[0]; ad_[node] = xv * S[1]; }
}

// ======================= CSR build (dst-sorted, with self-loops) =======================
__global__ void k_deg_init(int* __restrict__ deg, int N){
  int i = blockIdx.x * blockDim.x + threadIdx.x;
  if(i < N) deg[i] = 1;
}
// XCD-partitioned: block p=blockIdx&7 handles dst range [p*Pdiv,(p+1)*Pdiv) only
__global__ void k_deg_count8(const int* __restrict__ ei, int E, int Pdiv,
                             int* __restrict__ deg){
  int p = blockIdx.x & 7;
  int lo = p * Pdiv, hi = lo + Pdiv;
  long stride = (long)(gridDim.x >> 3) * blockDim.x;
  for(long e = (long)(blockIdx.x >> 3) * blockDim.x + threadIdx.x; e < E; e += stride){
    int d = ei[E + e];
    if(d >= lo && d < hi) atomicAdd(&deg[d], 1);
  }
}

// ---- hierarchical exclusive scan of deg[N] -> rowptr[N+1], cursor[N], dinv[N] ----
__global__ void k_scan_part(const int* __restrict__ deg, int* __restrict__ bsum, int N){
  __shared__ int red[256];
  int i = blockIdx.x * 256 + threadIdx.x;
  int v = (i < N) ? deg[i] : 0;
  red[threadIdx.x] = v;
  __syncthreads();
  #pragma unroll
  for(int off = 128; off > 0; off >>= 1){
    if(threadIdx.x < off) red[threadIdx.x] += red[threadIdx.x + off];
    __syncthreads();
  }
  if(threadIdx.x == 0) bsum[blockIdx.x] = red[0];
}
__global__ void k_scan_mid(int* __restrict__ bsum, int NB, int* __restrict__ rowptr, int N){
  __shared__ int buf[1024];
  int t = threadIdx.x;
  int v = (t < NB) ? bsum[t] : 0;
  buf[t] = v;
  __syncthreads();
  for(int off = 1; off < 1024; off <<= 1){
    int u = (t >= off) ? buf[t - off] : 0;
    __syncthreads();
    buf[t] += u;
    __syncthreads();
  }
  if(t < NB) bsum[t] = buf[t] - v;                // exclusive
  if(t == 1023) rowptr[N] = buf[1023];
}
__global__ void k_scan_fin(const int* __restrict__ deg, const int* __restrict__ bsum,
                           int* __restrict__ rowptr, int* __restrict__ cursor,
                           float* __restrict__ dinv, int N){
  __shared__ int buf[256];
  int i = blockIdx.x * 256 + threadIdx.x;
  int t = threadIdx.x;
  int v = (i < N) ? deg[i] : 0;
  buf[t] = v;
  __syncthreads();
  #pragma unroll
  for(int off = 1; off < 256; off <<= 1){
    int u = (t >= off) ? buf[t - off] : 0;
    __syncthreads();
    buf[t] += u;
    __syncthreads();
  }
  if(i < N){
    int ex = buf[t] - v + bsum[blockIdx.x];
    rowptr[i] = ex; cursor[i] = ex;
    dinv[i] = rsqrtf((float)v);                   // deg >= 1 (self-loop)
  }
}

// XCD-partitioned CSR fill
__global__ void k_fill8(const int* __restrict__ ei, int E, int N, int Pdiv,
                        int* __restrict__ cursor, int* __restrict__ csr){
  int p = blockIdx.x & 7;
  int lo = p * Pdiv, hi = lo + Pdiv;
  long ET = (long)E + N;
  long stride = (long)(gridDim.x >> 3) * blockDim.x;
  for(long e = (long)(blockIdx.x >> 3) * blockDim.x + threadIdx.x; e < ET; e += stride){
    int d = (e < E) ? ei[E + e] : (int)(e - E);
    if(d < lo || d >= hi) continue;
    int s = (e < E) ? ei[e] : d;
    int pos = atomicAdd(&cursor[d], 1);
    csr[pos] = s;
  }
}

// ======================= fused GAT aggregation: TWO dst per wave (32-lane halves) =======================
__global__ void k_gat_agg(const int* __restrict__ rowptr, const int* __restrict__ csr,
                          const float* __restrict__ as_, const float* __restrict__ ad_,
                          const short* __restrict__ h, const float* __restrict__ bias,
                          short* __restrict__ out, int N){
  int pair = (int)(((long)blockIdx.x * blockDim.x + threadIdx.x) >> 6);
  if(pair * 2 >= N) return;
  int lane = threadIdx.x & 63;
  int half = lane >> 5, hl = lane & 31;
  int w = pair * 2 + half;
  bool active = (w < N);
  int start = 0, end = 0, deg = 0;
  float add = 0.f;
  if(active){ start = rowptr[w]; end = rowptr[w + 1]; deg = end - start; add = ad_[w]; }

  int s_reg = 0;
  float logit = -INFINITY;
  if(hl < deg){                                  // implies active
    s_reg = csr[start + hl];
    logit = lrelu(as_[s_reg] + add);
  }
  float m, inv, alpha_reg;
  if(deg <= 32){
    // fast path: per-half 3-phase softmax (offsets <=16 never cross the half)
    m = logit;
    #pragma unroll
    for(int off = 16; off > 0; off >>= 1) m = fmaxf(m, __shfl_xor(m, off));
    float e = __expf(logit - m);                 // inactive lanes: exp(-INF)=0
    float ssum = e;
    #pragma unroll
    for(int off = 16; off > 0; off >>= 1) ssum += __shfl_xor(ssum, off);
    inv = 1.f / (ssum + 1e-16f);
    alpha_reg = e * inv;
  }else{
    // rare overflow: per-lane online over strided edges, then per-half merge
    float mm = logit, ssum = (hl < deg) ? 1.f : 0.f;
    for(int e = start + hl + 32; e < end; e += 32){
      int s = csr[e];
      float l = lrelu(as_[s] + add);
      if(l > mm){ ssum = ssum * __expf(mm - l) + 1.f; mm = l; }
      else        ssum += __expf(l - mm);
    }
    #pragma unroll
    for(int off = 16; off > 0; off >>= 1){
      float mo = __shfl_xor(mm, off);
      float so = __shfl_xor(ssum, off);
      float mn = fmaxf(mm, mo);
      float ea = (mm > -INFINITY) ? __expf(mm - mn) : 0.f;
      float eb = (mo > -INFINITY) ? __expf(mo - mn) : 0.f;
      ssum = ssum * ea + so * eb;
      mm = mn;
    }
    m = mm;
    inv = 1.f / (ssum + 1e-16f);
    alpha_reg = __expf(logit - m) * inv;
  }

  // phase B: per half, 2 edges/iter; 16-lane subgroup gg covers all 128 features (16B/lane)
  float acc[8] = {};
  int nb = deg < 32 ? deg : 32;
  int gg = hl >> 4;
  int fo = (hl & 15) * 8;
  const short* hf = h + fo;
  for(int k = 0; k < nb; k += 2){
    int idx = k + gg;
    if(idx < nb){
      int sl = (half << 5) + idx;
      float a = __shfl(alpha_reg, sl);
      int s   = __shfl(s_reg, sl);
      uint4 hv = *(const uint4*)(hf + (long)s * 128);
      acc[0] = fmaf(a, bflo(hv.x), acc[0]);
      acc[1] = fmaf(a, bfhi(hv.x), acc[1]);
      acc[2] = fmaf(a, bflo(hv.y), acc[2]);
      acc[3] = fmaf(a, bfhi(hv.y), acc[3]);
      acc[4] = fmaf(a, bflo(hv.z), acc[4]);
      acc[5] = fmaf(a, bfhi(hv.z), acc[5]);
      acc[6] = fmaf(a, bflo(hv.w), acc[6]);
      acc[7] = fmaf(a, bfhi(hv.w), acc[7]);
    }
  }
  for(int e = start + 32; e < end; ++e){          // rare overflow (subgroup 0 of half)
    if(hl < 16){
      int s = csr[e];
      float l = lrelu(as_[s] + add);
      float a = __expf(l - m) * inv;
      uint4 hv = *(const uint4*)(hf + (long)s * 128);
      acc[0] = fmaf(a, bflo(hv.x), acc[0]);
      acc[1] = fmaf(a, bfhi(hv.x), acc[1]);
      acc[2] = fmaf(a, bflo(hv.y), acc[2]);
      acc[3] = fmaf(a, bfhi(hv.y), acc[3]);
      acc[4] = fmaf(a, bflo(hv.z), acc[4]);
      acc[5] = fmaf(a, bfhi(hv.z), acc[5]);
      acc[6] = fmaf(a, bflo(hv.w), acc[6]);
      acc[7] = fmaf(a, bfhi(hv.w), acc[7]);
    }
  }
  #pragma unroll
  for(int j = 0; j < 8; ++j) acc[j] += __shfl_xor(acc[j], 16);
  if(active && hl < 16){
    float4 b0 = *(const float4*)(bias + fo);
    float4 b1 = *(const float4*)(bias + fo + 4);
    bf16x8 v;
    v[0] = f2bf(eluf(acc[0] + b0.x)); v[1] = f2bf(eluf(acc[1] + b0.y));
    v[2] = f2bf(eluf(acc[2] + b0.z)); v[3] = f2bf(eluf(acc[3] + b0.w));
    v[4] = f2bf(eluf(acc[4] + b1.x)); v[5] = f2bf(eluf(acc[5] + b1.y));
    v[6] = f2bf(eluf(acc[6] + b1.z)); v[7] = f2bf(eluf(acc[7] + b1.w));
    *(bf16x8*)(out + (long)w * 128 + fo) = v;
  }
}

// ======================= fused GCN aggregation: TWO dst per wave =======================
template<int F, bool BFOUT>
__global__ void k_gcn_agg(const int* __restrict__ rowptr, const int* __restrict__ csr,
                          const float* __restrict__ dinv, const short* __restrict__ h,
                          const float* __restrict__ bias, short* __restrict__ out_bf,
                          float* __restrict__ out_f, int N){
  constexpr int FPL = F / 16;                     // features per lane (4 or 2)
  int pair = (int)(((long)blockIdx.x * blockDim.x + threadIdx.x) >> 6);
  if(pair * 2 >= N) return;
  int lane = threadIdx.x & 63;
  int half = lane >> 5, hl = lane & 31;
  int w = pair * 2 + half;
  bool active = (w < N);
  int start = 0, end = 0, deg = 0;
  float dd = 0.f;
  if(active){ start = rowptr[w]; end = rowptr[w + 1]; deg = end - start; dd = dinv[w]; }
  int s_reg = 0; float dv_reg = 0.f;
  if(hl < deg){
    s_reg = csr[start + hl];
    dv_reg = dinv[s_reg];
  }
  float acc[FPL] = {};
  int nb = deg < 32 ? deg : 32;
  int gg = hl >> 4;
  int fo = (hl & 15) * FPL;
  const short* hf = h + fo;
  for(int k = 0; k < nb; k += 2){
    int idx = k + gg;
    if(idx < nb){
      int sl = (half << 5) + idx;
      int s = __shfl(s_reg, sl);
      float nrm = dd * __shfl(dv_reg, sl);
      if(FPL == 4){
        uint2 hv = *(const uint2*)(hf + (long)s * F);
        acc[0] = fmaf(nrm, bflo(hv.x), acc[0]);
        acc[1] = fmaf(nrm, bfhi(hv.x), acc[1]);
        acc[2] = fmaf(nrm, bflo(hv.y), acc[2]);
        acc[3] = fmaf(nrm, bfhi(hv.y), acc[3]);
      }else{
        unsigned hv = *(const unsigned*)(hf + (long)s * F);
        acc[0] = fmaf(nrm, bflo(hv), acc[0]);
        acc[1] = fmaf(nrm, bfhi(hv), acc[1]);
      }
    }
  }
  for(int e = start + 32; e < end; ++e){          // rare overflow (subgroup 0 of half)
    if(hl < 16){
      int s = csr[e];
      float nrm = dd * dinv[s];
      if(FPL == 4){
        uint2 hv = *(const uint2*)(hf + (long)s * F);
        acc[0] = fmaf(nrm, bflo(hv.x), acc[0]);
        acc[1] = fmaf(nrm, bfhi(hv.x), acc[1]);
        acc[2] = fmaf(nrm, bflo(hv.y), acc[2]);
        acc[3] = fmaf(nrm, bfhi(hv.y), acc[3]);
      }else{
        unsigned hv = *(const unsigned*)(hf + (long)s * F);
        acc[0] = fmaf(nrm, bflo(hv), acc[0]);
        acc[1] = fmaf(nrm, bfhi(hv), acc[1]);
      }
    }
  }
  #pragma unroll
  for(int j = 0; j < FPL; ++j) acc[j] += __shfl_xor(acc[j], 16);
  if(active && hl < 16){
    if(BFOUT){
      if(FPL == 4){
        bf16x4 v;
        #pragma unroll
        for(int j = 0; j < 4; ++j) v[j] = f2bf(eluf(acc[j] + bias[fo + j]));
        *(bf16x4*)(out_bf + (long)w * F + fo) = v;
      }else{
        #pragma unroll
        for(int j = 0; j < FPL; ++j)
          out_bf[(long)w * F + fo + j] = f2bf(eluf(acc[j] + bias[fo + j]));
      }
    }else{
      if(FPL == 2){
        float2 v2 = make_float2(eluf(acc[0] + bias[fo]), eluf(acc[1] + bias[fo + 1]));
        *(float2*)(out_f + (long)w * F + fo) = v2;
      }else{
        #pragma unroll
        for(int j = 0; j < FPL; ++j)
          out_f[(long)w * F + fo + j] = eluf(acc[j] + bias[fo + j]);
      }
    }
  }
}

// ============ per-graph softmax aggregation: chunked online (m,s,v) + combine ============
template<int S>
__global__ void k_bagg_part(const float* __restrict__ h, const int* __restrict__ batch,
                            const float* __restrict__ t, float* __restrict__ pM,
                            float* __restrict__ pS, float* __restrict__ pV, int N){
  int chunk = blockIdx.x;
  int b = chunk / S, s = chunk % S;
  __shared__ int s_lo, s_hi;
  if(threadIdx.x == 0){
    int lo = 0, hi = N;
    while(lo < hi){ int mid = (lo + hi) >> 1; if(batch[mid] < b) lo = mid + 1; else hi = mid; }
    s_lo = lo;
    int lo2 = lo, hi2 = N;
    while(lo2 < hi2){ int mid = (lo2 + hi2) >> 1; if(batch[mid] < b + 1) lo2 = mid + 1; else hi2 = mid; }
    s_hi = lo2;
  }
  __syncthreads();
  int lo = s_lo, hi = s_hi;
  int len = hi - lo;
  int per = (len + S - 1) / S;
  int clo = lo + s * per;
  int chi = clo + per; if(chi > hi) chi = hi;
  float tv = t[0];
  int c = threadIdx.x & 31, r = threadIdx.x >> 5;   // 8 rows x 32 channels

  float m = -INFINITY, ss = 0.f, vv = 0.f;
  for(int i = clo + r; i < chi; i += 8){
    float hv = h[(long)i * 32 + c];
    float l = hv * tv;
    if(l > m){
      float e = (m > -INFINITY) ? __expf(m - l) : 0.f;
      ss = ss * e + 1.f; vv = vv * e + hv; m = l;
    }else{
      float e = __expf(l - m);
      ss += e; vv += e * hv;
    }
  }
  __shared__ float rm[8][32], rs[8][32], rv[8][32];
  rm[r][c] = m; rs[r][c] = ss; rv[r][c] = vv;
  __syncthreads();
  if(r == 0){
    float M = rm[0][c], SS = rs[0][c], VV = rv[0][c];
    #pragma unroll
    for(int k = 1; k < 8; ++k){
      float mo = rm[k][c], so = rs[k][c], vo = rv[k][c];
      float mn = fmaxf(M, mo);
      float ea = (M  > -INFINITY) ? __expf(M  - mn) : 0.f;
      float eb = (mo > -INFINITY) ? __expf(mo - mn) : 0.f;
      SS = SS * ea + so * eb; VV = VV * ea + vo * eb; M = mn;
    }
    pM[chunk * 32 + c] = M; pS[chunk * 32 + c] = SS; pV[chunk * 32 + c] = VV;
  }
}
template<int S>
__global__ void k_bagg_comb(const float* __restrict__ pM, const float* __restrict__ pS,
                            const float* __restrict__ pV, float* __restrict__ g, int B){
  int idx = blockIdx.x * blockDim.x + threadIdx.x;  // b*32 + c
  if(idx >= B * 32) return;
  int b = idx >> 5, c = idx & 31;
  float M = -INFINITY, SS = 0.f, VV = 0.f;
  #pragma unroll 4
  for(int k = 0; k < S; ++k){
    int p = (b * S + k) * 32 + c;
    float mo = pM[p], so = pS[p], vo = pV[p];
    float mn = fmaxf(M, mo);
    float ea = (M  > -INFINITY) ? __expf(M  - mn) : 0.f;
    float eb = (mo > -INFINITY) ? __expf(mo - mn) : 0.f;
    SS = SS * ea + so * eb; VV = VV * ea + vo * eb; M = mn;
  }
  g[idx] = VV / (SS + 1e-16f);
}

// ---- heads ----
__global__ void k_head(const float* __restrict__ g, const float* __restrict__ Wl1,
                       const float* __restrict__ bl1, const float* __restrict__ Wl2,
                       const float* __restrict__ bl2, float* __restrict__ out, int B){
  int b = blockIdx.x * blockDim.x + threadIdx.x;
  if(b >= B) return;
  float gr[32];
  #pragma unroll
  for(int k = 0; k < 32; ++k) gr[k] = g[b * 32 + k];
  float h1[16];
  #pragma unroll
  for(int j = 0; j < 16; ++j){
    float acc = bl1[j];
    #pragma unroll
    for(int k = 0; k < 32; ++k) acc = fmaf(gr[k], Wl1[k * 16 + j], acc);
    h1[j] = eluf(acc);
  }
  float l0 = bl2[0], l1 = bl2[1];
  #pragma unroll
  for(int k = 0; k < 16; ++k){
    l0 = fmaf(h1[k], Wl2[k * 2 + 0], l0);
    l1 = fmaf(h1[k], Wl2[k * 2 + 1], l1);
  }
  float mx = fmaxf(l0, l1);
  float lse = mx + __logf(__expf(l0 - mx) + __expf(l1 - mx));
  out[b * 2 + 0] = l0 - lse;
  out[b * 2 + 1] = l1 - lse;
}

extern "C" void kernel_launch(void* const* d_in, const int* in_sizes, int n_in,
                              void* d_out, int out_size, void* d_ws, size_t ws_size,
                              hipStream_t stream){
  const float* x     = (const float*)d_in[0];
  const int*   ei    = (const int*)d_in[1];
  const int*   batch = (const int*)d_in[2];
  const float* W1 = (const float*)d_in[3];
  const float* a1s = (const float*)d_in[4];
  const float* a1d = (const float*)d_in[5];
  const float* b1 = (const float*)d_in[6];
  const float* W2 = (const float*)d_in[7];
  const float* a2s = (const float*)d_in[8];
  const float* a2d = (const float*)d_in[9];
  const float* b2 = (const float*)d_in[10];
  const float* W3 = (const float*)d_in[11];
  const float* a3s = (const float*)d_in[12];
  const float* a3d = (const float*)d_in[13];
  const float* b3 = (const float*)d_in[14];
  const float* Wg1 = (const float*)d_in[15];
  const float* bg1 = (const float*)d_in[16];
  const float* Wg2 = (const float*)d_in[17];
  const float* bg2 = (const float*)d_in[18];
  const float* t   = (const float*)d_in[19];
  const float* Wl1 = (const float*)d_in[20];
  const float* bl1 = (const float*)d_in[21];
  const float* Wl2 = (const float*)d_in[22];
  const float* bl2 = (const float*)d_in[23];

  const int N = in_sizes[0];
  const int E = in_sizes[1] / 2;
  const int B = out_size / 2;
  const int ET = E + N;
  float* out = (float*)d_out;
  constexpr int BS = 32;                         // chunks per graph for batch agg

  // ---- workspace layout ----
  char* p = (char*)d_ws;
  short* Hbf  = (short*)p;            p += (size_t)N * 128 * 2;   // gemm/layer out (bf16)
  short* Abf  = (short*)p;            p += (size_t)N * 128 * 2;   // agg out (bf16)
  float* A32  = (float*)p;            p += (size_t)N * 32 * 4;    // final GCN out (fp32)
  float* as_  = (float*)p;            p += (size_t)N * 4;
  float* ad_  = (float*)p;            p += (size_t)N * 4;
  float* dinv = (float*)p;            p += (size_t)N * 4;
  int*   deg    = (int*)p;            p += (size_t)N * 4;
  int*   rowptr = (int*)p;            p += (size_t)(N + 1) * 4;
  int*   cursor = (int*)p;            p += (size_t)N * 4;
  int*   csr    = (int*)p;            p += (size_t)ET * 4;
  int*   bsum   = (int*)p;            p += (size_t)1024 * 4;
  p = alignp(p, 16);
  short* Wp2  = (short*)p;            p += 128 * 128 * 2;
  short* Wp3  = (short*)p;            p += 128 * 128 * 2;
  short* Wpg1 = (short*)p;            p += 128 * 64 * 2;
  short* Wpg2 = (short*)p;            p += 64 * 32 * 2;
  p = alignp(p, 16);
  float* S    = (float*)p;            p += 16 * 4;
  float* pM   = (float*)p;            p += (size_t)B * BS * 32 * 4;
  float* pSb  = (float*)p;            p += (size_t)B * BS * 32 * 4;
  float* pV   = (float*)p;            p += (size_t)B * BS * 32 * 4;
  float* g    = (float*)p;

  const int T = 256;
  const int gN   = cdiv(N, T);
  const int gW2  = cdiv((long)N * 32, T);        // 2-dst-per-wave grids
  const int gG   = cdiv(N, 64);                  // mfma gemm: 64 rows/block
  const int NB   = cdiv(N, 256);                 // scan blocks (<=1024)
  const int Pdiv = cdiv(N, 8);                   // XCD dst-partition width

  // ---------- CSR build + weight packs ----------
  k_deg_init<<<dim3(gN), dim3(T), 0, stream>>>(deg, N);
  k_deg_count8<<<dim3(2048), dim3(T), 0, stream>>>(ei, E, Pdiv, deg);
  k_scan_part<<<dim3(NB), dim3(256), 0, stream>>>(deg, bsum, N);
  k_scan_mid<<<dim3(1), dim3(1024), 0, stream>>>(bsum, NB, rowptr, N);
  k_scan_fin<<<dim3(NB), dim3(256), 0, stream>>>(deg, bsum, rowptr, cursor, dinv, N);
  k_fill8<<<dim3(2048), dim3(T), 0, stream>>>(ei, E, N, Pdiv, cursor, csr);
  k_pack_all<<<dim3(22), dim3(T), 0, stream>>>(W2, W3, Wg1, Wg2, W1, a1s, a1d,
                                               Wp2, Wp3, Wpg1, Wpg2, S);

  // ---------- GAT layer 1 (1 -> 128): outer product + dots ----------
  k_l1v<<<dim3(cdiv((long)N * 16, T)), dim3(T), 0, stream>>>(x, W1, S, Hbf, as_, ad_, N);
  k_gat_agg<<<dim3(gW2), dim3(T), 0, stream>>>(rowptr, csr, as_, ad_, Hbf, b1, Abf, N);

  // ---------- GAT layer 2 (128 -> 128) ----------
  k_gemm_mfma<128,128,true><<<dim3(gG), dim3(T), 0, stream>>>(Abf, Wp2, Hbf, a2s, a2d, as_, ad_, N);
  k_gat_agg<<<dim3(gW2), dim3(T), 0, stream>>>(rowptr, csr, as_, ad_, Hbf, b2, Abf, N);

  // ---------- GAT layer 3 (128 -> 128) ----------
  k_gemm_mfma<128,128,true><<<dim3(gG), dim3(T), 0, stream>>>(Abf, Wp3, Hbf, a3s, a3d, as_, ad_, N);
  k_gat_agg<<<dim3(gW2), dim3(T), 0, stream>>>(rowptr, csr, as_, ad_, Hbf, b3, Abf, N);

  // ---------- GCN layer 1 (128 -> 64) ----------
  k_gemm_mfma<128,64,false><<<dim3(gG), dim3(T), 0, stream>>>(Abf, Wpg1, Hbf, nullptr, nullptr, nullptr, nullptr, N);
  k_gcn_agg<64,true><<<dim3(gW2), dim3(T), 0, stream>>>(rowptr, csr, dinv, Hbf, bg1, Abf, (float*)nullptr, N);

  // ---------- GCN layer 2 (64 -> 32) ----------
  k_gemm_mfma<64,32,false><<<dim3(gG), dim3(T), 0, stream>>>(Abf, Wpg2, Hbf, nullptr, nullptr, nullptr, nullptr, N);
  k_gcn_agg<32,false><<<dim3(gW2), dim3(T), 0, stream>>>(rowptr, csr, dinv, Hbf, bg2, (short*)nullptr, A32, N);

  // ---------- per-graph softmax aggregation (chunked online) ----------
  k_bagg_part<BS><<<dim3(B * BS), dim3(256), 0, stream>>>(A32, batch, t, pM, pSb, pV, N);
  k_bagg_comb<BS><<<dim3(cdiv(B * 32, 256)), dim3(256), 0, stream>>>(pM, pSb, pV, g, B);

  // ---------- MLP heads + log_softmax ----------
  k_head<<<dim3(cdiv(B, 64)), dim3(64), 0, stream>>>(g, Wl1, bl1, Wl2, bl2, out, B);
}

// Round 11
// 258.141 us; speedup vs baseline: 8.0538x; 1.0785x over previous
//
#include <hip/hip_runtime.h>
#include <math.h>

static inline int cdiv(long a, long b){ return (int)((a + b - 1) / b); }
static inline char* alignp(char* p, size_t a){ return (char*)(((uintptr_t)p + a - 1) & ~(uintptr_t)(a - 1)); }

typedef __attribute__((ext_vector_type(8))) short bf16x8;
typedef __attribute__((ext_vector_type(4))) short bf16x4;
typedef __attribute__((ext_vector_type(4))) float f32x4;

__device__ __forceinline__ float lrelu(float x){ return x > 0.f ? x : 0.2f * x; }
__device__ __forceinline__ float eluf(float x){ return x > 0.f ? x : __expf(x) - 1.f; }
__device__ __forceinline__ short f2bf(float f){            // RNE f32 -> bf16 bits
  unsigned u = __float_as_uint(f);
  return (short)((u + 0x7FFFu + ((u >> 16) & 1u)) >> 16);
}
__device__ __forceinline__ float bflo(unsigned v){ return __uint_as_float(v << 16); }
__device__ __forceinline__ float bfhi(unsigned v){ return __uint_as_float(v & 0xFFFF0000u); }

// ======================= MFMA GEMM: outb[N,FOUT](bf16) = Abf[N,K] @ W[K,FOUT] =======================
template<int K, int FOUT, bool DOTS>
__global__ void k_gemm_mfma(const short* __restrict__ Abf, const short* __restrict__ Wp,
                            short* __restrict__ outb,
                            const float* __restrict__ av_s, const float* __restrict__ av_d,
                            float* __restrict__ as_, float* __restrict__ ad_, int N){
  constexpr int NKS = K / 32, NCT = FOUT / 16;
  int wid  = threadIdx.x >> 6;
  int lane = threadIdx.x & 63;
  int rowbase = (blockIdx.x * 4 + wid) * 16;
  if(rowbase >= N) return;
  int arow = rowbase + (lane & 15);
  if(arow >= N) arow = N - 1;                     // clamp; clamped rows never stored
  f32x4 acc[NCT] = {};
  const short* ap = Abf + (long)arow * K + (lane >> 4) * 8;
  #pragma unroll
  for(int ks = 0; ks < NKS; ++ks){
    bf16x8 a = *(const bf16x8*)(ap + ks * 32);
    #pragma unroll
    for(int ct = 0; ct < NCT; ++ct){
      bf16x8 b = *(const bf16x8*)(Wp + ((ks * NCT + ct) * 64 + lane) * 8);
      acc[ct] = __builtin_amdgcn_mfma_f32_16x16x32_bf16(a, b, acc[ct], 0, 0, 0);
    }
  }
  int r0 = rowbase + (lane >> 4) * 4;             // D: row=(lane>>4)*4+j, col=lane&15
  int c0 = lane & 15;
  #pragma unroll
  for(int j = 0; j < 4; ++j){
    int r = r0 + j;
    if(r < N){
      #pragma unroll
      for(int ct = 0; ct < NCT; ++ct)
        outb[(long)r * FOUT + ct * 16 + c0] = f2bf(acc[ct][j]);
    }
  }
  if(DOTS){
    float avs[NCT], avd[NCT];
    #pragma unroll
    for(int ct = 0; ct < NCT; ++ct){ avs[ct] = av_s[ct * 16 + c0]; avd[ct] = av_d[ct * 16 + c0]; }
    #pragma unroll
    for(int j = 0; j < 4; ++j){
      float ps = 0.f, pd = 0.f;
      #pragma unroll
      for(int ct = 0; ct < NCT; ++ct){
        float hv = acc[ct][j];
        ps = fmaf(hv, avs[ct], ps);
        pd = fmaf(hv, avd[ct], pd);
      }
      #pragma unroll
      for(int off = 1; off < 16; off <<= 1){
        ps += __shfl_xor(ps, off);
        pd += __shfl_xor(pd, off);
      }
      int r = r0 + j;
      if(c0 == 0 && r < N){ as_[r] = ps; ad_[r] = pd; }
    }
  }
}

// ======================= combined weight pack + layer1 dot (one launch) =======================
template<int K, int FOUT>
__device__ __forceinline__ void pack_dev(const float* __restrict__ W, short* __restrict__ Wp, int idx){
  constexpr int NKS = K / 32, NCT = FOUT / 16;
  if(idx >= NKS * NCT * 64) return;
  int lane = idx & 63;
  int ct = (idx >> 6) % NCT;
  int ks = (idx >> 6) / NCT;
  int col = ct * 16 + (lane & 15);
  int kb  = ks * 32 + (lane >> 4) * 8;
  #pragma unroll
  for(int j = 0; j < 8; ++j) Wp[idx * 8 + j] = f2bf(W[(kb + j) * FOUT + col]);
}
__global__ void k_pack_all(const float* __restrict__ W2, const float* __restrict__ W3,
                           const float* __restrict__ Wg1, const float* __restrict__ Wg2,
                           const float* __restrict__ W1, const float* __restrict__ a1s,
                           const float* __restrict__ a1d,
                           short* __restrict__ Wp2, short* __restrict__ Wp3,
                           short* __restrict__ Wpg1, short* __restrict__ Wpg2,
                           float* __restrict__ S){
  int b = blockIdx.x;
  if(b < 8)       pack_dev<128,128>(W2,  Wp2,  b * 256 + threadIdx.x);
  else if(b < 16) pack_dev<128,128>(W3,  Wp3,  (b - 8) * 256 + threadIdx.x);
  else if(b < 20) pack_dev<128, 64>(Wg1, Wpg1, (b - 16) * 256 + threadIdx.x);
  else if(b == 20) pack_dev<64, 32>(Wg2, Wpg2, threadIdx.x);
  else{
    __shared__ float s1[128], s2[128];
    int t = threadIdx.x;
    if(t < 128){ float w = W1[t]; s1[t] = w * a1s[t]; s2[t] = w * a1d[t]; }
    __syncthreads();
    for(int off = 64; off > 0; off >>= 1){
      if(t < off){ s1[t] += s1[t + off]; s2[t] += s2[t + off]; }
      __syncthreads();
    }
    if(t == 0){ S[0] = s1[0]; S[1] = s2[0]; }
  }
}

// layer1 outer product (bf16 out) + fused attention dots
__global__ void k_l1v(const float* __restrict__ x, const float* __restrict__ W1,
                      const float* __restrict__ S, short* __restrict__ outb,
                      float* __restrict__ as_, float* __restrict__ ad_, int N){
  long idx = (long)blockIdx.x * blockDim.x + threadIdx.x;
  if(idx >= (long)N * 16) return;
  int node = (int)(idx >> 4), j8 = ((int)idx & 15) * 8;
  float xv = x[node];
  float4 w0 = *(const float4*)(W1 + j8);
  float4 w1 = *(const float4*)(W1 + j8 + 4);
  bf16x8 v;
  v[0] = f2bf(xv * w0.x); v[1] = f2bf(xv * w0.y);
  v[2] = f2bf(xv * w0.z); v[3] = f2bf(xv * w0.w);
  v[4] = f2bf(xv * w1.x); v[5] = f2bf(xv * w1.y);
  v[6] = f2bf(xv * w1.z); v[7] = f2bf(xv * w1.w);
  *(bf16x8*)(outb + (long)node * 128 + j8) = v;
  if((idx & 15) == 0){ as_[node] = xv * S[0]; ad_[node] = xv * S[1]; }
}

// ======================= CSR build (dst-sorted, with self-loops) =======================
// deg[] is memset(0); the self-loop "+1" is folded into the scans below.
// XCD-partitioned: block p=blockIdx&7 handles dst range [p*Pdiv,(p+1)*Pdiv) only
__global__ void k_deg_count8(const int* __restrict__ ei, int E, int Pdiv,
                             int* __restrict__ deg){
  int p = blockIdx.x & 7;
  int lo = p * Pdiv, hi = lo + Pdiv;
  long stride = (long)(gridDim.x >> 3) * blockDim.x;
  for(long e = (long)(blockIdx.x >> 3) * blockDim.x + threadIdx.x; e < E; e += stride){
    int d = ei[E + e];
    if(d >= lo && d < hi) atomicAdd(&deg[d], 1);
  }
}

// ---- hierarchical exclusive scan of (deg[N]+1) -> rowptr[N+1], cursor[N], dinv[N] ----
__global__ void k_scan_part(const int* __restrict__ deg, int* __restrict__ bsum, int N){
  __shared__ int red[256];
  int i = blockIdx.x * 256 + threadIdx.x;
  int v = (i < N) ? deg[i] + 1 : 0;
  red[threadIdx.x] = v;
  __syncthreads();
  #pragma unroll
  for(int off = 128; off > 0; off >>= 1){
    if(threadIdx.x < off) red[threadIdx.x] += red[threadIdx.x + off];
    __syncthreads();
  }
  if(threadIdx.x == 0) bsum[blockIdx.x] = red[0];
}
__global__ void k_scan_mid(int* __restrict__ bsum, int NB, int* __restrict__ rowptr, int N){
  __shared__ int buf[1024];
  int t = threadIdx.x;
  int v = (t < NB) ? bsum[t] : 0;
  buf[t] = v;
  __syncthreads();
  for(int off = 1; off < 1024; off <<= 1){
    int u = (t >= off) ? buf[t - off] : 0;
    __syncthreads();
    buf[t] += u;
    __syncthreads();
  }
  if(t < NB) bsum[t] = buf[t] - v;                // exclusive
  if(t == 1023) rowptr[N] = buf[1023];
}
__global__ void k_scan_fin(const int* __restrict__ deg, const int* __restrict__ bsum,
                           int* __restrict__ rowptr, int* __restrict__ cursor,
                           float* __restrict__ dinv, int N){
  __shared__ int buf[256];
  int i = blockIdx.x * 256 + threadIdx.x;
  int t = threadIdx.x;
  int v = (i < N) ? deg[i] + 1 : 0;
  buf[t] = v;
  __syncthreads();
  #pragma unroll
  for(int off = 1; off < 256; off <<= 1){
    int u = (t >= off) ? buf[t - off] : 0;
    __syncthreads();
    buf[t] += u;
    __syncthreads();
  }
  if(i < N){
    int ex = buf[t] - v + bsum[blockIdx.x];
    rowptr[i] = ex; cursor[i] = ex;
    dinv[i] = rsqrtf((float)v);                   // v >= 1 (self-loop)
  }
}

// XCD-partitioned CSR fill
__global__ void k_fill8(const int* __restrict__ ei, int E, int N, int Pdiv,
                        int* __restrict__ cursor, int* __restrict__ csr){
  int p = blockIdx.x & 7;
  int lo = p * Pdiv, hi = lo + Pdiv;
  long ET = (long)E + N;
  long stride = (long)(gridDim.x >> 3) * blockDim.x;
  for(long e = (long)(blockIdx.x >> 3) * blockDim.x + threadIdx.x; e < ET; e += stride){
    int d = (e < E) ? ei[E + e] : (int)(e - E);
    if(d < lo || d >= hi) continue;
    int s = (e < E) ? ei[e] : d;
    int pos = atomicAdd(&cursor[d], 1);
    csr[pos] = s;
  }
}

// ======================= fused GAT aggregation: TWO dst per wave, 4-deep load batching =======================
__global__ void k_gat_agg(const int* __restrict__ rowptr, const int* __restrict__ csr,
                          const float* __restrict__ as_, const float* __restrict__ ad_,
                          const short* __restrict__ h, const float* __restrict__ bias,
                          short* __restrict__ out, int N){
  int pair = (int)(((long)blockIdx.x * blockDim.x + threadIdx.x) >> 6);
  if(pair * 2 >= N) return;
  int lane = threadIdx.x & 63;
  int half = lane >> 5, hl = lane & 31;
  int w = pair * 2 + half;
  bool active = (w < N);
  int start = 0, end = 0, deg = 0;
  float add = 0.f;
  if(active){ start = rowptr[w]; end = rowptr[w + 1]; deg = end - start; add = ad_[w]; }

  int s_reg = 0;
  float logit = -INFINITY;
  if(hl < deg){                                  // implies active
    s_reg = csr[start + hl];
    logit = lrelu(as_[s_reg] + add);
  }
  float m, inv, alpha_reg;
  if(deg <= 32){
    // fast path: per-half 3-phase softmax (offsets <=16 never cross the half)
    m = logit;
    #pragma unroll
    for(int off = 16; off > 0; off >>= 1) m = fmaxf(m, __shfl_xor(m, off));
    float e = __expf(logit - m);                 // inactive lanes: exp(-INF)=0
    float ssum = e;
    #pragma unroll
    for(int off = 16; off > 0; off >>= 1) ssum += __shfl_xor(ssum, off);
    inv = 1.f / (ssum + 1e-16f);
    alpha_reg = e * inv;
  }else{
    // rare overflow: per-lane online over strided edges, then per-half merge
    float mm = logit, ssum = (hl < deg) ? 1.f : 0.f;
    for(int e = start + hl + 32; e < end; e += 32){
      int s = csr[e];
      float l = lrelu(as_[s] + add);
      if(l > mm){ ssum = ssum * __expf(mm - l) + 1.f; mm = l; }
      else        ssum += __expf(l - mm);
    }
    #pragma unroll
    for(int off = 16; off > 0; off >>= 1){
      float mo = __shfl_xor(mm, off);
      float so = __shfl_xor(ssum, off);
      float mn = fmaxf(mm, mo);
      float ea = (mm > -INFINITY) ? __expf(mm - mn) : 0.f;
      float eb = (mo > -INFINITY) ? __expf(mo - mn) : 0.f;
      ssum = ssum * ea + so * eb;
      mm = mn;
    }
    m = mm;
    inv = 1.f / (ssum + 1e-16f);
    alpha_reg = __expf(logit - m) * inv;
  }

  // phase B: per half, 8 edges per outer iter (4 per 16-lane subgroup), all 4 loads
  // issued before any FMA -> 4 gathers in flight. Invalid slots clamp to edge 0 with a=0.
  float acc[8] = {};
  int nb = deg < 32 ? deg : 32;
  int gg = hl >> 4;
  int fo = (hl & 15) * 8;
  int base = half << 5;
  const short* hf = h + fo;
  for(int k = 0; k < nb; k += 8){
    uint4 hv[4]; float av[4];
    #pragma unroll
    for(int u = 0; u < 4; ++u){
      int idx = k + 2 * u + gg;
      bool ok = idx < nb;
      int sl = base + (ok ? idx : 0);
      float a = __shfl(alpha_reg, sl);
      av[u] = ok ? a : 0.f;
      int s  = __shfl(s_reg, sl);
      hv[u] = *(const uint4*)(hf + (long)s * 128);
    }
    #pragma unroll
    for(int u = 0; u < 4; ++u){
      acc[0] = fmaf(av[u], bflo(hv[u].x), acc[0]);
      acc[1] = fmaf(av[u], bfhi(hv[u].x), acc[1]);
      acc[2] = fmaf(av[u], bflo(hv[u].y), acc[2]);
      acc[3] = fmaf(av[u], bfhi(hv[u].y), acc[3]);
      acc[4] = fmaf(av[u], bflo(hv[u].z), acc[4]);
      acc[5] = fmaf(av[u], bfhi(hv[u].z), acc[5]);
      acc[6] = fmaf(av[u], bflo(hv[u].w), acc[6]);
      acc[7] = fmaf(av[u], bfhi(hv[u].w), acc[7]);
    }
  }
  for(int e = start + 32; e < end; ++e){          // rare overflow (subgroup 0 of half)
    if(hl < 16){
      int s = csr[e];
      float l = lrelu(as_[s] + add);
      float a = __expf(l - m) * inv;
      uint4 hv = *(const uint4*)(hf + (long)s * 128);
      acc[0] = fmaf(a, bflo(hv.x), acc[0]);
      acc[1] = fmaf(a, bfhi(hv.x), acc[1]);
      acc[2] = fmaf(a, bflo(hv.y), acc[2]);
      acc[3] = fmaf(a, bfhi(hv.y), acc[3]);
      acc[4] = fmaf(a, bflo(hv.z), acc[4]);
      acc[5] = fmaf(a, bfhi(hv.z), acc[5]);
      acc[6] = fmaf(a, bflo(hv.w), acc[6]);
      acc[7] = fmaf(a, bfhi(hv.w), acc[7]);
    }
  }
  #pragma unroll
  for(int j = 0; j < 8; ++j) acc[j] += __shfl_xor(acc[j], 16);
  if(active && hl < 16){
    float4 b0 = *(const float4*)(bias + fo);
    float4 b1 = *(const float4*)(bias + fo + 4);
    bf16x8 v;
    v[0] = f2bf(eluf(acc[0] + b0.x)); v[1] = f2bf(eluf(acc[1] + b0.y));
    v[2] = f2bf(eluf(acc[2] + b0.z)); v[3] = f2bf(eluf(acc[3] + b0.w));
    v[4] = f2bf(eluf(acc[4] + b1.x)); v[5] = f2bf(eluf(acc[5] + b1.y));
    v[6] = f2bf(eluf(acc[6] + b1.z)); v[7] = f2bf(eluf(acc[7] + b1.w));
    *(bf16x8*)(out + (long)w * 128 + fo) = v;
  }
}

// ======================= fused GCN aggregation: TWO dst per wave, 4-deep load batching =======================
template<int F, bool BFOUT>
__global__ void k_gcn_agg(const int* __restrict__ rowptr, const int* __restrict__ csr,
                          const float* __restrict__ dinv, const short* __restrict__ h,
                          const float* __restrict__ bias, short* __restrict__ out_bf,
                          float* __restrict__ out_f, int N){
  constexpr int FPL = F / 16;                     // features per lane (4 or 2)
  int pair = (int)(((long)blockIdx.x * blockDim.x + threadIdx.x) >> 6);
  if(pair * 2 >= N) return;
  int lane = threadIdx.x & 63;
  int half = lane >> 5, hl = lane & 31;
  int w = pair * 2 + half;
  bool active = (w < N);
  int start = 0, end = 0, deg = 0;
  float dd = 0.f;
  if(active){ start = rowptr[w]; end = rowptr[w + 1]; deg = end - start; dd = dinv[w]; }
  int s_reg = 0; float dv_reg = 0.f;
  if(hl < deg){
    s_reg = csr[start + hl];
    dv_reg = dinv[s_reg];
  }
  float acc[FPL] = {};
  int nb = deg < 32 ? deg : 32;
  int gg = hl >> 4;
  int fo = (hl & 15) * FPL;
  int base = half << 5;
  const short* hf = h + fo;
  for(int k = 0; k < nb; k += 8){
    uint2 hv4[4]; unsigned hv2[4]; float nv[4];
    #pragma unroll
    for(int u = 0; u < 4; ++u){
      int idx = k + 2 * u + gg;
      bool ok = idx < nb;
      int sl = base + (ok ? idx : 0);
      float nrm = dd * __shfl(dv_reg, sl);
      nv[u] = ok ? nrm : 0.f;
      int s = __shfl(s_reg, sl);
      if(FPL == 4) hv4[u] = *(const uint2*)(hf + (long)s * F);
      else         hv2[u] = *(const unsigned*)(hf + (long)s * F);
    }
    #pragma unroll
    for(int u = 0; u < 4; ++u){
      if(FPL == 4){
        acc[0] = fmaf(nv[u], bflo(hv4[u].x), acc[0]);
        acc[1] = fmaf(nv[u], bfhi(hv4[u].x), acc[1]);
        acc[2] = fmaf(nv[u], bflo(hv4[u].y), acc[2]);
        acc[3] = fmaf(nv[u], bfhi(hv4[u].y), acc[3]);
      }else{
        acc[0] = fmaf(nv[u], bflo(hv2[u]), acc[0]);
        acc[1] = fmaf(nv[u], bfhi(hv2[u]), acc[1]);
      }
    }
  }
  for(int e = start + 32; e < end; ++e){          // rare overflow (subgroup 0 of half)
    if(hl < 16){
      int s = csr[e];
      float nrm = dd * dinv[s];
      if(FPL == 4){
        uint2 hv = *(const uint2*)(hf + (long)s * F);
        acc[0] = fmaf(nrm, bflo(hv.x), acc[0]);
        acc[1] = fmaf(nrm, bfhi(hv.x), acc[1]);
        acc[2] = fmaf(nrm, bflo(hv.y), acc[2]);
        acc[3] = fmaf(nrm, bfhi(hv.y), acc[3]);
      }else{
        unsigned hv = *(const unsigned*)(hf + (long)s * F);
        acc[0] = fmaf(nrm, bflo(hv), acc[0]);
        acc[1] = fmaf(nrm, bfhi(hv), acc[1]);
      }
    }
  }
  #pragma unroll
  for(int j = 0; j < FPL; ++j) acc[j] += __shfl_xor(acc[j], 16);
  if(active && hl < 16){
    if(BFOUT){
      if(FPL == 4){
        bf16x4 v;
        #pragma unroll
        for(int j = 0; j < 4; ++j) v[j] = f2bf(eluf(acc[j] + bias[fo + j]));
        *(bf16x4*)(out_bf + (long)w * F + fo) = v;
      }else{
        #pragma unroll
        for(int j = 0; j < FPL; ++j)
          out_bf[(long)w * F + fo + j] = f2bf(eluf(acc[j] + bias[fo + j]));
      }
    }else{
      if(FPL == 2){
        float2 v2 = make_float2(eluf(acc[0] + bias[fo]), eluf(acc[1] + bias[fo + 1]));
        *(float2*)(out_f + (long)w * F + fo) = v2;
      }else{
        #pragma unroll
        for(int j = 0; j < FPL; ++j)
          out_f[(long)w * F + fo + j] = eluf(acc[j] + bias[fo + j]);
      }
    }
  }
}

// ============ per-graph softmax aggregation: chunked online (m,s,v) + combine ============
template<int S>
__global__ void k_bagg_part(const float* __restrict__ h, const int* __restrict__ batch,
                            const float* __restrict__ t, float* __restrict__ pM,
                            float* __restrict__ pS, float* __restrict__ pV, int N){
  int chunk = blockIdx.x;
  int b = chunk / S, s = chunk % S;
  __shared__ int s_lo, s_hi;
  if(threadIdx.x == 0){
    int lo = 0, hi = N;
    while(lo < hi){ int mid = (lo + hi) >> 1; if(batch[mid] < b) lo = mid + 1; else hi = mid; }
    s_lo = lo;
    int lo2 = lo, hi2 = N;
    while(lo2 < hi2){ int mid = (lo2 + hi2) >> 1; if(batch[mid] < b + 1) lo2 = mid + 1; else hi2 = mid; }
    s_hi = lo2;
  }
  __syncthreads();
  int lo = s_lo, hi = s_hi;
  int len = hi - lo;
  int per = (len + S - 1) / S;
  int clo = lo + s * per;
  int chi = clo + per; if(chi > hi) chi = hi;
  float tv = t[0];
  int c = threadIdx.x & 31, r = threadIdx.x >> 5;   // 8 rows x 32 channels

  float m = -INFINITY, ss = 0.f, vv = 0.f;
  for(int i = clo + r; i < chi; i += 8){
    float hv = h[(long)i * 32 + c];
    float l = hv * tv;
    if(l > m){
      float e = (m > -INFINITY) ? __expf(m - l) : 0.f;
      ss = ss * e + 1.f; vv = vv * e + hv; m = l;
    }else{
      float e = __expf(l - m);
      ss += e; vv += e * hv;
    }
  }
  __shared__ float rm[8][32], rs[8][32], rv[8][32];
  rm[r][c] = m; rs[r][c] = ss; rv[r][c] = vv;
  __syncthreads();
  if(r == 0){
    float M = rm[0][c], SS = rs[0][c], VV = rv[0][c];
    #pragma unroll
    for(int k = 1; k < 8; ++k){
      float mo = rm[k][c], so = rs[k][c], vo = rv[k][c];
      float mn = fmaxf(M, mo);
      float ea = (M  > -INFINITY) ? __expf(M  - mn) : 0.f;
      float eb = (mo > -INFINITY) ? __expf(mo - mn) : 0.f;
      SS = SS * ea + so * eb; VV = VV * ea + vo * eb; M = mn;
    }
    pM[chunk * 32 + c] = M; pS[chunk * 32 + c] = SS; pV[chunk * 32 + c] = VV;
  }
}
template<int S>
__global__ void k_bagg_comb(const float* __restrict__ pM, const float* __restrict__ pS,
                            const float* __restrict__ pV, float* __restrict__ g, int B){
  int idx = blockIdx.x * blockDim.x + threadIdx.x;  // b*32 + c
  if(idx >= B * 32) return;
  int b = idx >> 5, c = idx & 31;
  float M = -INFINITY, SS = 0.f, VV = 0.f;
  #pragma unroll 4
  for(int k = 0; k < S; ++k){
    int p = (b * S + k) * 32 + c;
    float mo = pM[p], so = pS[p], vo = pV[p];
    float mn = fmaxf(M, mo);
    float ea = (M  > -INFINITY) ? __expf(M  - mn) : 0.f;
    float eb = (mo > -INFINITY) ? __expf(mo - mn) : 0.f;
    SS = SS * ea + so * eb; VV = VV * ea + vo * eb; M = mn;
  }
  g[idx] = VV / (SS + 1e-16f);
}

// ---- heads ----
__global__ void k_head(const float* __restrict__ g, const float* __restrict__ Wl1,
                       const float* __restrict__ bl1, const float* __restrict__ Wl2,
                       const float* __restrict__ bl2, float* __restrict__ out, int B){
  int b = blockIdx.x * blockDim.x + threadIdx.x;
  if(b >= B) return;
  float gr[32];
  #pragma unroll
  for(int k = 0; k < 32; ++k) gr[k] = g[b * 32 + k];
  float h1[16];
  #pragma unroll
  for(int j = 0; j < 16; ++j){
    float acc = bl1[j];
    #pragma unroll
    for(int k = 0; k < 32; ++k) acc = fmaf(gr[k], Wl1[k * 16 + j], acc);
    h1[j] = eluf(acc);
  }
  float l0 = bl2[0], l1 = bl2[1];
  #pragma unroll
  for(int k = 0; k < 16; ++k){
    l0 = fmaf(h1[k], Wl2[k * 2 + 0], l0);
    l1 = fmaf(h1[k], Wl2[k * 2 + 1], l1);
  }
  float mx = fmaxf(l0, l1);
  float lse = mx + __logf(__expf(l0 - mx) + __expf(l1 - mx));
  out[b * 2 + 0] = l0 - lse;
  out[b * 2 + 1] = l1 - lse;
}

extern "C" void kernel_launch(void* const* d_in, const int* in_sizes, int n_in,
                              void* d_out, int out_size, void* d_ws, size_t ws_size,
                              hipStream_t stream){
  const float* x     = (const float*)d_in[0];
  const int*   ei    = (const int*)d_in[1];
  const int*   batch = (const int*)d_in[2];
  const float* W1 = (const float*)d_in[3];
  const float* a1s = (const float*)d_in[4];
  const float* a1d = (const float*)d_in[5];
  const float* b1 = (const float*)d_in[6];
  const float* W2 = (const float*)d_in[7];
  const float* a2s = (const float*)d_in[8];
  const float* a2d = (const float*)d_in[9];
  const float* b2 = (const float*)d_in[10];
  const float* W3 = (const float*)d_in[11];
  const float* a3s = (const float*)d_in[12];
  const float* a3d = (const float*)d_in[13];
  const float* b3 = (const float*)d_in[14];
  const float* Wg1 = (const float*)d_in[15];
  const float* bg1 = (const float*)d_in[16];
  const float* Wg2 = (const float*)d_in[17];
  const float* bg2 = (const float*)d_in[18];
  const float* t   = (const float*)d_in[19];
  const float* Wl1 = (const float*)d_in[20];
  const float* bl1 = (const float*)d_in[21];
  const float* Wl2 = (const float*)d_in[22];
  const float* bl2 = (const float*)d_in[23];

  const int N = in_sizes[0];
  const int E = in_sizes[1] / 2;
  const int B = out_size / 2;
  const int ET = E + N;
  float* out = (float*)d_out;
  constexpr int BS = 32;                         // chunks per graph for batch agg

  // ---- workspace layout ----
  char* p = (char*)d_ws;
  short* Hbf  = (short*)p;            p += (size_t)N * 128 * 2;   // gemm/layer out (bf16)
  short* Abf  = (short*)p;            p += (size_t)N * 128 * 2;   // agg out (bf16)
  float* A32  = (float*)p;            p += (size_t)N * 32 * 4;    // final GCN out (fp32)
  float* as_  = (float*)p;            p += (size_t)N * 4;
  float* ad_  = (float*)p;            p += (size_t)N * 4;
  float* dinv = (float*)p;            p += (size_t)N * 4;
  int*   deg    = (int*)p;            p += (size_t)N * 4;
  int*   rowptr = (int*)p;            p += (size_t)(N + 1) * 4;
  int*   cursor = (int*)p;            p += (size_t)N * 4;
  int*   csr    = (int*)p;            p += (size_t)ET * 4;
  int*   bsum   = (int*)p;            p += (size_t)1024 * 4;
  p = alignp(p, 16);
  short* Wp2  = (short*)p;            p += 128 * 128 * 2;
  short* Wp3  = (short*)p;            p += 128 * 128 * 2;
  short* Wpg1 = (short*)p;            p += 128 * 64 * 2;
  short* Wpg2 = (short*)p;            p += 64 * 32 * 2;
  p = alignp(p, 16);
  float* S    = (float*)p;            p += 16 * 4;
  float* pM   = (float*)p;            p += (size_t)B * BS * 32 * 4;
  float* pSb  = (float*)p;            p += (size_t)B * BS * 32 * 4;
  float* pV   = (float*)p;            p += (size_t)B * BS * 32 * 4;
  float* g    = (float*)p;

  const int T = 256;
  const int gW2  = cdiv((long)N * 32, T);        // 2-dst-per-wave grids
  const int gG   = cdiv(N, 64);                  // mfma gemm: 64 rows/block
  const int NB   = cdiv(N, 256);                 // scan blocks (<=1024)
  const int Pdiv = cdiv(N, 8);                   // XCD dst-partition width

  // ---------- CSR build + weight packs ----------
  hipMemsetAsync(deg, 0, (size_t)N * 4, stream);
  k_deg_count8<<<dim3(2048), dim3(T), 0, stream>>>(ei, E, Pdiv, deg);
  k_scan_part<<<dim3(NB), dim3(256), 0, stream>>>(deg, bsum, N);
  k_scan_mid<<<dim3(1), dim3(1024), 0, stream>>>(bsum, NB, rowptr, N);
  k_scan_fin<<<dim3(NB), dim3(256), 0, stream>>>(deg, bsum, rowptr, cursor, dinv, N);
  k_fill8<<<dim3(2048), dim3(T), 0, stream>>>(ei, E, N, Pdiv, cursor, csr);
  k_pack_all<<<dim3(22), dim3(T), 0, stream>>>(W2, W3, Wg1, Wg2, W1, a1s, a1d,
                                               Wp2, Wp3, Wpg1, Wpg2, S);

  // ---------- GAT layer 1 (1 -> 128): outer product + dots ----------
  k_l1v<<<dim3(cdiv((long)N * 16, T)), dim3(T), 0, stream>>>(x, W1, S, Hbf, as_, ad_, N);
  k_gat_agg<<<dim3(gW2), dim3(T), 0, stream>>>(rowptr, csr, as_, ad_, Hbf, b1, Abf, N);

  // ---------- GAT layer 2 (128 -> 128) ----------
  k_gemm_mfma<128,128,true><<<dim3(gG), dim3(T), 0, stream>>>(Abf, Wp2, Hbf, a2s, a2d, as_, ad_, N);
  k_gat_agg<<<dim3(gW2), dim3(T), 0, stream>>>(rowptr, csr, as_, ad_, Hbf, b2, Abf, N);

  // ---------- GAT layer 3 (128 -> 128) ----------
  k_gemm_mfma<128,128,true><<<dim3(gG), dim3(T), 0, stream>>>(Abf, Wp3, Hbf, a3s, a3d, as_, ad_, N);
  k_gat_agg<<<dim3(gW2), dim3(T), 0, stream>>>(rowptr, csr, as_, ad_, Hbf, b3, Abf, N);

  // ---------- GCN layer 1 (128 -> 64) ----------
  k_gemm_mfma<128,64,false><<<dim3(gG), dim3(T), 0, stream>>>(Abf, Wpg1, Hbf, nullptr, nullptr, nullptr, nullptr, N);
  k_gcn_agg<64,true><<<dim3(gW2), dim3(T), 0, stream>>>(rowptr, csr, dinv, Hbf, bg1, Abf, (float*)nullptr, N);

  // ---------- GCN layer 2 (64 -> 32) ----------
  k_gemm_mfma<64,32,false><<<dim3(gG), dim3(T), 0, stream>>>(Abf, Wpg2, Hbf, nullptr, nullptr, nullptr, nullptr, N);
  k_gcn_agg<32,false><<<dim3(gW2), dim3(T), 0, stream>>>(rowptr, csr, dinv, Hbf, bg2, (short*)nullptr, A32, N);

  // ---------- per-graph softmax aggregation (chunked online) ----------
  k_bagg_part<BS><<<dim3(B * BS), dim3(256), 0, stream>>>(A32, batch, t, pM, pSb, pV, N);
  k_bagg_comb<BS><<<dim3(cdiv(B * 32, 256)), dim3(256), 0, stream>>>(pM, pSb, pV, g, B);

  // ---------- MLP heads + log_softmax ----------
  k_head<<<dim3(cdiv(B, 64)), dim3(64), 0, stream>>>(g, Wl1, bl1, Wl2, bl2, out, B);
}